// Round 12
// baseline (542.136 us; speedup 1.0000x reference)
//
#include <hip/hip_runtime.h>
#include <hip/hip_bf16.h>

// ---------------------------------------------------------------------------
// GAT 2-layer, N=16384 nodes, D=512, H=8, E=524288 edges (+self loops)
// GEMMs: split-bf16 MFMA 16x16x32, BM=BN=128, XOR-swizzled global_load_lds
// (round-10 staging, untouched). Layer-1 GEMM K-split z=2 (grid 1024 blocks
// = 4/CU) into f32 partials aliasing dead h0 + combine(+bias,ELU).
// Node kernels: one wave per node (round-11). alpha1 fused into node0.
// ---------------------------------------------------------------------------

#define NNODES 16384

typedef unsigned short u16;
typedef unsigned int u32;
typedef __attribute__((ext_vector_type(8))) __bf16 bf16x8;
typedef __attribute__((ext_vector_type(4))) float f32x4;

__device__ __forceinline__ u16 f2bf(float v) {
    u32 u = __builtin_bit_cast(u32, v);
    u32 r = (u + 0x7fffu + ((u >> 16) & 1u)) >> 16;
    return (u16)r;
}
__device__ __forceinline__ float bf2f(u16 s) {
    u32 u = ((u32)s) << 16;
    return __builtin_bit_cast(float, u);
}
__device__ __forceinline__ void split2(float v, u16& h, u16& l) {
    h = f2bf(v);
    l = f2bf(v - bf2f(h));
}

// async global->LDS, 16B per lane
__device__ __forceinline__ void gload_lds16(const u16* g, u16* l) {
    __builtin_amdgcn_global_load_lds(
        (__attribute__((address_space(1))) void*)(void*)(g),
        (__attribute__((address_space(3))) void*)(void*)(l), 16, 0, 0);
}

// ------------------------------ CSR build ---------------------------------
__global__ void zero_k(int* p, int n) {
    int i = blockIdx.x * 256 + threadIdx.x;
    if (i < n) p[i] = 0;
}

__global__ void count_k(const int* __restrict__ dst, int E, int* __restrict__ deg) {
    int i = blockIdx.x * 256 + threadIdx.x;
    if (i < E) atomicAdd(&deg[dst[i]], 1);
}

__global__ __launch_bounds__(1024) void scan_k(const int* __restrict__ deg,
                                               int* __restrict__ indptr,
                                               int* __restrict__ cursor, int n) {
    __shared__ int sums[1024];
    int t = threadIdx.x;
    int base = t * 16;
    int local[16];
    int s = 0;
    #pragma unroll
    for (int i = 0; i < 16; i++) { local[i] = s; s += deg[base + i]; }
    sums[t] = s;
    __syncthreads();
    for (int off = 1; off < 1024; off <<= 1) {
        int v = (t >= off) ? sums[t - off] : 0;
        __syncthreads();
        sums[t] += v;
        __syncthreads();
    }
    int base_sum = (t == 0) ? 0 : sums[t - 1];
    #pragma unroll
    for (int i = 0; i < 16; i++) {
        int v = base_sum + local[i];
        indptr[base + i] = v;
        cursor[base + i] = v;
    }
    if (t == 1023) indptr[n] = base_sum + s;
}

__global__ void scatter_k(const int* __restrict__ src, const int* __restrict__ dst,
                          int E, int* __restrict__ cursor, int* __restrict__ csr) {
    int i = blockIdx.x * 256 + threadIdx.x;
    if (i < E) {
        int pos = atomicAdd(&cursor[dst[i]], 1);
        csr[pos] = src[i];
    }
}

// ------------------------- split-bf16 prep kernels -------------------------
__global__ void prepx_k(const float* __restrict__ x, u16* __restrict__ xh,
                        u16* __restrict__ xl) {
    int idx = blockIdx.x * 256 + threadIdx.x;
    int e = idx << 2;
    int n = e >> 9, k = e & 511;
    int g = n >> 10, s = n & 1023;
    float4 v = *(const float4*)(x + ((size_t)(s * 16 + g) << 9) + k);
    u16 h[4], l[4];
    split2(v.x, h[0], l[0]);
    split2(v.y, h[1], l[1]);
    split2(v.z, h[2], l[2]);
    split2(v.w, h[3], l[3]);
    size_t o = ((size_t)n << 9) + k;
    *(ushort4*)(xh + o) = make_ushort4(h[0], h[1], h[2], h[3]);
    *(ushort4*)(xl + o) = make_ushort4(l[0], l[1], l[2], l[3]);
}

// W0t[n][k] = W0[k][n], tiled 64x64 transpose through LDS
__global__ __launch_bounds__(256) void prepW0t_k(const float* __restrict__ W0,
                                                 u16* __restrict__ Wh,
                                                 u16* __restrict__ Wl) {
    __shared__ u32 tile[64][65];
    int b = blockIdx.x;
    int kt = (b >> 3) * 64, nt = (b & 7) * 64;
    int t = threadIdx.x;
    #pragma unroll
    for (int i = 0; i < 16; i++) {
        int idx = i * 256 + t;
        int r = idx >> 6, c = idx & 63;
        float v = W0[(size_t)(kt + r) * 512 + nt + c];
        u16 h, l;
        split2(v, h, l);
        tile[r][c] = ((u32)h << 16) | l;
    }
    __syncthreads();
    #pragma unroll
    for (int i = 0; i < 8; i++) {
        int idx = i * 256 + t;
        int r = idx >> 5, c2 = (idx & 31) * 2;
        u32 p0 = tile[c2][r], p1 = tile[c2 + 1][r];
        size_t o = (size_t)(nt + r) * 512 + kt + c2;
        *(ushort2*)(Wh + o) = make_ushort2((u16)(p0 >> 16), (u16)(p1 >> 16));
        *(ushort2*)(Wl + o) = make_ushort2((u16)(p0 & 0xffff), (u16)(p1 & 0xffff));
    }
}

// B1t[c][h*512+k] = W1[k][h*512+c]/8, per-head tiled 64x64 transpose
__global__ __launch_bounds__(256) void prepW1t_k(const float* __restrict__ W1,
                                                 u16* __restrict__ Bh,
                                                 u16* __restrict__ Bl) {
    __shared__ u32 tile[64][65];
    int b = blockIdx.x;
    int hh = b >> 6;
    int rem = b & 63;
    int kt = (rem >> 3) * 64, ct = (rem & 7) * 64;
    int t = threadIdx.x;
    #pragma unroll
    for (int i = 0; i < 16; i++) {
        int idx = i * 256 + t;
        int r = idx >> 6, c = idx & 63;
        float v = W1[(size_t)(kt + r) * 4096 + hh * 512 + ct + c] * 0.125f;
        u16 h, l;
        split2(v, h, l);
        tile[r][c] = ((u32)h << 16) | l;
    }
    __syncthreads();
    #pragma unroll
    for (int i = 0; i < 8; i++) {
        int idx = i * 256 + t;
        int r = idx >> 5, c2 = (idx & 31) * 2;
        u32 p0 = tile[c2][r], p1 = tile[c2 + 1][r];
        size_t o = (size_t)(ct + r) * 4096 + hh * 512 + kt + c2;
        *(ushort2*)(Bh + o) = make_ushort2((u16)(p0 >> 16), (u16)(p1 >> 16));
        *(ushort2*)(Bl + o) = make_ushort2((u16)(p0 & 0xffff), (u16)(p1 & 0xffff));
    }
}

// ---------------------------------------------------------------------------
// Split-bf16 MFMA GEMM (round-10 staging): C[M,512] = A[M,K] @ Bt[512,K]^T
// SPLIT=1: K halved over blockIdx.z, f32 partials to P (no bias/ELU).
// ---------------------------------------------------------------------------
template <int MODE, int TERMS, int SPLIT>
__global__ __launch_bounds__(256) void mgemm_k(
    const u16* __restrict__ Ah, const u16* __restrict__ Al,
    const u16* __restrict__ Bh, const u16* __restrict__ Bl,
    float* __restrict__ C, int K, const float* __restrict__ bias,
    float* __restrict__ P) {
    constexpr int pAl = 4096;
    constexpr int pBh = (TERMS == 3) ? 8192 : 4096;
    constexpr int pBl = (TERMS == 3) ? 12288 : 8192;
    constexpr int NSEG = (TERMS == 3) ? 8 : 6;
    __shared__ u16 smem[(TERMS == 3) ? 16384 : 12288];

    int t = threadIdx.x;
    int lane = t & 63, w = t >> 6;
    int wr = w >> 1, wc = w & 1;
    int row0 = blockIdx.y * 128, col0 = blockIdx.x * 128;
    int kcnt = SPLIT ? (K >> 1) : K;
    int kbeg = SPLIT ? ((int)blockIdx.z * kcnt) : 0;

    f32x4 acc[4][4];
    #pragma unroll
    for (int i = 0; i < 4; i++)
        #pragma unroll
        for (int j = 0; j < 4; j++) acc[i][j] = (f32x4){0.f, 0.f, 0.f, 0.f};

    int srow = lane >> 2;
    int sl4 = lane & 3;
    const u16* gp[NSEG];
    u16* lp[NSEG];
    #pragma unroll
    for (int ii = 0; ii < NSEG; ii++) {
        int s = w * NSEG + ii;
        int pl = s >> 3, seg = s & 7;
        const u16* gb;
        int g0;
        if (TERMS == 3) {
            gb = (pl == 0) ? Ah : (pl == 1) ? Al : (pl == 2) ? Bh : Bl;
            g0 = (pl < 2) ? row0 : col0;
        } else {
            gb = (pl == 0) ? Ah : (pl == 1) ? Bh : Bl;
            g0 = (pl == 0) ? row0 : col0;
        }
        int row = seg * 16 + srow;
        int slot = sl4 ^ ((row >> 1) & 3);
        gp[ii] = gb + (size_t)(g0 + row) * K + kbeg + slot * 8;
        lp[ii] = smem + pl * 4096 + seg * 512;
    }

    int rl = lane & 15, kb = lane >> 4;

    for (int k0 = 0; k0 < kcnt; k0 += 32) {
        #pragma unroll
        for (int ii = 0; ii < NSEG; ii++) gload_lds16(gp[ii] + k0, lp[ii]);
        __syncthreads();

        bf16x8 afh[4], afl_[4], bfh[4], bfl[4];
        #pragma unroll
        for (int f = 0; f < 4; f++) {
            int r = wr * 64 + f * 16 + rl;
            int off = r * 32 + ((kb ^ ((r >> 1) & 3)) << 3);
            afh[f] = *(const bf16x8*)(smem + off);
            if (TERMS == 3) afl_[f] = *(const bf16x8*)(smem + pAl + off);
        }
        #pragma unroll
        for (int j = 0; j < 4; j++) {
            int r = wc * 64 + j * 16 + rl;
            int off = r * 32 + ((kb ^ ((r >> 1) & 3)) << 3);
            bfh[j] = *(const bf16x8*)(smem + pBh + off);
            bfl[j] = *(const bf16x8*)(smem + pBl + off);
        }
        #pragma unroll
        for (int i = 0; i < 4; i++)
            #pragma unroll
            for (int j = 0; j < 4; j++) {
                if (TERMS == 3)
                    acc[i][j] = __builtin_amdgcn_mfma_f32_16x16x32_bf16(
                        afl_[i], bfh[j], acc[i][j], 0, 0, 0);
                acc[i][j] = __builtin_amdgcn_mfma_f32_16x16x32_bf16(
                    afh[i], bfl[j], acc[i][j], 0, 0, 0);
                acc[i][j] = __builtin_amdgcn_mfma_f32_16x16x32_bf16(
                    afh[i], bfh[j], acc[i][j], 0, 0, 0);
            }
        __syncthreads();
    }

    // C/D layout 16x16: col = lane&15, row = (lane>>4)*4 + q
    int cr = kb * 4;
    #pragma unroll
    for (int i = 0; i < 4; i++) {
        #pragma unroll
        for (int j = 0; j < 4; j++) {
            int col = col0 + wc * 64 + j * 16 + rl;
            float bv = (MODE == 1 && !SPLIT) ? bias[col] : 0.f;
            f32x4 v = acc[i][j];
            #pragma unroll
            for (int q = 0; q < 4; q++) {
                float o = v[q] + bv;
                if (MODE == 1 && !SPLIT) o = o > 0.f ? o : __expf(o) - 1.f;
                size_t grow = (size_t)(row0 + wr * 64 + i * 16 + cr + q);
                if (SPLIT) {
                    size_t M = (size_t)gridDim.y * 128;
                    P[((size_t)blockIdx.z * M + grow) * 512 + col] = o;
                } else {
                    C[grow * 512 + col] = o;
                }
            }
        }
    }
}

// combine K-split partials: out = ELU(P0 + P1 + bias)
__global__ void combine_k(const float* __restrict__ P,
                          const float* __restrict__ bias,
                          float* __restrict__ out, int CH) {
    int i = blockIdx.x * 256 + threadIdx.x;
    if (i >= CH * 128) return;
    int e = i << 2;
    size_t stride = (size_t)CH * 512;
    float4 a = *(const float4*)(P + e);
    float4 b = *(const float4*)(P + stride + e);
    float4 bv = *(const float4*)(bias + (e & 511));
    float4 s;
    s.x = a.x + b.x + bv.x;
    s.y = a.y + b.y + bv.y;
    s.z = a.z + b.z + bv.z;
    s.w = a.w + b.w + bv.w;
    s.x = s.x > 0.f ? s.x : __expf(s.x) - 1.f;
    s.y = s.y > 0.f ? s.y : __expf(s.y) - 1.f;
    s.z = s.z > 0.f ? s.z : __expf(s.z) - 1.f;
    s.w = s.w > 0.f ? s.w : __expf(s.w) - 1.f;
    *(float4*)(out + e) = s;
}

// ------------------------------ attention ---------------------------------
__global__ __launch_bounds__(256) void alpha0_k(const float* __restrict__ h0,
                                                const float* __restrict__ att_s,
                                                const float* __restrict__ att_d,
                                                float* __restrict__ as_,
                                                float* __restrict__ ad_) {
    int n = blockIdx.x * 4 + (threadIdx.x >> 6);
    int l = threadIdx.x & 63;
    int h = l >> 3, i = l & 7;
    float ps = 0.f, pd = 0.f;
    #pragma unroll
    for (int c = 0; c < 64; c += 8) {
        float v = h0[(size_t)n * 512 + h * 64 + c + i];
        ps += v * att_s[h * 64 + c + i];
        pd += v * att_d[h * 64 + c + i];
    }
    #pragma unroll
    for (int off = 1; off < 8; off <<= 1) {
        ps += __shfl_xor(ps, off);
        pd += __shfl_xor(pd, off);
    }
    if (i == 0) {
        as_[n * 8 + h] = ps;
        ad_[n * 8 + h] = pd;
    }
}

__global__ __launch_bounds__(256) void prep1_k(const float* __restrict__ W1,
                                               const float* __restrict__ as1,
                                               const float* __restrict__ ad1,
                                               float* __restrict__ ws1,
                                               float* __restrict__ wd1) {
    int k = blockIdx.x;
    int t = threadIdx.x;
    int h = t >> 5, lane = t & 31;
    float ps = 0.f, pd = 0.f;
    for (int c = lane; c < 512; c += 32) {
        float w = W1[(size_t)k * 4096 + h * 512 + c];
        ps += w * as1[h * 512 + c];
        pd += w * ad1[h * 512 + c];
    }
    #pragma unroll
    for (int off = 1; off < 32; off <<= 1) {
        ps += __shfl_xor(ps, off);
        pd += __shfl_xor(pd, off);
    }
    if (lane == 0) {
        ws1[k * 8 + h] = ps;
        wd1[k * 8 + h] = pd;
    }
}

// ---------------------------------------------------------------------------
// node0w: ONE WAVE PER NODE (4 nodes/block, zero barriers). Lane l: softmax
// head h=l>>3 (stripe l&7); aggregates channels 8l..8l+7 (same head).
// ---------------------------------------------------------------------------
__global__ __launch_bounds__(256) void node0w_k(
    const float* __restrict__ h0, const float* __restrict__ asrc,
    const float* __restrict__ adst, const int* __restrict__ indptr,
    const int* __restrict__ csr, const float* __restrict__ b0,
    const float* __restrict__ ws1, const float* __restrict__ wd1,
    float* __restrict__ hl0, float* __restrict__ as1, float* __restrict__ ad1) {
    int b = blockIdx.x;
    int wid = threadIdx.x >> 6;
    int l = threadIdx.x & 63;
    int d = (b & 7) * (NNODES / 8) + ((b >> 3) << 2) + wid;  // XCD-pinned
    int h = l >> 3;
    int e0 = indptr[d];
    int ne = indptr[d + 1] - e0;   // real edges; e==ne is the self loop
    float adh = adst[d * 8 + h];

    float m = -3.0e38f, z = 0.f;
    for (int e = (l & 7); e <= ne; e += 8) {
        int s = (e < ne) ? csr[e0 + e] : d;
        float v = asrc[s * 8 + h] + adh;
        v = v > 0.f ? v : 0.2f * v;
        float mn = fmaxf(m, v);
        z = z * __expf(m - mn) + __expf(v - mn);
        m = mn;
    }
    #pragma unroll
    for (int off = 1; off < 8; off <<= 1) {
        float mo = __shfl_xor(m, off);
        float zo = __shfl_xor(z, off);
        float mn = fmaxf(m, mo);
        z = z * __expf(m - mn) + zo * __expf(mo - mn);
        m = mn;
    }
    float rz = 1.0f / (z + 1e-16f);

    float acc[8] = {};
    for (int eb = 0; eb <= ne; eb += 8) {
        int idx = eb + (l & 7);
        int sv = (idx < ne) ? csr[e0 + idx] : d;
        int nn = min(8, ne + 1 - eb);
        #pragma unroll
        for (int i = 0; i < 8; i++) {
            if (i < nn) {
                int s = __shfl(sv, (l & 56) | i);
                float v = asrc[s * 8 + h] + adh;
                v = v > 0.f ? v : 0.2f * v;
                float a = __expf(v - m) * rz;
                const float4* hp = (const float4*)(h0 + ((size_t)s << 9) + 8 * l);
                float4 v0 = hp[0], v1 = hp[1];
                acc[0] = fmaf(a, v0.x, acc[0]);
                acc[1] = fmaf(a, v0.y, acc[1]);
                acc[2] = fmaf(a, v0.z, acc[2]);
                acc[3] = fmaf(a, v0.w, acc[3]);
                acc[4] = fmaf(a, v1.x, acc[4]);
                acc[5] = fmaf(a, v1.y, acc[5]);
                acc[6] = fmaf(a, v1.z, acc[6]);
                acc[7] = fmaf(a, v1.w, acc[7]);
            }
        }
    }

    const float4* b4 = (const float4*)(b0 + 8 * l);
    float4 bva = b4[0], bvb = b4[1];
    float o[8];
    o[0] = acc[0] + bva.x; o[1] = acc[1] + bva.y;
    o[2] = acc[2] + bva.z; o[3] = acc[3] + bva.w;
    o[4] = acc[4] + bvb.x; o[5] = acc[5] + bvb.y;
    o[6] = acc[6] + bvb.z; o[7] = acc[7] + bvb.w;
    #pragma unroll
    for (int k = 0; k < 8; k++) o[k] = o[k] > 0.f ? o[k] : __expf(o[k]) - 1.f;
    float* hr = hl0 + ((size_t)d << 9) + 8 * l;
    *(float4*)hr = make_float4(o[0], o[1], o[2], o[3]);
    *(float4*)(hr + 4) = make_float4(o[4], o[5], o[6], o[7]);

    float ps[8] = {}, pd[8] = {};
    #pragma unroll
    for (int k = 0; k < 8; k++) {
        const float4* w4 = (const float4*)(ws1 + (size_t)(8 * l + k) * 8);
        const float4* v4 = (const float4*)(wd1 + (size_t)(8 * l + k) * 8);
        float4 wa = w4[0], wb = w4[1];
        float4 va = v4[0], vb = v4[1];
        float ok = o[k];
        ps[0] = fmaf(ok, wa.x, ps[0]); ps[1] = fmaf(ok, wa.y, ps[1]);
        ps[2] = fmaf(ok, wa.z, ps[2]); ps[3] = fmaf(ok, wa.w, ps[3]);
        ps[4] = fmaf(ok, wb.x, ps[4]); ps[5] = fmaf(ok, wb.y, ps[5]);
        ps[6] = fmaf(ok, wb.z, ps[6]); ps[7] = fmaf(ok, wb.w, ps[7]);
        pd[0] = fmaf(ok, va.x, pd[0]); pd[1] = fmaf(ok, va.y, pd[1]);
        pd[2] = fmaf(ok, va.z, pd[2]); pd[3] = fmaf(ok, va.w, pd[3]);
        pd[4] = fmaf(ok, vb.x, pd[4]); pd[5] = fmaf(ok, vb.y, pd[5]);
        pd[6] = fmaf(ok, vb.z, pd[6]); pd[7] = fmaf(ok, vb.w, pd[7]);
    }
    #pragma unroll
    for (int off = 1; off < 64; off <<= 1) {
        #pragma unroll
        for (int j = 0; j < 8; j++) {
            ps[j] += __shfl_xor(ps[j], off);
            pd[j] += __shfl_xor(pd[j], off);
        }
    }
    #pragma unroll
    for (int j = 0; j < 8; j++) {
        if (l == j) as1[(size_t)d * 8 + j] = ps[j];
        if (l == 8 + j) ad1[(size_t)d * 8 + j] = pd[j];
    }
}

// ---------------------------------------------------------------------------
// node1w: ONE WAVE PER NODE. Lane l: softmax head hme=l&7 (stripe l>>3);
// aggregates acc[8 heads][8 ch] for channels 8l..8l+7. bf16 single plane out.
// ---------------------------------------------------------------------------
__global__ __launch_bounds__(256) void node1w_k(
    const float* __restrict__ hl0, const float* __restrict__ asrc,
    const float* __restrict__ adst, const int* __restrict__ indptr,
    const int* __restrict__ csr, u16* __restrict__ aggh, int base, int ch) {
    int b = blockIdx.x;
    int wid = threadIdx.x >> 6;
    int l = threadIdx.x & 63;
    int dl = (b & 7) * (ch >> 3) + ((b >> 3) << 2) + wid;
    int d = base + dl;
    int hme = l & 7;
    int e0 = indptr[d];
    int ne = indptr[d + 1] - e0;
    float adh = adst[d * 8 + hme];

    float m = -3.0e38f, z = 0.f;
    for (int e = (l >> 3); e <= ne; e += 8) {
        int s = (e < ne) ? csr[e0 + e] : d;
        float v = asrc[s * 8 + hme] + adh;
        v = v > 0.f ? v : 0.2f * v;
        float mn = fmaxf(m, v);
        z = z * __expf(m - mn) + __expf(v - mn);
        m = mn;
    }
    #pragma unroll
    for (int off = 8; off < 64; off <<= 1) {
        float mo = __shfl_xor(m, off);
        float zo = __shfl_xor(z, off);
        float mn = fmaxf(m, mo);
        z = z * __expf(m - mn) + zo * __expf(mo - mn);
        m = mn;
    }
    float rz = 1.0f / (z + 1e-16f);

    float acc[8][8] = {};
    for (int eb = 0; eb <= ne; eb += 8) {
        int idx = eb + (l & 7);
        int sv = (idx < ne) ? csr[e0 + idx] : d;
        int nn = min(8, ne + 1 - eb);
        #pragma unroll
        for (int i = 0; i < 8; i++) {
            if (i < nn) {
                int s = __shfl(sv, (l & 56) | i);
                float v = asrc[s * 8 + hme] + adh;
                v = v > 0.f ? v : 0.2f * v;
                float amine = __expf(v - m) * rz;
                float a[8];
                #pragma unroll
                for (int hh = 0; hh < 8; hh++)
                    a[hh] = __shfl(amine, (l & 56) | hh);
                const float4* hp = (const float4*)(hl0 + ((size_t)s << 9) + 8 * l);
                float4 v0 = hp[0], v1 = hp[1];
                #pragma unroll
                for (int hh = 0; hh < 8; hh++) {
                    acc[hh][0] = fmaf(a[hh], v0.x, acc[hh][0]);
                    acc[hh][1] = fmaf(a[hh], v0.y, acc[hh][1]);
                    acc[hh][2] = fmaf(a[hh], v0.z, acc[hh][2]);
                    acc[hh][3] = fmaf(a[hh], v0.w, acc[hh][3]);
                    acc[hh][4] = fmaf(a[hh], v1.x, acc[hh][4]);
                    acc[hh][5] = fmaf(a[hh], v1.y, acc[hh][5]);
                    acc[hh][6] = fmaf(a[hh], v1.z, acc[hh][6]);
                    acc[hh][7] = fmaf(a[hh], v1.w, acc[hh][7]);
                }
            }
        }
    }

    #pragma unroll
    for (int hh = 0; hh < 8; hh++) {
        ushort4 qa = make_ushort4(f2bf(acc[hh][0]), f2bf(acc[hh][1]),
                                  f2bf(acc[hh][2]), f2bf(acc[hh][3]));
        ushort4 qb = make_ushort4(f2bf(acc[hh][4]), f2bf(acc[hh][5]),
                                  f2bf(acc[hh][6]), f2bf(acc[hh][7]));
        size_t ob = (size_t)dl * 4096 + hh * 512 + 8 * l;
        *(ushort4*)(aggh + ob) = qa;
        *(ushort4*)(aggh + ob + 4) = qb;
    }
}

// ------------------------------- launcher ----------------------------------
extern "C" void kernel_launch(void* const* d_in, const int* in_sizes, int n_in,
                              void* d_out, int out_size, void* d_ws, size_t ws_size,
                              hipStream_t stream) {
    const float* x = (const float*)d_in[0];
    const int* ei = (const int*)d_in[1];
    const float* W0 = (const float*)d_in[2];
    const float* at_s0 = (const float*)d_in[3];
    const float* at_d0 = (const float*)d_in[4];
    const float* b0 = (const float*)d_in[5];
    const float* W1 = (const float*)d_in[6];
    const float* at_s1 = (const float*)d_in[7];
    const float* at_d1 = (const float*)d_in[8];
    const float* b1 = (const float*)d_in[9];
    float* out = (float*)d_out;

    const int N = NNODES;
    const int E = in_sizes[1] / 2;
    const int* esrc = ei;
    const int* edst = ei + E;

    char* p = (char*)d_ws;
    auto carve = [&](size_t bytes) -> void* {
        void* r = (void*)p;
        p += ((bytes + 255) & ~(size_t)255);
        return r;
    };
    float* h0 = (float*)carve((size_t)N * 512 * 4);   // aliased by P in layer 1
    float* hl0 = (float*)carve((size_t)N * 512 * 4);
    float* as0 = (float*)carve((size_t)N * 8 * 4);
    float* ad0 = (float*)carve((size_t)N * 8 * 4);
    float* as1 = (float*)carve((size_t)N * 8 * 4);
    float* ad1 = (float*)carve((size_t)N * 8 * 4);
    int* deg = (int*)carve((size_t)N * 4);
    int* indptr = (int*)carve((size_t)(N + 1) * 4);
    int* cursor = (int*)carve((size_t)N * 4);
    int* csr = (int*)carve((size_t)E * 4);
    float* ws1 = (float*)carve(512 * 8 * 4);
    float* wd1 = (float*)carve(512 * 8 * 4);
    u16* xh = (u16*)carve((size_t)N * 512 * 2);
    u16* xl = (u16*)carve((size_t)N * 512 * 2);
    u16* W0h = (u16*)carve((size_t)512 * 512 * 2);
    u16* W0l = (u16*)carve((size_t)512 * 512 * 2);
    u16* B1h = (u16*)carve((size_t)512 * 4096 * 2);
    u16* B1l = (u16*)carve((size_t)512 * 4096 * 2);
    size_t used = (size_t)(p - (char*)d_ws);

    // chunk size: agg is 8 KB/node (single bf16 plane); P (2*CH*512 f32)
    // aliases h0, which is dead once node0w has produced hl0/as1/ad1.
    int CH = 1024;
    const int cands[5] = {16384, 8192, 4096, 2048, 1024};
    for (int ci = 0; ci < 5; ci++) {
        if (ws_size >= used + (size_t)cands[ci] * 8192 + 512) {
            CH = cands[ci];
            break;
        }
    }
    u16* aggh = (u16*)carve((size_t)CH * 4096 * 2);
    float* P = h0;   // 2 * CH * 512 floats <= N * 512 floats = |h0|

    // CSR build
    zero_k<<<(N + 255) / 256, 256, 0, stream>>>(deg, N);
    count_k<<<(E + 255) / 256, 256, 0, stream>>>(edst, E, deg);
    scan_k<<<1, 1024, 0, stream>>>(deg, indptr, cursor, N);
    scatter_k<<<(E + 255) / 256, 256, 0, stream>>>(esrc, edst, E, cursor, csr);

    // operand prep (split bf16) + folded layer-1 attention weights
    prepx_k<<<(N * 512 / 4 + 255) / 256, 256, 0, stream>>>(x, xh, xl);
    prepW0t_k<<<64, 256, 0, stream>>>(W0, W0h, W0l);
    prepW1t_k<<<512, 256, 0, stream>>>(W1, B1h, B1l);
    prep1_k<<<512, 256, 0, stream>>>(W1, at_s1, at_d1, ws1, wd1);

    // Layer 0
    mgemm_k<0, 3, 0><<<dim3(4, N / 128), 256, 0, stream>>>(
        xh, xl, W0h, W0l, h0, 512, nullptr, nullptr);
    alpha0_k<<<N / 4, 256, 0, stream>>>(h0, at_s0, at_d0, as0, ad0);
    node0w_k<<<N / 4, 256, 0, stream>>>(h0, as0, ad0, indptr, csr, b0, ws1, wd1,
                                        hl0, as1, ad1);

    // Layer 1: bf16 aggregate, K-split 2-term GEMM into P, combine(+b1, ELU)
    for (int base = 0; base < N; base += CH) {
        node1w_k<<<CH / 4, 256, 0, stream>>>(hl0, as1, ad1, indptr, csr, aggh,
                                             base, CH);
        mgemm_k<1, 2, 1><<<dim3(4, CH / 128, 2), 256, 0, stream>>>(
            aggh, nullptr, B1h, B1l, nullptr, 4096, nullptr, P);
        combine_k<<<CH / 2, 256, 0, stream>>>(P, b1, out + (size_t)base * 512,
                                              CH);
    }
}

// Round 13
// 512.668 us; speedup vs baseline: 1.0575x; 1.0575x over previous
//
#include <hip/hip_runtime.h>
#include <hip/hip_bf16.h>

// ---------------------------------------------------------------------------
// GAT 2-layer, N=16384 nodes, D=512, H=8, E=524288 edges (+self loops)
// GEMMs: split-bf16 MFMA 16x16x32, BM=BN=128, XOR-swizzled global_load_lds
// (round-10/11 proven, no K-split). GEMM0 epilogue fuses alpha0 (per-head
// dot with att vectors -- each wave's fragment covers exactly one head).
// Node kernels: one wave per node. alpha1 fused into node0.
// ---------------------------------------------------------------------------

#define NNODES 16384

typedef unsigned short u16;
typedef unsigned int u32;
typedef __attribute__((ext_vector_type(8))) __bf16 bf16x8;
typedef __attribute__((ext_vector_type(4))) float f32x4;

__device__ __forceinline__ u16 f2bf(float v) {
    u32 u = __builtin_bit_cast(u32, v);
    u32 r = (u + 0x7fffu + ((u >> 16) & 1u)) >> 16;
    return (u16)r;
}
__device__ __forceinline__ float bf2f(u16 s) {
    u32 u = ((u32)s) << 16;
    return __builtin_bit_cast(float, u);
}
__device__ __forceinline__ void split2(float v, u16& h, u16& l) {
    h = f2bf(v);
    l = f2bf(v - bf2f(h));
}

// async global->LDS, 16B per lane
__device__ __forceinline__ void gload_lds16(const u16* g, u16* l) {
    __builtin_amdgcn_global_load_lds(
        (__attribute__((address_space(1))) void*)(void*)(g),
        (__attribute__((address_space(3))) void*)(void*)(l), 16, 0, 0);
}

// ------------------------------ CSR build ---------------------------------
__global__ void zero_k(int* p, int n) {
    int i = blockIdx.x * 256 + threadIdx.x;
    if (i < n) p[i] = 0;
}

__global__ void count_k(const int* __restrict__ dst, int E, int* __restrict__ deg) {
    int i = blockIdx.x * 256 + threadIdx.x;
    if (i < E) atomicAdd(&deg[dst[i]], 1);
}

__global__ __launch_bounds__(1024) void scan_k(const int* __restrict__ deg,
                                               int* __restrict__ indptr,
                                               int* __restrict__ cursor, int n) {
    __shared__ int sums[1024];
    int t = threadIdx.x;
    int base = t * 16;
    int local[16];
    int s = 0;
    #pragma unroll
    for (int i = 0; i < 16; i++) { local[i] = s; s += deg[base + i]; }
    sums[t] = s;
    __syncthreads();
    for (int off = 1; off < 1024; off <<= 1) {
        int v = (t >= off) ? sums[t - off] : 0;
        __syncthreads();
        sums[t] += v;
        __syncthreads();
    }
    int base_sum = (t == 0) ? 0 : sums[t - 1];
    #pragma unroll
    for (int i = 0; i < 16; i++) {
        int v = base_sum + local[i];
        indptr[base + i] = v;
        cursor[base + i] = v;
    }
    if (t == 1023) indptr[n] = base_sum + s;
}

__global__ void scatter_k(const int* __restrict__ src, const int* __restrict__ dst,
                          int E, int* __restrict__ cursor, int* __restrict__ csr) {
    int i = blockIdx.x * 256 + threadIdx.x;
    if (i < E) {
        int pos = atomicAdd(&cursor[dst[i]], 1);
        csr[pos] = src[i];
    }
}

// ------------------------- split-bf16 prep kernels -------------------------
__global__ void prepx_k(const float* __restrict__ x, u16* __restrict__ xh,
                        u16* __restrict__ xl) {
    int idx = blockIdx.x * 256 + threadIdx.x;
    int e = idx << 2;
    int n = e >> 9, k = e & 511;
    int g = n >> 10, s = n & 1023;
    float4 v = *(const float4*)(x + ((size_t)(s * 16 + g) << 9) + k);
    u16 h[4], l[4];
    split2(v.x, h[0], l[0]);
    split2(v.y, h[1], l[1]);
    split2(v.z, h[2], l[2]);
    split2(v.w, h[3], l[3]);
    size_t o = ((size_t)n << 9) + k;
    *(ushort4*)(xh + o) = make_ushort4(h[0], h[1], h[2], h[3]);
    *(ushort4*)(xl + o) = make_ushort4(l[0], l[1], l[2], l[3]);
}

// W0t[n][k] = W0[k][n], tiled 64x64 transpose through LDS
__global__ __launch_bounds__(256) void prepW0t_k(const float* __restrict__ W0,
                                                 u16* __restrict__ Wh,
                                                 u16* __restrict__ Wl) {
    __shared__ u32 tile[64][65];
    int b = blockIdx.x;
    int kt = (b >> 3) * 64, nt = (b & 7) * 64;
    int t = threadIdx.x;
    #pragma unroll
    for (int i = 0; i < 16; i++) {
        int idx = i * 256 + t;
        int r = idx >> 6, c = idx & 63;
        float v = W0[(size_t)(kt + r) * 512 + nt + c];
        u16 h, l;
        split2(v, h, l);
        tile[r][c] = ((u32)h << 16) | l;
    }
    __syncthreads();
    #pragma unroll
    for (int i = 0; i < 8; i++) {
        int idx = i * 256 + t;
        int r = idx >> 5, c2 = (idx & 31) * 2;
        u32 p0 = tile[c2][r], p1 = tile[c2 + 1][r];
        size_t o = (size_t)(nt + r) * 512 + kt + c2;
        *(ushort2*)(Wh + o) = make_ushort2((u16)(p0 >> 16), (u16)(p1 >> 16));
        *(ushort2*)(Wl + o) = make_ushort2((u16)(p0 & 0xffff), (u16)(p1 & 0xffff));
    }
}

// B1t[c][h*512+k] = W1[k][h*512+c]/8, per-head tiled 64x64 transpose
__global__ __launch_bounds__(256) void prepW1t_k(const float* __restrict__ W1,
                                                 u16* __restrict__ Bh,
                                                 u16* __restrict__ Bl) {
    __shared__ u32 tile[64][65];
    int b = blockIdx.x;
    int hh = b >> 6;
    int rem = b & 63;
    int kt = (rem >> 3) * 64, ct = (rem & 7) * 64;
    int t = threadIdx.x;
    #pragma unroll
    for (int i = 0; i < 16; i++) {
        int idx = i * 256 + t;
        int r = idx >> 6, c = idx & 63;
        float v = W1[(size_t)(kt + r) * 4096 + hh * 512 + ct + c] * 0.125f;
        u16 h, l;
        split2(v, h, l);
        tile[r][c] = ((u32)h << 16) | l;
    }
    __syncthreads();
    #pragma unroll
    for (int i = 0; i < 8; i++) {
        int idx = i * 256 + t;
        int r = idx >> 5, c2 = (idx & 31) * 2;
        u32 p0 = tile[c2][r], p1 = tile[c2 + 1][r];
        size_t o = (size_t)(ct + r) * 4096 + hh * 512 + kt + c2;
        *(ushort2*)(Bh + o) = make_ushort2((u16)(p0 >> 16), (u16)(p1 >> 16));
        *(ushort2*)(Bl + o) = make_ushort2((u16)(p0 & 0xffff), (u16)(p1 & 0xffff));
    }
}

// ---------------------------------------------------------------------------
// Split-bf16 MFMA GEMM: C[M,512] = A[M,K] @ Bt[512,K]^T  (round-10 structure)
// MODE 0: plain store. MODE 1: +bias, ELU. MODE 2: plain store + fused
// alpha0 (each wave's 64-col fragment = one head; dot with att_s/att_d over
// the 64 channels via in-register FMA + 16-lane shfl reduction).
// ---------------------------------------------------------------------------
template <int MODE, int TERMS>
__global__ __launch_bounds__(256) void mgemm_k(
    const u16* __restrict__ Ah, const u16* __restrict__ Al,
    const u16* __restrict__ Bh, const u16* __restrict__ Bl,
    float* __restrict__ C, int K, const float* __restrict__ bias,
    const float* __restrict__ att_s, const float* __restrict__ att_d,
    float* __restrict__ as_, float* __restrict__ ad_) {
    constexpr int pAl = 4096;
    constexpr int pBh = (TERMS == 3) ? 8192 : 4096;
    constexpr int pBl = (TERMS == 3) ? 12288 : 8192;
    constexpr int NSEG = (TERMS == 3) ? 8 : 6;
    __shared__ u16 smem[(TERMS == 3) ? 16384 : 12288];

    int t = threadIdx.x;
    int lane = t & 63, w = t >> 6;
    int wr = w >> 1, wc = w & 1;
    int row0 = blockIdx.y * 128, col0 = blockIdx.x * 128;

    f32x4 acc[4][4];
    #pragma unroll
    for (int i = 0; i < 4; i++)
        #pragma unroll
        for (int j = 0; j < 4; j++) acc[i][j] = (f32x4){0.f, 0.f, 0.f, 0.f};

    int srow = lane >> 2;
    int sl4 = lane & 3;
    const u16* gp[NSEG];
    u16* lp[NSEG];
    #pragma unroll
    for (int ii = 0; ii < NSEG; ii++) {
        int s = w * NSEG + ii;
        int pl = s >> 3, seg = s & 7;
        const u16* gb;
        int g0;
        if (TERMS == 3) {
            gb = (pl == 0) ? Ah : (pl == 1) ? Al : (pl == 2) ? Bh : Bl;
            g0 = (pl < 2) ? row0 : col0;
        } else {
            gb = (pl == 0) ? Ah : (pl == 1) ? Bh : Bl;
            g0 = (pl == 0) ? row0 : col0;
        }
        int row = seg * 16 + srow;
        int slot = sl4 ^ ((row >> 1) & 3);
        gp[ii] = gb + (size_t)(g0 + row) * K + slot * 8;
        lp[ii] = smem + pl * 4096 + seg * 512;
    }

    int rl = lane & 15, kb = lane >> 4;

    for (int k0 = 0; k0 < K; k0 += 32) {
        #pragma unroll
        for (int ii = 0; ii < NSEG; ii++) gload_lds16(gp[ii] + k0, lp[ii]);
        __syncthreads();

        bf16x8 afh[4], afl_[4], bfh[4], bfl[4];
        #pragma unroll
        for (int f = 0; f < 4; f++) {
            int r = wr * 64 + f * 16 + rl;
            int off = r * 32 + ((kb ^ ((r >> 1) & 3)) << 3);
            afh[f] = *(const bf16x8*)(smem + off);
            if (TERMS == 3) afl_[f] = *(const bf16x8*)(smem + pAl + off);
        }
        #pragma unroll
        for (int j = 0; j < 4; j++) {
            int r = wc * 64 + j * 16 + rl;
            int off = r * 32 + ((kb ^ ((r >> 1) & 3)) << 3);
            bfh[j] = *(const bf16x8*)(smem + pBh + off);
            bfl[j] = *(const bf16x8*)(smem + pBl + off);
        }
        #pragma unroll
        for (int i = 0; i < 4; i++)
            #pragma unroll
            for (int j = 0; j < 4; j++) {
                if (TERMS == 3)
                    acc[i][j] = __builtin_amdgcn_mfma_f32_16x16x32_bf16(
                        afl_[i], bfh[j], acc[i][j], 0, 0, 0);
                acc[i][j] = __builtin_amdgcn_mfma_f32_16x16x32_bf16(
                    afh[i], bfl[j], acc[i][j], 0, 0, 0);
                acc[i][j] = __builtin_amdgcn_mfma_f32_16x16x32_bf16(
                    afh[i], bfh[j], acc[i][j], 0, 0, 0);
            }
        __syncthreads();
    }

    // C/D layout 16x16: col = lane&15, row = (lane>>4)*4 + q
    int cr = kb * 4;
    #pragma unroll
    for (int i = 0; i < 4; i++) {
        #pragma unroll
        for (int j = 0; j < 4; j++) {
            int col = col0 + wc * 64 + j * 16 + rl;
            float bv = (MODE == 1) ? bias[col] : 0.f;
            f32x4 v = acc[i][j];
            #pragma unroll
            for (int q = 0; q < 4; q++) {
                float o = v[q] + bv;
                if (MODE == 1) o = o > 0.f ? o : __expf(o) - 1.f;
                size_t grow = (size_t)(row0 + wr * 64 + i * 16 + cr + q);
                C[grow * 512 + col] = o;
            }
        }
    }

    if (MODE == 2) {
        // this wave's 64 cols = head h, channels j*16+rl
        int h = (col0 >> 6) + wc;
        float as_v[4], ad_v[4];
        #pragma unroll
        for (int j = 0; j < 4; j++) {
            as_v[j] = att_s[h * 64 + j * 16 + rl];
            ad_v[j] = att_d[h * 64 + j * 16 + rl];
        }
        #pragma unroll
        for (int i = 0; i < 4; i++) {
            float ps[4] = {}, pd[4] = {};
            #pragma unroll
            for (int j = 0; j < 4; j++) {
                f32x4 v = acc[i][j];
                #pragma unroll
                for (int q = 0; q < 4; q++) {
                    ps[q] = fmaf(v[q], as_v[j], ps[q]);
                    pd[q] = fmaf(v[q], ad_v[j], pd[q]);
                }
            }
            #pragma unroll
            for (int off = 1; off < 16; off <<= 1) {
                #pragma unroll
                for (int q = 0; q < 4; q++) {
                    ps[q] += __shfl_xor(ps[q], off);
                    pd[q] += __shfl_xor(pd[q], off);
                }
            }
            if (rl == 0) {
                #pragma unroll
                for (int q = 0; q < 4; q++) {
                    size_t row = (size_t)(row0 + wr * 64 + i * 16 + cr + q);
                    as_[row * 8 + h] = ps[q];
                    ad_[row * 8 + h] = pd[q];
                }
            }
        }
    }
}

// ------------------------------ attention ---------------------------------
__global__ __launch_bounds__(256) void prep1_k(const float* __restrict__ W1,
                                               const float* __restrict__ as1,
                                               const float* __restrict__ ad1,
                                               float* __restrict__ ws1,
                                               float* __restrict__ wd1) {
    int k = blockIdx.x;
    int t = threadIdx.x;
    int h = t >> 5, lane = t & 31;
    float ps = 0.f, pd = 0.f;
    for (int c = lane; c < 512; c += 32) {
        float w = W1[(size_t)k * 4096 + h * 512 + c];
        ps += w * as1[h * 512 + c];
        pd += w * ad1[h * 512 + c];
    }
    #pragma unroll
    for (int off = 1; off < 32; off <<= 1) {
        ps += __shfl_xor(ps, off);
        pd += __shfl_xor(pd, off);
    }
    if (lane == 0) {
        ws1[k * 8 + h] = ps;
        wd1[k * 8 + h] = pd;
    }
}

// ---------------------------------------------------------------------------
// node0w: ONE WAVE PER NODE (4 nodes/block, zero barriers). Lane l: softmax
// head h=l>>3 (stripe l&7); aggregates channels 8l..8l+7 (same head).
// ---------------------------------------------------------------------------
__global__ __launch_bounds__(256) void node0w_k(
    const float* __restrict__ h0, const float* __restrict__ asrc,
    const float* __restrict__ adst, const int* __restrict__ indptr,
    const int* __restrict__ csr, const float* __restrict__ b0,
    const float* __restrict__ ws1, const float* __restrict__ wd1,
    float* __restrict__ hl0, float* __restrict__ as1, float* __restrict__ ad1) {
    int b = blockIdx.x;
    int wid = threadIdx.x >> 6;
    int l = threadIdx.x & 63;
    int d = (b & 7) * (NNODES / 8) + ((b >> 3) << 2) + wid;  // XCD-pinned
    int h = l >> 3;
    int e0 = indptr[d];
    int ne = indptr[d + 1] - e0;   // real edges; e==ne is the self loop
    float adh = adst[d * 8 + h];

    float m = -3.0e38f, z = 0.f;
    for (int e = (l & 7); e <= ne; e += 8) {
        int s = (e < ne) ? csr[e0 + e] : d;
        float v = asrc[s * 8 + h] + adh;
        v = v > 0.f ? v : 0.2f * v;
        float mn = fmaxf(m, v);
        z = z * __expf(m - mn) + __expf(v - mn);
        m = mn;
    }
    #pragma unroll
    for (int off = 1; off < 8; off <<= 1) {
        float mo = __shfl_xor(m, off);
        float zo = __shfl_xor(z, off);
        float mn = fmaxf(m, mo);
        z = z * __expf(m - mn) + zo * __expf(mo - mn);
        m = mn;
    }
    float rz = 1.0f / (z + 1e-16f);

    float acc[8] = {};
    for (int eb = 0; eb <= ne; eb += 8) {
        int idx = eb + (l & 7);
        int sv = (idx < ne) ? csr[e0 + idx] : d;
        int nn = min(8, ne + 1 - eb);
        #pragma unroll
        for (int i = 0; i < 8; i++) {
            if (i < nn) {
                int s = __shfl(sv, (l & 56) | i);
                float v = asrc[s * 8 + h] + adh;
                v = v > 0.f ? v : 0.2f * v;
                float a = __expf(v - m) * rz;
                const float4* hp = (const float4*)(h0 + ((size_t)s << 9) + 8 * l);
                float4 v0 = hp[0], v1 = hp[1];
                acc[0] = fmaf(a, v0.x, acc[0]);
                acc[1] = fmaf(a, v0.y, acc[1]);
                acc[2] = fmaf(a, v0.z, acc[2]);
                acc[3] = fmaf(a, v0.w, acc[3]);
                acc[4] = fmaf(a, v1.x, acc[4]);
                acc[5] = fmaf(a, v1.y, acc[5]);
                acc[6] = fmaf(a, v1.z, acc[6]);
                acc[7] = fmaf(a, v1.w, acc[7]);
            }
        }
    }

    const float4* b4 = (const float4*)(b0 + 8 * l);
    float4 bva = b4[0], bvb = b4[1];
    float o[8];
    o[0] = acc[0] + bva.x; o[1] = acc[1] + bva.y;
    o[2] = acc[2] + bva.z; o[3] = acc[3] + bva.w;
    o[4] = acc[4] + bvb.x; o[5] = acc[5] + bvb.y;
    o[6] = acc[6] + bvb.z; o[7] = acc[7] + bvb.w;
    #pragma unroll
    for (int k = 0; k < 8; k++) o[k] = o[k] > 0.f ? o[k] : __expf(o[k]) - 1.f;
    float* hr = hl0 + ((size_t)d << 9) + 8 * l;
    *(float4*)hr = make_float4(o[0], o[1], o[2], o[3]);
    *(float4*)(hr + 4) = make_float4(o[4], o[5], o[6], o[7]);

    float ps[8] = {}, pd[8] = {};
    #pragma unroll
    for (int k = 0; k < 8; k++) {
        const float4* w4 = (const float4*)(ws1 + (size_t)(8 * l + k) * 8);
        const float4* v4 = (const float4*)(wd1 + (size_t)(8 * l + k) * 8);
        float4 wa = w4[0], wb = w4[1];
        float4 va = v4[0], vb = v4[1];
        float ok = o[k];
        ps[0] = fmaf(ok, wa.x, ps[0]); ps[1] = fmaf(ok, wa.y, ps[1]);
        ps[2] = fmaf(ok, wa.z, ps[2]); ps[3] = fmaf(ok, wa.w, ps[3]);
        ps[4] = fmaf(ok, wb.x, ps[4]); ps[5] = fmaf(ok, wb.y, ps[5]);
        ps[6] = fmaf(ok, wb.z, ps[6]); ps[7] = fmaf(ok, wb.w, ps[7]);
        pd[0] = fmaf(ok, va.x, pd[0]); pd[1] = fmaf(ok, va.y, pd[1]);
        pd[2] = fmaf(ok, va.z, pd[2]); pd[3] = fmaf(ok, va.w, pd[3]);
        pd[4] = fmaf(ok, vb.x, pd[4]); pd[5] = fmaf(ok, vb.y, pd[5]);
        pd[6] = fmaf(ok, vb.z, pd[6]); pd[7] = fmaf(ok, vb.w, pd[7]);
    }
    #pragma unroll
    for (int off = 1; off < 64; off <<= 1) {
        #pragma unroll
        for (int j = 0; j < 8; j++) {
            ps[j] += __shfl_xor(ps[j], off);
            pd[j] += __shfl_xor(pd[j], off);
        }
    }
    #pragma unroll
    for (int j = 0; j < 8; j++) {
        if (l == j) as1[(size_t)d * 8 + j] = ps[j];
        if (l == 8 + j) ad1[(size_t)d * 8 + j] = pd[j];
    }
}

// ---------------------------------------------------------------------------
// node1w: ONE WAVE PER NODE. Lane l: softmax head hme=l&7 (stripe l>>3);
// aggregates acc[8 heads][8 ch] for channels 8l..8l+7. bf16 single plane out.
// ---------------------------------------------------------------------------
__global__ __launch_bounds__(256) void node1w_k(
    const float* __restrict__ hl0, const float* __restrict__ asrc,
    const float* __restrict__ adst, const int* __restrict__ indptr,
    const int* __restrict__ csr, u16* __restrict__ aggh, int base, int ch) {
    int b = blockIdx.x;
    int wid = threadIdx.x >> 6;
    int l = threadIdx.x & 63;
    int dl = (b & 7) * (ch >> 3) + ((b >> 3) << 2) + wid;
    int d = base + dl;
    int hme = l & 7;
    int e0 = indptr[d];
    int ne = indptr[d + 1] - e0;
    float adh = adst[d * 8 + hme];

    float m = -3.0e38f, z = 0.f;
    for (int e = (l >> 3); e <= ne; e += 8) {
        int s = (e < ne) ? csr[e0 + e] : d;
        float v = asrc[s * 8 + hme] + adh;
        v = v > 0.f ? v : 0.2f * v;
        float mn = fmaxf(m, v);
        z = z * __expf(m - mn) + __expf(v - mn);
        m = mn;
    }
    #pragma unroll
    for (int off = 8; off < 64; off <<= 1) {
        float mo = __shfl_xor(m, off);
        float zo = __shfl_xor(z, off);
        float mn = fmaxf(m, mo);
        z = z * __expf(m - mn) + zo * __expf(mo - mn);
        m = mn;
    }
    float rz = 1.0f / (z + 1e-16f);

    float acc[8][8] = {};
    for (int eb = 0; eb <= ne; eb += 8) {
        int idx = eb + (l & 7);
        int sv = (idx < ne) ? csr[e0 + idx] : d;
        int nn = min(8, ne + 1 - eb);
        #pragma unroll
        for (int i = 0; i < 8; i++) {
            if (i < nn) {
                int s = __shfl(sv, (l & 56) | i);
                float v = asrc[s * 8 + hme] + adh;
                v = v > 0.f ? v : 0.2f * v;
                float amine = __expf(v - m) * rz;
                float a[8];
                #pragma unroll
                for (int hh = 0; hh < 8; hh++)
                    a[hh] = __shfl(amine, (l & 56) | hh);
                const float4* hp = (const float4*)(hl0 + ((size_t)s << 9) + 8 * l);
                float4 v0 = hp[0], v1 = hp[1];
                #pragma unroll
                for (int hh = 0; hh < 8; hh++) {
                    acc[hh][0] = fmaf(a[hh], v0.x, acc[hh][0]);
                    acc[hh][1] = fmaf(a[hh], v0.y, acc[hh][1]);
                    acc[hh][2] = fmaf(a[hh], v0.z, acc[hh][2]);
                    acc[hh][3] = fmaf(a[hh], v0.w, acc[hh][3]);
                    acc[hh][4] = fmaf(a[hh], v1.x, acc[hh][4]);
                    acc[hh][5] = fmaf(a[hh], v1.y, acc[hh][5]);
                    acc[hh][6] = fmaf(a[hh], v1.z, acc[hh][6]);
                    acc[hh][7] = fmaf(a[hh], v1.w, acc[hh][7]);
                }
            }
        }
    }

    #pragma unroll
    for (int hh = 0; hh < 8; hh++) {
        ushort4 qa = make_ushort4(f2bf(acc[hh][0]), f2bf(acc[hh][1]),
                                  f2bf(acc[hh][2]), f2bf(acc[hh][3]));
        ushort4 qb = make_ushort4(f2bf(acc[hh][4]), f2bf(acc[hh][5]),
                                  f2bf(acc[hh][6]), f2bf(acc[hh][7]));
        size_t ob = (size_t)dl * 4096 + hh * 512 + 8 * l;
        *(ushort4*)(aggh + ob) = qa;
        *(ushort4*)(aggh + ob + 4) = qb;
    }
}

// ------------------------------- launcher ----------------------------------
extern "C" void kernel_launch(void* const* d_in, const int* in_sizes, int n_in,
                              void* d_out, int out_size, void* d_ws, size_t ws_size,
                              hipStream_t stream) {
    const float* x = (const float*)d_in[0];
    const int* ei = (const int*)d_in[1];
    const float* W0 = (const float*)d_in[2];
    const float* at_s0 = (const float*)d_in[3];
    const float* at_d0 = (const float*)d_in[4];
    const float* b0 = (const float*)d_in[5];
    const float* W1 = (const float*)d_in[6];
    const float* at_s1 = (const float*)d_in[7];
    const float* at_d1 = (const float*)d_in[8];
    const float* b1 = (const float*)d_in[9];
    float* out = (float*)d_out;

    const int N = NNODES;
    const int E = in_sizes[1] / 2;
    const int* esrc = ei;
    const int* edst = ei + E;

    char* p = (char*)d_ws;
    auto carve = [&](size_t bytes) -> void* {
        void* r = (void*)p;
        p += ((bytes + 255) & ~(size_t)255);
        return r;
    };
    float* h0 = (float*)carve((size_t)N * 512 * 4);
    float* hl0 = (float*)carve((size_t)N * 512 * 4);
    float* as0 = (float*)carve((size_t)N * 8 * 4);
    float* ad0 = (float*)carve((size_t)N * 8 * 4);
    float* as1 = (float*)carve((size_t)N * 8 * 4);
    float* ad1 = (float*)carve((size_t)N * 8 * 4);
    int* deg = (int*)carve((size_t)N * 4);
    int* indptr = (int*)carve((size_t)(N + 1) * 4);
    int* cursor = (int*)carve((size_t)N * 4);
    int* csr = (int*)carve((size_t)E * 4);
    float* ws1 = (float*)carve(512 * 8 * 4);
    float* wd1 = (float*)carve(512 * 8 * 4);
    u16* xh = (u16*)carve((size_t)N * 512 * 2);
    u16* xl = (u16*)carve((size_t)N * 512 * 2);
    u16* W0h = (u16*)carve((size_t)512 * 512 * 2);
    u16* W0l = (u16*)carve((size_t)512 * 512 * 2);
    u16* B1h = (u16*)carve((size_t)512 * 4096 * 2);
    u16* B1l = (u16*)carve((size_t)512 * 4096 * 2);
    size_t used = (size_t)(p - (char*)d_ws);

    int CH = 1024;
    const int cands[5] = {16384, 8192, 4096, 2048, 1024};
    for (int ci = 0; ci < 5; ci++) {
        if (ws_size >= used + (size_t)cands[ci] * 8192 + 512) {
            CH = cands[ci];
            break;
        }
    }
    u16* aggh = (u16*)carve((size_t)CH * 4096 * 2);

    // CSR build
    zero_k<<<(N + 255) / 256, 256, 0, stream>>>(deg, N);
    count_k<<<(E + 255) / 256, 256, 0, stream>>>(edst, E, deg);
    scan_k<<<1, 1024, 0, stream>>>(deg, indptr, cursor, N);
    scatter_k<<<(E + 255) / 256, 256, 0, stream>>>(esrc, edst, E, cursor, csr);

    // operand prep (split bf16) + folded layer-1 attention weights
    prepx_k<<<(N * 512 / 4 + 255) / 256, 256, 0, stream>>>(x, xh, xl);
    prepW0t_k<<<64, 256, 0, stream>>>(W0, W0h, W0l);
    prepW1t_k<<<512, 256, 0, stream>>>(W1, B1h, B1l);
    prep1_k<<<512, 256, 0, stream>>>(W1, at_s1, at_d1, ws1, wd1);

    // Layer 0: GEMM with fused alpha0 epilogue
    mgemm_k<2, 3><<<dim3(4, N / 128), 256, 0, stream>>>(
        xh, xl, W0h, W0l, h0, 512, nullptr, at_s0, at_d0, as0, ad0);
    node0w_k<<<N / 4, 256, 0, stream>>>(h0, as0, ad0, indptr, csr, b0, ws1, wd1,
                                        hl0, as1, ad1);

    // Layer 1: bf16 aggregate per chunk, 2-term fused GEMM (+b1, ELU)
    for (int base = 0; base < N; base += CH) {
        node1w_k<<<CH / 4, 256, 0, stream>>>(hl0, as1, ad1, indptr, csr, aggh,
                                             base, CH);
        mgemm_k<1, 2><<<dim3(4, CH / 128), 256, 0, stream>>>(
            aggh, nullptr, B1h, B1l, out + (size_t)base * 512, 4096, b1,
            nullptr, nullptr, nullptr, nullptr);
    }
}

// Round 14
// 484.592 us; speedup vs baseline: 1.1187x; 1.0579x over previous
//
#include <hip/hip_runtime.h>
#include <hip/hip_bf16.h>

// ---------------------------------------------------------------------------
// GAT 2-layer, N=16384 nodes, D=512, H=8, E=524288 edges (+self loops)
// GEMMs: split-bf16 MFMA 16x16x32, BM=BN=128, XOR-swizzled global_load_lds.
// GEMM0 epilogue fuses alpha0 and stores h0 as bf16. Node features (h0, hl0)
// are bf16 (halved gather traffic); attention scores computed in f32 pre-
// rounding. One wave per node; alpha1 fused into node0.
// ---------------------------------------------------------------------------

#define NNODES 16384

typedef unsigned short u16;
typedef unsigned int u32;
typedef __attribute__((ext_vector_type(8))) __bf16 bf16x8;
typedef __attribute__((ext_vector_type(4))) float f32x4;

__device__ __forceinline__ u16 f2bf(float v) {
    u32 u = __builtin_bit_cast(u32, v);
    u32 r = (u + 0x7fffu + ((u >> 16) & 1u)) >> 16;
    return (u16)r;
}
__device__ __forceinline__ float bf2f(u16 s) {
    u32 u = ((u32)s) << 16;
    return __builtin_bit_cast(float, u);
}
__device__ __forceinline__ float bflo(u32 u) {
    return __builtin_bit_cast(float, u << 16);
}
__device__ __forceinline__ float bfhi(u32 u) {
    return __builtin_bit_cast(float, u & 0xffff0000u);
}
__device__ __forceinline__ void split2(float v, u16& h, u16& l) {
    h = f2bf(v);
    l = f2bf(v - bf2f(h));
}
__device__ __forceinline__ u32 pack2(float a, float b) {
    return (u32)f2bf(a) | ((u32)f2bf(b) << 16);
}

// async global->LDS, 16B per lane
__device__ __forceinline__ void gload_lds16(const u16* g, u16* l) {
    __builtin_amdgcn_global_load_lds(
        (__attribute__((address_space(1))) void*)(void*)(g),
        (__attribute__((address_space(3))) void*)(void*)(l), 16, 0, 0);
}

// ------------------------------ CSR build ---------------------------------
__global__ void zero_k(int* p, int n) {
    int i = blockIdx.x * 256 + threadIdx.x;
    if (i < n) p[i] = 0;
}

__global__ void count_k(const int* __restrict__ dst, int E, int* __restrict__ deg) {
    int i = blockIdx.x * 256 + threadIdx.x;
    if (i < E) atomicAdd(&deg[dst[i]], 1);
}

__global__ __launch_bounds__(1024) void scan_k(const int* __restrict__ deg,
                                               int* __restrict__ indptr,
                                               int* __restrict__ cursor, int n) {
    __shared__ int sums[1024];
    int t = threadIdx.x;
    int base = t * 16;
    int local[16];
    int s = 0;
    #pragma unroll
    for (int i = 0; i < 16; i++) { local[i] = s; s += deg[base + i]; }
    sums[t] = s;
    __syncthreads();
    for (int off = 1; off < 1024; off <<= 1) {
        int v = (t >= off) ? sums[t - off] : 0;
        __syncthreads();
        sums[t] += v;
        __syncthreads();
    }
    int base_sum = (t == 0) ? 0 : sums[t - 1];
    #pragma unroll
    for (int i = 0; i < 16; i++) {
        int v = base_sum + local[i];
        indptr[base + i] = v;
        cursor[base + i] = v;
    }
    if (t == 1023) indptr[n] = base_sum + s;
}

__global__ void scatter_k(const int* __restrict__ src, const int* __restrict__ dst,
                          int E, int* __restrict__ cursor, int* __restrict__ csr) {
    int i = blockIdx.x * 256 + threadIdx.x;
    if (i < E) {
        int pos = atomicAdd(&cursor[dst[i]], 1);
        csr[pos] = src[i];
    }
}

// ------------------------- split-bf16 prep kernels -------------------------
__global__ void prepx_k(const float* __restrict__ x, u16* __restrict__ xh,
                        u16* __restrict__ xl) {
    int idx = blockIdx.x * 256 + threadIdx.x;
    int e = idx << 2;
    int n = e >> 9, k = e & 511;
    int g = n >> 10, s = n & 1023;
    float4 v = *(const float4*)(x + ((size_t)(s * 16 + g) << 9) + k);
    u16 h[4], l[4];
    split2(v.x, h[0], l[0]);
    split2(v.y, h[1], l[1]);
    split2(v.z, h[2], l[2]);
    split2(v.w, h[3], l[3]);
    size_t o = ((size_t)n << 9) + k;
    *(ushort4*)(xh + o) = make_ushort4(h[0], h[1], h[2], h[3]);
    *(ushort4*)(xl + o) = make_ushort4(l[0], l[1], l[2], l[3]);
}

// W0t[n][k] = W0[k][n], tiled 64x64 transpose through LDS
__global__ __launch_bounds__(256) void prepW0t_k(const float* __restrict__ W0,
                                                 u16* __restrict__ Wh,
                                                 u16* __restrict__ Wl) {
    __shared__ u32 tile[64][65];
    int b = blockIdx.x;
    int kt = (b >> 3) * 64, nt = (b & 7) * 64;
    int t = threadIdx.x;
    #pragma unroll
    for (int i = 0; i < 16; i++) {
        int idx = i * 256 + t;
        int r = idx >> 6, c = idx & 63;
        float v = W0[(size_t)(kt + r) * 512 + nt + c];
        u16 h, l;
        split2(v, h, l);
        tile[r][c] = ((u32)h << 16) | l;
    }
    __syncthreads();
    #pragma unroll
    for (int i = 0; i < 8; i++) {
        int idx = i * 256 + t;
        int r = idx >> 5, c2 = (idx & 31) * 2;
        u32 p0 = tile[c2][r], p1 = tile[c2 + 1][r];
        size_t o = (size_t)(nt + r) * 512 + kt + c2;
        *(ushort2*)(Wh + o) = make_ushort2((u16)(p0 >> 16), (u16)(p1 >> 16));
        *(ushort2*)(Wl + o) = make_ushort2((u16)(p0 & 0xffff), (u16)(p1 & 0xffff));
    }
}

// B1t[c][h*512+k] = W1[k][h*512+c]/8, per-head tiled 64x64 transpose
__global__ __launch_bounds__(256) void prepW1t_k(const float* __restrict__ W1,
                                                 u16* __restrict__ Bh,
                                                 u16* __restrict__ Bl) {
    __shared__ u32 tile[64][65];
    int b = blockIdx.x;
    int hh = b >> 6;
    int rem = b & 63;
    int kt = (rem >> 3) * 64, ct = (rem & 7) * 64;
    int t = threadIdx.x;
    #pragma unroll
    for (int i = 0; i < 16; i++) {
        int idx = i * 256 + t;
        int r = idx >> 6, c = idx & 63;
        float v = W1[(size_t)(kt + r) * 4096 + hh * 512 + ct + c] * 0.125f;
        u16 h, l;
        split2(v, h, l);
        tile[r][c] = ((u32)h << 16) | l;
    }
    __syncthreads();
    #pragma unroll
    for (int i = 0; i < 8; i++) {
        int idx = i * 256 + t;
        int r = idx >> 5, c2 = (idx & 31) * 2;
        u32 p0 = tile[c2][r], p1 = tile[c2 + 1][r];
        size_t o = (size_t)(ct + r) * 4096 + hh * 512 + kt + c2;
        *(ushort2*)(Bh + o) = make_ushort2((u16)(p0 >> 16), (u16)(p1 >> 16));
        *(ushort2*)(Bl + o) = make_ushort2((u16)(p0 & 0xffff), (u16)(p1 & 0xffff));
    }
}

// ---------------------------------------------------------------------------
// Split-bf16 MFMA GEMM: C[M,512] = A[M,K] @ Bt[512,K]^T  (round-10 structure)
// MODE 1: f32 out, +bias, ELU. MODE 2: bf16 out (u16* C) + fused alpha0.
// ---------------------------------------------------------------------------
template <int MODE, int TERMS>
__global__ __launch_bounds__(256) void mgemm_k(
    const u16* __restrict__ Ah, const u16* __restrict__ Al,
    const u16* __restrict__ Bh, const u16* __restrict__ Bl,
    void* __restrict__ Cv, int K, const float* __restrict__ bias,
    const float* __restrict__ att_s, const float* __restrict__ att_d,
    float* __restrict__ as_, float* __restrict__ ad_) {
    constexpr int pAl = 4096;
    constexpr int pBh = (TERMS == 3) ? 8192 : 4096;
    constexpr int pBl = (TERMS == 3) ? 12288 : 8192;
    constexpr int NSEG = (TERMS == 3) ? 8 : 6;
    __shared__ u16 smem[(TERMS == 3) ? 16384 : 12288];

    int t = threadIdx.x;
    int lane = t & 63, w = t >> 6;
    int wr = w >> 1, wc = w & 1;
    int row0 = blockIdx.y * 128, col0 = blockIdx.x * 128;

    f32x4 acc[4][4];
    #pragma unroll
    for (int i = 0; i < 4; i++)
        #pragma unroll
        for (int j = 0; j < 4; j++) acc[i][j] = (f32x4){0.f, 0.f, 0.f, 0.f};

    int srow = lane >> 2;
    int sl4 = lane & 3;
    const u16* gp[NSEG];
    u16* lp[NSEG];
    #pragma unroll
    for (int ii = 0; ii < NSEG; ii++) {
        int s = w * NSEG + ii;
        int pl = s >> 3, seg = s & 7;
        const u16* gb;
        int g0;
        if (TERMS == 3) {
            gb = (pl == 0) ? Ah : (pl == 1) ? Al : (pl == 2) ? Bh : Bl;
            g0 = (pl < 2) ? row0 : col0;
        } else {
            gb = (pl == 0) ? Ah : (pl == 1) ? Bh : Bl;
            g0 = (pl == 0) ? row0 : col0;
        }
        int row = seg * 16 + srow;
        int slot = sl4 ^ ((row >> 1) & 3);
        gp[ii] = gb + (size_t)(g0 + row) * K + slot * 8;
        lp[ii] = smem + pl * 4096 + seg * 512;
    }

    int rl = lane & 15, kb = lane >> 4;

    for (int k0 = 0; k0 < K; k0 += 32) {
        #pragma unroll
        for (int ii = 0; ii < NSEG; ii++) gload_lds16(gp[ii] + k0, lp[ii]);
        __syncthreads();

        bf16x8 afh[4], afl_[4], bfh[4], bfl[4];
        #pragma unroll
        for (int f = 0; f < 4; f++) {
            int r = wr * 64 + f * 16 + rl;
            int off = r * 32 + ((kb ^ ((r >> 1) & 3)) << 3);
            afh[f] = *(const bf16x8*)(smem + off);
            if (TERMS == 3) afl_[f] = *(const bf16x8*)(smem + pAl + off);
        }
        #pragma unroll
        for (int j = 0; j < 4; j++) {
            int r = wc * 64 + j * 16 + rl;
            int off = r * 32 + ((kb ^ ((r >> 1) & 3)) << 3);
            bfh[j] = *(const bf16x8*)(smem + pBh + off);
            bfl[j] = *(const bf16x8*)(smem + pBl + off);
        }
        #pragma unroll
        for (int i = 0; i < 4; i++)
            #pragma unroll
            for (int j = 0; j < 4; j++) {
                if (TERMS == 3)
                    acc[i][j] = __builtin_amdgcn_mfma_f32_16x16x32_bf16(
                        afl_[i], bfh[j], acc[i][j], 0, 0, 0);
                acc[i][j] = __builtin_amdgcn_mfma_f32_16x16x32_bf16(
                    afh[i], bfl[j], acc[i][j], 0, 0, 0);
                acc[i][j] = __builtin_amdgcn_mfma_f32_16x16x32_bf16(
                    afh[i], bfh[j], acc[i][j], 0, 0, 0);
            }
        __syncthreads();
    }

    // C/D layout 16x16: col = lane&15, row = (lane>>4)*4 + q
    int cr = kb * 4;
    #pragma unroll
    for (int i = 0; i < 4; i++) {
        #pragma unroll
        for (int j = 0; j < 4; j++) {
            int col = col0 + wc * 64 + j * 16 + rl;
            float bv = (MODE == 1) ? bias[col] : 0.f;
            f32x4 v = acc[i][j];
            #pragma unroll
            for (int q = 0; q < 4; q++) {
                float o = v[q] + bv;
                size_t grow = (size_t)(row0 + wr * 64 + i * 16 + cr + q);
                if (MODE == 1) {
                    o = o > 0.f ? o : __expf(o) - 1.f;
                    ((float*)Cv)[grow * 512 + col] = o;
                } else {
                    ((u16*)Cv)[grow * 512 + col] = f2bf(o);
                }
            }
        }
    }

    if (MODE == 2) {
        // this wave's 64 cols = head h, channels j*16+rl (f32-accurate alpha0)
        int h = (col0 >> 6) + wc;
        float as_v[4], ad_v[4];
        #pragma unroll
        for (int j = 0; j < 4; j++) {
            as_v[j] = att_s[h * 64 + j * 16 + rl];
            ad_v[j] = att_d[h * 64 + j * 16 + rl];
        }
        #pragma unroll
        for (int i = 0; i < 4; i++) {
            float ps[4] = {}, pd[4] = {};
            #pragma unroll
            for (int j = 0; j < 4; j++) {
                f32x4 v = acc[i][j];
                #pragma unroll
                for (int q = 0; q < 4; q++) {
                    ps[q] = fmaf(v[q], as_v[j], ps[q]);
                    pd[q] = fmaf(v[q], ad_v[j], pd[q]);
                }
            }
            #pragma unroll
            for (int off = 1; off < 16; off <<= 1) {
                #pragma unroll
                for (int q = 0; q < 4; q++) {
                    ps[q] += __shfl_xor(ps[q], off);
                    pd[q] += __shfl_xor(pd[q], off);
                }
            }
            if (rl == 0) {
                #pragma unroll
                for (int q = 0; q < 4; q++) {
                    size_t row = (size_t)(row0 + wr * 64 + i * 16 + cr + q);
                    as_[row * 8 + h] = ps[q];
                    ad_[row * 8 + h] = pd[q];
                }
            }
        }
    }
}

// ------------------------------ attention ---------------------------------
__global__ __launch_bounds__(256) void prep1_k(const float* __restrict__ W1,
                                               const float* __restrict__ as1,
                                               const float* __restrict__ ad1,
                                               float* __restrict__ ws1,
                                               float* __restrict__ wd1) {
    int k = blockIdx.x;
    int t = threadIdx.x;
    int h = t >> 5, lane = t & 31;
    float ps = 0.f, pd = 0.f;
    for (int c = lane; c < 512; c += 32) {
        float w = W1[(size_t)k * 4096 + h * 512 + c];
        ps += w * as1[h * 512 + c];
        pd += w * ad1[h * 512 + c];
    }
    #pragma unroll
    for (int off = 1; off < 32; off <<= 1) {
        ps += __shfl_xor(ps, off);
        pd += __shfl_xor(pd, off);
    }
    if (lane == 0) {
        ws1[k * 8 + h] = ps;
        wd1[k * 8 + h] = pd;
    }
}

// ---------------------------------------------------------------------------
// node0w: ONE WAVE PER NODE (4 nodes/block, zero barriers). h0 is bf16.
// Lane l: softmax head h=l>>3 (stripe l&7); aggregates channels 8l..8l+7.
// hl0 stored bf16; fused alpha1 from f32 registers.
// ---------------------------------------------------------------------------
__global__ __launch_bounds__(256) void node0w_k(
    const u16* __restrict__ h0b, const float* __restrict__ asrc,
    const float* __restrict__ adst, const int* __restrict__ indptr,
    const int* __restrict__ csr, const float* __restrict__ b0,
    const float* __restrict__ ws1, const float* __restrict__ wd1,
    u16* __restrict__ hl0b, float* __restrict__ as1, float* __restrict__ ad1) {
    int b = blockIdx.x;
    int wid = threadIdx.x >> 6;
    int l = threadIdx.x & 63;
    int d = (b & 7) * (NNODES / 8) + ((b >> 3) << 2) + wid;  // XCD-pinned
    int h = l >> 3;
    int e0 = indptr[d];
    int ne = indptr[d + 1] - e0;   // real edges; e==ne is the self loop
    float adh = adst[d * 8 + h];

    float m = -3.0e38f, z = 0.f;
    for (int e = (l & 7); e <= ne; e += 8) {
        int s = (e < ne) ? csr[e0 + e] : d;
        float v = asrc[s * 8 + h] + adh;
        v = v > 0.f ? v : 0.2f * v;
        float mn = fmaxf(m, v);
        z = z * __expf(m - mn) + __expf(v - mn);
        m = mn;
    }
    #pragma unroll
    for (int off = 1; off < 8; off <<= 1) {
        float mo = __shfl_xor(m, off);
        float zo = __shfl_xor(z, off);
        float mn = fmaxf(m, mo);
        z = z * __expf(m - mn) + zo * __expf(mo - mn);
        m = mn;
    }
    float rz = 1.0f / (z + 1e-16f);

    float acc[8] = {};
    for (int eb = 0; eb <= ne; eb += 8) {
        int idx = eb + (l & 7);
        int sv = (idx < ne) ? csr[e0 + idx] : d;
        int nn = min(8, ne + 1 - eb);
        #pragma unroll
        for (int i = 0; i < 8; i++) {
            if (i < nn) {
                int s = __shfl(sv, (l & 56) | i);
                float v = asrc[s * 8 + h] + adh;
                v = v > 0.f ? v : 0.2f * v;
                float a = __expf(v - m) * rz;
                int4 pv = *(const int4*)(h0b + ((size_t)s << 9) + 8 * l);
                acc[0] = fmaf(a, bflo(pv.x), acc[0]);
                acc[1] = fmaf(a, bfhi(pv.x), acc[1]);
                acc[2] = fmaf(a, bflo(pv.y), acc[2]);
                acc[3] = fmaf(a, bfhi(pv.y), acc[3]);
                acc[4] = fmaf(a, bflo(pv.z), acc[4]);
                acc[5] = fmaf(a, bfhi(pv.z), acc[5]);
                acc[6] = fmaf(a, bflo(pv.w), acc[6]);
                acc[7] = fmaf(a, bfhi(pv.w), acc[7]);
            }
        }
    }

    const float4* b4 = (const float4*)(b0 + 8 * l);
    float4 bva = b4[0], bvb = b4[1];
    float o[8];
    o[0] = acc[0] + bva.x; o[1] = acc[1] + bva.y;
    o[2] = acc[2] + bva.z; o[3] = acc[3] + bva.w;
    o[4] = acc[4] + bvb.x; o[5] = acc[5] + bvb.y;
    o[6] = acc[6] + bvb.z; o[7] = acc[7] + bvb.w;
    #pragma unroll
    for (int k = 0; k < 8; k++) o[k] = o[k] > 0.f ? o[k] : __expf(o[k]) - 1.f;
    int4 hv;
    hv.x = (int)pack2(o[0], o[1]);
    hv.y = (int)pack2(o[2], o[3]);
    hv.z = (int)pack2(o[4], o[5]);
    hv.w = (int)pack2(o[6], o[7]);
    *(int4*)(hl0b + ((size_t)d << 9) + 8 * l) = hv;

    float ps[8] = {}, pd[8] = {};
    #pragma unroll
    for (int k = 0; k < 8; k++) {
        const float4* w4 = (const float4*)(ws1 + (size_t)(8 * l + k) * 8);
        const float4* v4 = (const float4*)(wd1 + (size_t)(8 * l + k) * 8);
        float4 wa = w4[0], wb = w4[1];
        float4 va = v4[0], vb = v4[1];
        float ok = o[k];
        ps[0] = fmaf(ok, wa.x, ps[0]); ps[1] = fmaf(ok, wa.y, ps[1]);
        ps[2] = fmaf(ok, wa.z, ps[2]); ps[3] = fmaf(ok, wa.w, ps[3]);
        ps[4] = fmaf(ok, wb.x, ps[4]); ps[5] = fmaf(ok, wb.y, ps[5]);
        ps[6] = fmaf(ok, wb.z, ps[6]); ps[7] = fmaf(ok, wb.w, ps[7]);
        pd[0] = fmaf(ok, va.x, pd[0]); pd[1] = fmaf(ok, va.y, pd[1]);
        pd[2] = fmaf(ok, va.z, pd[2]); pd[3] = fmaf(ok, va.w, pd[3]);
        pd[4] = fmaf(ok, vb.x, pd[4]); pd[5] = fmaf(ok, vb.y, pd[5]);
        pd[6] = fmaf(ok, vb.z, pd[6]); pd[7] = fmaf(ok, vb.w, pd[7]);
    }
    #pragma unroll
    for (int off = 1; off < 64; off <<= 1) {
        #pragma unroll
        for (int j = 0; j < 8; j++) {
            ps[j] += __shfl_xor(ps[j], off);
            pd[j] += __shfl_xor(pd[j], off);
        }
    }
    #pragma unroll
    for (int j = 0; j < 8; j++) {
        if (l == j) as1[(size_t)d * 8 + j] = ps[j];
        if (l == 8 + j) ad1[(size_t)d * 8 + j] = pd[j];
    }
}

// ---------------------------------------------------------------------------
// node1w: ONE WAVE PER NODE. hl0 is bf16. Lane l: softmax head hme=l&7
// (stripe l>>3); aggregates acc[8 heads][8 ch] for channels 8l..8l+7.
// ---------------------------------------------------------------------------
__global__ __launch_bounds__(256) void node1w_k(
    const u16* __restrict__ hl0b, const float* __restrict__ asrc,
    const float* __restrict__ adst, const int* __restrict__ indptr,
    const int* __restrict__ csr, u16* __restrict__ aggh, int base, int ch) {
    int b = blockIdx.x;
    int wid = threadIdx.x >> 6;
    int l = threadIdx.x & 63;
    int dl = (b & 7) * (ch >> 3) + ((b >> 3) << 2) + wid;
    int d = base + dl;
    int hme = l & 7;
    int e0 = indptr[d];
    int ne = indptr[d + 1] - e0;
    float adh = adst[d * 8 + hme];

    float m = -3.0e38f, z = 0.f;
    for (int e = (l >> 3); e <= ne; e += 8) {
        int s = (e < ne) ? csr[e0 + e] : d;
        float v = asrc[s * 8 + hme] + adh;
        v = v > 0.f ? v : 0.2f * v;
        float mn = fmaxf(m, v);
        z = z * __expf(m - mn) + __expf(v - mn);
        m = mn;
    }
    #pragma unroll
    for (int off = 8; off < 64; off <<= 1) {
        float mo = __shfl_xor(m, off);
        float zo = __shfl_xor(z, off);
        float mn = fmaxf(m, mo);
        z = z * __expf(m - mn) + zo * __expf(mo - mn);
        m = mn;
    }
    float rz = 1.0f / (z + 1e-16f);

    float acc[8][8] = {};
    for (int eb = 0; eb <= ne; eb += 8) {
        int idx = eb + (l & 7);
        int sv = (idx < ne) ? csr[e0 + idx] : d;
        int nn = min(8, ne + 1 - eb);
        #pragma unroll
        for (int i = 0; i < 8; i++) {
            if (i < nn) {
                int s = __shfl(sv, (l & 56) | i);
                float v = asrc[s * 8 + hme] + adh;
                v = v > 0.f ? v : 0.2f * v;
                float amine = __expf(v - m) * rz;
                float a[8];
                #pragma unroll
                for (int hh = 0; hh < 8; hh++)
                    a[hh] = __shfl(amine, (l & 56) | hh);
                int4 pv = *(const int4*)(hl0b + ((size_t)s << 9) + 8 * l);
                float f0 = bflo(pv.x), f1 = bfhi(pv.x);
                float f2 = bflo(pv.y), f3 = bfhi(pv.y);
                float f4 = bflo(pv.z), f5 = bfhi(pv.z);
                float f6 = bflo(pv.w), f7 = bfhi(pv.w);
                #pragma unroll
                for (int hh = 0; hh < 8; hh++) {
                    acc[hh][0] = fmaf(a[hh], f0, acc[hh][0]);
                    acc[hh][1] = fmaf(a[hh], f1, acc[hh][1]);
                    acc[hh][2] = fmaf(a[hh], f2, acc[hh][2]);
                    acc[hh][3] = fmaf(a[hh], f3, acc[hh][3]);
                    acc[hh][4] = fmaf(a[hh], f4, acc[hh][4]);
                    acc[hh][5] = fmaf(a[hh], f5, acc[hh][5]);
                    acc[hh][6] = fmaf(a[hh], f6, acc[hh][6]);
                    acc[hh][7] = fmaf(a[hh], f7, acc[hh][7]);
                }
            }
        }
    }

    #pragma unroll
    for (int hh = 0; hh < 8; hh++) {
        ushort4 qa = make_ushort4(f2bf(acc[hh][0]), f2bf(acc[hh][1]),
                                  f2bf(acc[hh][2]), f2bf(acc[hh][3]));
        ushort4 qb = make_ushort4(f2bf(acc[hh][4]), f2bf(acc[hh][5]),
                                  f2bf(acc[hh][6]), f2bf(acc[hh][7]));
        size_t ob = (size_t)dl * 4096 + hh * 512 + 8 * l;
        *(ushort4*)(aggh + ob) = qa;
        *(ushort4*)(aggh + ob + 4) = qb;
    }
}

// ------------------------------- launcher ----------------------------------
extern "C" void kernel_launch(void* const* d_in, const int* in_sizes, int n_in,
                              void* d_out, int out_size, void* d_ws, size_t ws_size,
                              hipStream_t stream) {
    const float* x = (const float*)d_in[0];
    const int* ei = (const int*)d_in[1];
    const float* W0 = (const float*)d_in[2];
    const float* at_s0 = (const float*)d_in[3];
    const float* at_d0 = (const float*)d_in[4];
    const float* b0 = (const float*)d_in[5];
    const float* W1 = (const float*)d_in[6];
    const float* at_s1 = (const float*)d_in[7];
    const float* at_d1 = (const float*)d_in[8];
    const float* b1 = (const float*)d_in[9];
    float* out = (float*)d_out;

    const int N = NNODES;
    const int E = in_sizes[1] / 2;
    const int* esrc = ei;
    const int* edst = ei + E;

    char* p = (char*)d_ws;
    auto carve = [&](size_t bytes) -> void* {
        void* r = (void*)p;
        p += ((bytes + 255) & ~(size_t)255);
        return r;
    };
    u16* h0b = (u16*)carve((size_t)N * 512 * 2);
    u16* hl0b = (u16*)carve((size_t)N * 512 * 2);
    float* as0 = (float*)carve((size_t)N * 8 * 4);
    float* ad0 = (float*)carve((size_t)N * 8 * 4);
    float* as1 = (float*)carve((size_t)N * 8 * 4);
    float* ad1 = (float*)carve((size_t)N * 8 * 4);
    int* deg = (int*)carve((size_t)N * 4);
    int* indptr = (int*)carve((size_t)(N + 1) * 4);
    int* cursor = (int*)carve((size_t)N * 4);
    int* csr = (int*)carve((size_t)E * 4);
    float* ws1 = (float*)carve(512 * 8 * 4);
    float* wd1 = (float*)carve(512 * 8 * 4);
    u16* xh = (u16*)carve((size_t)N * 512 * 2);
    u16* xl = (u16*)carve((size_t)N * 512 * 2);
    u16* W0h = (u16*)carve((size_t)512 * 512 * 2);
    u16* W0l = (u16*)carve((size_t)512 * 512 * 2);
    u16* B1h = (u16*)carve((size_t)512 * 4096 * 2);
    u16* B1l = (u16*)carve((size_t)512 * 4096 * 2);
    size_t used = (size_t)(p - (char*)d_ws);

    int CH = 1024;
    const int cands[5] = {16384, 8192, 4096, 2048, 1024};
    for (int ci = 0; ci < 5; ci++) {
        if (ws_size >= used + (size_t)cands[ci] * 8192 + 512) {
            CH = cands[ci];
            break;
        }
    }
    u16* aggh = (u16*)carve((size_t)CH * 4096 * 2);

    // CSR build
    zero_k<<<(N + 255) / 256, 256, 0, stream>>>(deg, N);
    count_k<<<(E + 255) / 256, 256, 0, stream>>>(edst, E, deg);
    scan_k<<<1, 1024, 0, stream>>>(deg, indptr, cursor, N);
    scatter_k<<<(E + 255) / 256, 256, 0, stream>>>(esrc, edst, E, cursor, csr);

    // operand prep (split bf16) + folded layer-1 attention weights
    prepx_k<<<(N * 512 / 4 + 255) / 256, 256, 0, stream>>>(x, xh, xl);
    prepW0t_k<<<64, 256, 0, stream>>>(W0, W0h, W0l);
    prepW1t_k<<<512, 256, 0, stream>>>(W1, B1h, B1l);
    prep1_k<<<512, 256, 0, stream>>>(W1, at_s1, at_d1, ws1, wd1);

    // Layer 0: GEMM (bf16 out) with fused alpha0 epilogue
    mgemm_k<2, 3><<<dim3(4, N / 128), 256, 0, stream>>>(
        xh, xl, W0h, W0l, h0b, 512, nullptr, at_s0, at_d0, as0, ad0);
    node0w_k<<<N / 4, 256, 0, stream>>>(h0b, as0, ad0, indptr, csr, b0, ws1,
                                        wd1, hl0b, as1, ad1);

    // Layer 1: bf16 aggregate per chunk, 2-term fused GEMM (+b1, ELU)
    for (int base = 0; base < N; base += CH) {
        node1w_k<<<CH / 4, 256, 0, stream>>>(hl0b, as1, ad1, indptr, csr, aggh,
                                             base, CH);
        mgemm_k<1, 2><<<dim3(4, CH / 128), 256, 0, stream>>>(
            aggh, nullptr, B1h, B1l, out + (size_t)base * 512, 4096, b1,
            nullptr, nullptr, nullptr, nullptr);
    }
}

// Round 15
// 441.491 us; speedup vs baseline: 1.2280x; 1.0976x over previous
//
#include <hip/hip_runtime.h>
#include <hip/hip_bf16.h>

// ---------------------------------------------------------------------------
// GAT 2-layer, N=16384 nodes, D=512, H=8, E=524288 edges (+self loops)
// GEMM0: split-bf16 3-term MFMA (f32-accurate), fused alpha0, bf16 h0 out.
// GEMM1: pure bf16 MFMA (1 term) -- agg bf16 @ B1h bf16 (error budget holds).
// Node features bf16; one wave per node; alpha1 fused into node0.
// ---------------------------------------------------------------------------

#define NNODES 16384

typedef unsigned short u16;
typedef unsigned int u32;
typedef __attribute__((ext_vector_type(8))) __bf16 bf16x8;
typedef __attribute__((ext_vector_type(4))) float f32x4;

__device__ __forceinline__ u16 f2bf(float v) {
    u32 u = __builtin_bit_cast(u32, v);
    u32 r = (u + 0x7fffu + ((u >> 16) & 1u)) >> 16;
    return (u16)r;
}
__device__ __forceinline__ float bf2f(u16 s) {
    u32 u = ((u32)s) << 16;
    return __builtin_bit_cast(float, u);
}
__device__ __forceinline__ float bflo(u32 u) {
    return __builtin_bit_cast(float, u << 16);
}
__device__ __forceinline__ float bfhi(u32 u) {
    return __builtin_bit_cast(float, u & 0xffff0000u);
}
__device__ __forceinline__ void split2(float v, u16& h, u16& l) {
    h = f2bf(v);
    l = f2bf(v - bf2f(h));
}
__device__ __forceinline__ u32 pack2(float a, float b) {
    return (u32)f2bf(a) | ((u32)f2bf(b) << 16);
}

// async global->LDS, 16B per lane
__device__ __forceinline__ void gload_lds16(const u16* g, u16* l) {
    __builtin_amdgcn_global_load_lds(
        (__attribute__((address_space(1))) void*)(void*)(g),
        (__attribute__((address_space(3))) void*)(void*)(l), 16, 0, 0);
}

// ------------------------------ CSR build ---------------------------------
__global__ void zero_k(int* p, int n) {
    int i = blockIdx.x * 256 + threadIdx.x;
    if (i < n) p[i] = 0;
}

__global__ void count_k(const int* __restrict__ dst, int E, int* __restrict__ deg) {
    int i = blockIdx.x * 256 + threadIdx.x;
    if (i < E) atomicAdd(&deg[dst[i]], 1);
}

__global__ __launch_bounds__(1024) void scan_k(const int* __restrict__ deg,
                                               int* __restrict__ indptr,
                                               int* __restrict__ cursor, int n) {
    __shared__ int sums[1024];
    int t = threadIdx.x;
    int base = t * 16;
    int local[16];
    int s = 0;
    #pragma unroll
    for (int i = 0; i < 16; i++) { local[i] = s; s += deg[base + i]; }
    sums[t] = s;
    __syncthreads();
    for (int off = 1; off < 1024; off <<= 1) {
        int v = (t >= off) ? sums[t - off] : 0;
        __syncthreads();
        sums[t] += v;
        __syncthreads();
    }
    int base_sum = (t == 0) ? 0 : sums[t - 1];
    #pragma unroll
    for (int i = 0; i < 16; i++) {
        int v = base_sum + local[i];
        indptr[base + i] = v;
        cursor[base + i] = v;
    }
    if (t == 1023) indptr[n] = base_sum + s;
}

__global__ void scatter_k(const int* __restrict__ src, const int* __restrict__ dst,
                          int E, int* __restrict__ cursor, int* __restrict__ csr) {
    int i = blockIdx.x * 256 + threadIdx.x;
    if (i < E) {
        int pos = atomicAdd(&cursor[dst[i]], 1);
        csr[pos] = src[i];
    }
}

// ------------------------- split-bf16 prep kernels -------------------------
__global__ void prepx_k(const float* __restrict__ x, u16* __restrict__ xh,
                        u16* __restrict__ xl) {
    int idx = blockIdx.x * 256 + threadIdx.x;
    int e = idx << 2;
    int n = e >> 9, k = e & 511;
    int g = n >> 10, s = n & 1023;
    float4 v = *(const float4*)(x + ((size_t)(s * 16 + g) << 9) + k);
    u16 h[4], l[4];
    split2(v.x, h[0], l[0]);
    split2(v.y, h[1], l[1]);
    split2(v.z, h[2], l[2]);
    split2(v.w, h[3], l[3]);
    size_t o = ((size_t)n << 9) + k;
    *(ushort4*)(xh + o) = make_ushort4(h[0], h[1], h[2], h[3]);
    *(ushort4*)(xl + o) = make_ushort4(l[0], l[1], l[2], l[3]);
}

// W0t[n][k] = W0[k][n], tiled 64x64 transpose through LDS
__global__ __launch_bounds__(256) void prepW0t_k(const float* __restrict__ W0,
                                                 u16* __restrict__ Wh,
                                                 u16* __restrict__ Wl) {
    __shared__ u32 tile[64][65];
    int b = blockIdx.x;
    int kt = (b >> 3) * 64, nt = (b & 7) * 64;
    int t = threadIdx.x;
    #pragma unroll
    for (int i = 0; i < 16; i++) {
        int idx = i * 256 + t;
        int r = idx >> 6, c = idx & 63;
        float v = W0[(size_t)(kt + r) * 512 + nt + c];
        u16 h, l;
        split2(v, h, l);
        tile[r][c] = ((u32)h << 16) | l;
    }
    __syncthreads();
    #pragma unroll
    for (int i = 0; i < 8; i++) {
        int idx = i * 256 + t;
        int r = idx >> 5, c2 = (idx & 31) * 2;
        u32 p0 = tile[c2][r], p1 = tile[c2 + 1][r];
        size_t o = (size_t)(nt + r) * 512 + kt + c2;
        *(ushort2*)(Wh + o) = make_ushort2((u16)(p0 >> 16), (u16)(p1 >> 16));
        *(ushort2*)(Wl + o) = make_ushort2((u16)(p0 & 0xffff), (u16)(p1 & 0xffff));
    }
}

// B1t[c][h*512+k] = bf16(W1[k][h*512+c]/8), per-head tiled 64x64 transpose
__global__ __launch_bounds__(256) void prepW1t_k(const float* __restrict__ W1,
                                                 u16* __restrict__ Bh) {
    __shared__ u16 tile[64][66];
    int b = blockIdx.x;
    int hh = b >> 6;
    int rem = b & 63;
    int kt = (rem >> 3) * 64, ct = (rem & 7) * 64;
    int t = threadIdx.x;
    #pragma unroll
    for (int i = 0; i < 16; i++) {
        int idx = i * 256 + t;
        int r = idx >> 6, c = idx & 63;
        float v = W1[(size_t)(kt + r) * 4096 + hh * 512 + ct + c] * 0.125f;
        tile[r][c] = f2bf(v);
    }
    __syncthreads();
    #pragma unroll
    for (int i = 0; i < 8; i++) {
        int idx = i * 256 + t;
        int r = idx >> 5, c2 = (idx & 31) * 2;
        size_t o = (size_t)(ct + r) * 4096 + hh * 512 + kt + c2;
        *(ushort2*)(Bh + o) = make_ushort2(tile[c2][r], tile[c2 + 1][r]);
    }
}

// ---------------------------------------------------------------------------
// Split-bf16 MFMA GEMM: C[M,512] = A[M,K] @ Bt[512,K]^T
// TERMS=3: A 2-plane, B 2-plane (3 MFMA). TERMS=1: A,B single bf16 (1 MFMA).
// MODE 1: f32 out, +bias, ELU. MODE 2: bf16 out + fused alpha0.
// ---------------------------------------------------------------------------
template <int MODE, int TERMS>
__global__ __launch_bounds__(256) void mgemm_k(
    const u16* __restrict__ Ah, const u16* __restrict__ Al,
    const u16* __restrict__ Bh, const u16* __restrict__ Bl,
    void* __restrict__ Cv, int K, const float* __restrict__ bias,
    const float* __restrict__ att_s, const float* __restrict__ att_d,
    float* __restrict__ as_, float* __restrict__ ad_) {
    constexpr int pAl = 4096;
    constexpr int pBh = (TERMS == 3) ? 8192 : 4096;
    constexpr int pBl = 12288;                     // TERMS=3 only
    constexpr int NSEG = (TERMS == 3) ? 8 : 4;     // segments per wave
    __shared__ u16 smem[(TERMS == 3) ? 16384 : 8192];

    int t = threadIdx.x;
    int lane = t & 63, w = t >> 6;
    int wr = w >> 1, wc = w & 1;
    int row0 = blockIdx.y * 128, col0 = blockIdx.x * 128;

    f32x4 acc[4][4];
    #pragma unroll
    for (int i = 0; i < 4; i++)
        #pragma unroll
        for (int j = 0; j < 4; j++) acc[i][j] = (f32x4){0.f, 0.f, 0.f, 0.f};

    int srow = lane >> 2;
    int sl4 = lane & 3;
    const u16* gp[NSEG];
    u16* lp[NSEG];
    #pragma unroll
    for (int ii = 0; ii < NSEG; ii++) {
        int s = w * NSEG + ii;
        int pl = s >> 3, seg = s & 7;
        const u16* gb;
        int g0;
        if (TERMS == 3) {
            gb = (pl == 0) ? Ah : (pl == 1) ? Al : (pl == 2) ? Bh : Bl;
            g0 = (pl < 2) ? row0 : col0;
        } else {
            gb = (pl == 0) ? Ah : Bh;
            g0 = (pl == 0) ? row0 : col0;
        }
        int row = seg * 16 + srow;
        int slot = sl4 ^ ((row >> 1) & 3);
        gp[ii] = gb + (size_t)(g0 + row) * K + slot * 8;
        lp[ii] = smem + pl * 4096 + seg * 512;
    }

    int rl = lane & 15, kb = lane >> 4;

    for (int k0 = 0; k0 < K; k0 += 32) {
        #pragma unroll
        for (int ii = 0; ii < NSEG; ii++) gload_lds16(gp[ii] + k0, lp[ii]);
        __syncthreads();

        bf16x8 afh[4], afl_[4], bfh[4], bfl[4];
        #pragma unroll
        for (int f = 0; f < 4; f++) {
            int r = wr * 64 + f * 16 + rl;
            int off = r * 32 + ((kb ^ ((r >> 1) & 3)) << 3);
            afh[f] = *(const bf16x8*)(smem + off);
            if (TERMS == 3) afl_[f] = *(const bf16x8*)(smem + pAl + off);
        }
        #pragma unroll
        for (int j = 0; j < 4; j++) {
            int r = wc * 64 + j * 16 + rl;
            int off = r * 32 + ((kb ^ ((r >> 1) & 3)) << 3);
            bfh[j] = *(const bf16x8*)(smem + pBh + off);
            if (TERMS == 3) bfl[j] = *(const bf16x8*)(smem + pBl + off);
        }
        #pragma unroll
        for (int i = 0; i < 4; i++)
            #pragma unroll
            for (int j = 0; j < 4; j++) {
                if (TERMS == 3) {
                    acc[i][j] = __builtin_amdgcn_mfma_f32_16x16x32_bf16(
                        afl_[i], bfh[j], acc[i][j], 0, 0, 0);
                    acc[i][j] = __builtin_amdgcn_mfma_f32_16x16x32_bf16(
                        afh[i], bfl[j], acc[i][j], 0, 0, 0);
                }
                acc[i][j] = __builtin_amdgcn_mfma_f32_16x16x32_bf16(
                    afh[i], bfh[j], acc[i][j], 0, 0, 0);
            }
        __syncthreads();
    }

    // C/D layout 16x16: col = lane&15, row = (lane>>4)*4 + q
    int cr = kb * 4;
    #pragma unroll
    for (int i = 0; i < 4; i++) {
        #pragma unroll
        for (int j = 0; j < 4; j++) {
            int col = col0 + wc * 64 + j * 16 + rl;
            float bv = (MODE == 1) ? bias[col] : 0.f;
            f32x4 v = acc[i][j];
            #pragma unroll
            for (int q = 0; q < 4; q++) {
                float o = v[q] + bv;
                size_t grow = (size_t)(row0 + wr * 64 + i * 16 + cr + q);
                if (MODE == 1) {
                    o = o > 0.f ? o : __expf(o) - 1.f;
                    ((float*)Cv)[grow * 512 + col] = o;
                } else {
                    ((u16*)Cv)[grow * 512 + col] = f2bf(o);
                }
            }
        }
    }

    if (MODE == 2) {
        // this wave's 64 cols = head h (f32-accurate alpha0 from registers)
        int h = (col0 >> 6) + wc;
        float as_v[4], ad_v[4];
        #pragma unroll
        for (int j = 0; j < 4; j++) {
            as_v[j] = att_s[h * 64 + j * 16 + rl];
            ad_v[j] = att_d[h * 64 + j * 16 + rl];
        }
        #pragma unroll
        for (int i = 0; i < 4; i++) {
            float ps[4] = {}, pd[4] = {};
            #pragma unroll
            for (int j = 0; j < 4; j++) {
                f32x4 v = acc[i][j];
                #pragma unroll
                for (int q = 0; q < 4; q++) {
                    ps[q] = fmaf(v[q], as_v[j], ps[q]);
                    pd[q] = fmaf(v[q], ad_v[j], pd[q]);
                }
            }
            #pragma unroll
            for (int off = 1; off < 16; off <<= 1) {
                #pragma unroll
                for (int q = 0; q < 4; q++) {
                    ps[q] += __shfl_xor(ps[q], off);
                    pd[q] += __shfl_xor(pd[q], off);
                }
            }
            if (rl == 0) {
                #pragma unroll
                for (int q = 0; q < 4; q++) {
                    size_t row = (size_t)(row0 + wr * 64 + i * 16 + cr + q);
                    as_[row * 8 + h] = ps[q];
                    ad_[row * 8 + h] = pd[q];
                }
            }
        }
    }
}

// ------------------------------ attention ---------------------------------
__global__ __launch_bounds__(256) void prep1_k(const float* __restrict__ W1,
                                               const float* __restrict__ as1,
                                               const float* __restrict__ ad1,
                                               float* __restrict__ ws1,
                                               float* __restrict__ wd1) {
    int k = blockIdx.x;
    int t = threadIdx.x;
    int h = t >> 5, lane = t & 31;
    float ps = 0.f, pd = 0.f;
    for (int c = lane; c < 512; c += 32) {
        float w = W1[(size_t)k * 4096 + h * 512 + c];
        ps += w * as1[h * 512 + c];
        pd += w * ad1[h * 512 + c];
    }
    #pragma unroll
    for (int off = 1; off < 32; off <<= 1) {
        ps += __shfl_xor(ps, off);
        pd += __shfl_xor(pd, off);
    }
    if (lane == 0) {
        ws1[k * 8 + h] = ps;
        wd1[k * 8 + h] = pd;
    }
}

// ---------------------------------------------------------------------------
// node0w: ONE WAVE PER NODE (4 nodes/block, zero barriers). h0 is bf16.
// Lane l: softmax head h=l>>3 (stripe l&7); aggregates channels 8l..8l+7.
// hl0 stored bf16; fused alpha1 from f32 registers.
// ---------------------------------------------------------------------------
__global__ __launch_bounds__(256) void node0w_k(
    const u16* __restrict__ h0b, const float* __restrict__ asrc,
    const float* __restrict__ adst, const int* __restrict__ indptr,
    const int* __restrict__ csr, const float* __restrict__ b0,
    const float* __restrict__ ws1, const float* __restrict__ wd1,
    u16* __restrict__ hl0b, float* __restrict__ as1, float* __restrict__ ad1) {
    int b = blockIdx.x;
    int wid = threadIdx.x >> 6;
    int l = threadIdx.x & 63;
    int d = (b & 7) * (NNODES / 8) + ((b >> 3) << 2) + wid;  // XCD-pinned
    int h = l >> 3;
    int e0 = indptr[d];
    int ne = indptr[d + 1] - e0;   // real edges; e==ne is the self loop
    float adh = adst[d * 8 + h];

    float m = -3.0e38f, z = 0.f;
    for (int e = (l & 7); e <= ne; e += 8) {
        int s = (e < ne) ? csr[e0 + e] : d;
        float v = asrc[s * 8 + h] + adh;
        v = v > 0.f ? v : 0.2f * v;
        float mn = fmaxf(m, v);
        z = z * __expf(m - mn) + __expf(v - mn);
        m = mn;
    }
    #pragma unroll
    for (int off = 1; off < 8; off <<= 1) {
        float mo = __shfl_xor(m, off);
        float zo = __shfl_xor(z, off);
        float mn = fmaxf(m, mo);
        z = z * __expf(m - mn) + zo * __expf(mo - mn);
        m = mn;
    }
    float rz = 1.0f / (z + 1e-16f);

    float acc[8] = {};
    for (int eb = 0; eb <= ne; eb += 8) {
        int idx = eb + (l & 7);
        int sv = (idx < ne) ? csr[e0 + idx] : d;
        int nn = min(8, ne + 1 - eb);
        #pragma unroll
        for (int i = 0; i < 8; i++) {
            if (i < nn) {
                int s = __shfl(sv, (l & 56) | i);
                float v = asrc[s * 8 + h] + adh;
                v = v > 0.f ? v : 0.2f * v;
                float a = __expf(v - m) * rz;
                int4 pv = *(const int4*)(h0b + ((size_t)s << 9) + 8 * l);
                acc[0] = fmaf(a, bflo(pv.x), acc[0]);
                acc[1] = fmaf(a, bfhi(pv.x), acc[1]);
                acc[2] = fmaf(a, bflo(pv.y), acc[2]);
                acc[3] = fmaf(a, bfhi(pv.y), acc[3]);
                acc[4] = fmaf(a, bflo(pv.z), acc[4]);
                acc[5] = fmaf(a, bfhi(pv.z), acc[5]);
                acc[6] = fmaf(a, bflo(pv.w), acc[6]);
                acc[7] = fmaf(a, bfhi(pv.w), acc[7]);
            }
        }
    }

    const float4* b4 = (const float4*)(b0 + 8 * l);
    float4 bva = b4[0], bvb = b4[1];
    float o[8];
    o[0] = acc[0] + bva.x; o[1] = acc[1] + bva.y;
    o[2] = acc[2] + bva.z; o[3] = acc[3] + bva.w;
    o[4] = acc[4] + bvb.x; o[5] = acc[5] + bvb.y;
    o[6] = acc[6] + bvb.z; o[7] = acc[7] + bvb.w;
    #pragma unroll
    for (int k = 0; k < 8; k++) o[k] = o[k] > 0.f ? o[k] : __expf(o[k]) - 1.f;
    int4 hv;
    hv.x = (int)pack2(o[0], o[1]);
    hv.y = (int)pack2(o[2], o[3]);
    hv.z = (int)pack2(o[4], o[5]);
    hv.w = (int)pack2(o[6], o[7]);
    *(int4*)(hl0b + ((size_t)d << 9) + 8 * l) = hv;

    float ps[8] = {}, pd[8] = {};
    #pragma unroll
    for (int k = 0; k < 8; k++) {
        const float4* w4 = (const float4*)(ws1 + (size_t)(8 * l + k) * 8);
        const float4* v4 = (const float4*)(wd1 + (size_t)(8 * l + k) * 8);
        float4 wa = w4[0], wb = w4[1];
        float4 va = v4[0], vb = v4[1];
        float ok = o[k];
        ps[0] = fmaf(ok, wa.x, ps[0]); ps[1] = fmaf(ok, wa.y, ps[1]);
        ps[2] = fmaf(ok, wa.z, ps[2]); ps[3] = fmaf(ok, wa.w, ps[3]);
        ps[4] = fmaf(ok, wb.x, ps[4]); ps[5] = fmaf(ok, wb.y, ps[5]);
        ps[6] = fmaf(ok, wb.z, ps[6]); ps[7] = fmaf(ok, wb.w, ps[7]);
        pd[0] = fmaf(ok, va.x, pd[0]); pd[1] = fmaf(ok, va.y, pd[1]);
        pd[2] = fmaf(ok, va.z, pd[2]); pd[3] = fmaf(ok, va.w, pd[3]);
        pd[4] = fmaf(ok, vb.x, pd[4]); pd[5] = fmaf(ok, vb.y, pd[5]);
        pd[6] = fmaf(ok, vb.z, pd[6]); pd[7] = fmaf(ok, vb.w, pd[7]);
    }
    #pragma unroll
    for (int off = 1; off < 64; off <<= 1) {
        #pragma unroll
        for (int j = 0; j < 8; j++) {
            ps[j] += __shfl_xor(ps[j], off);
            pd[j] += __shfl_xor(pd[j], off);
        }
    }
    #pragma unroll
    for (int j = 0; j < 8; j++) {
        if (l == j) as1[(size_t)d * 8 + j] = ps[j];
        if (l == 8 + j) ad1[(size_t)d * 8 + j] = pd[j];
    }
}

// ---------------------------------------------------------------------------
// node1w: ONE WAVE PER NODE. hl0 is bf16. Lane l: softmax head hme=l&7
// (stripe l>>3); aggregates acc[8 heads][8 ch] for channels 8l..8l+7.
// ---------------------------------------------------------------------------
__global__ __launch_bounds__(256) void node1w_k(
    const u16* __restrict__ hl0b, const float* __restrict__ asrc,
    const float* __restrict__ adst, const int* __restrict__ indptr,
    const int* __restrict__ csr, u16* __restrict__ aggh, int base, int ch) {
    int b = blockIdx.x;
    int wid = threadIdx.x >> 6;
    int l = threadIdx.x & 63;
    int dl = (b & 7) * (ch >> 3) + ((b >> 3) << 2) + wid;
    int d = base + dl;
    int hme = l & 7;
    int e0 = indptr[d];
    int ne = indptr[d + 1] - e0;
    float adh = adst[d * 8 + hme];

    float m = -3.0e38f, z = 0.f;
    for (int e = (l >> 3); e <= ne; e += 8) {
        int s = (e < ne) ? csr[e0 + e] : d;
        float v = asrc[s * 8 + hme] + adh;
        v = v > 0.f ? v : 0.2f * v;
        float mn = fmaxf(m, v);
        z = z * __expf(m - mn) + __expf(v - mn);
        m = mn;
    }
    #pragma unroll
    for (int off = 8; off < 64; off <<= 1) {
        float mo = __shfl_xor(m, off);
        float zo = __shfl_xor(z, off);
        float mn = fmaxf(m, mo);
        z = z * __expf(m - mn) + zo * __expf(mo - mn);
        m = mn;
    }
    float rz = 1.0f / (z + 1e-16f);

    float acc[8][8] = {};
    for (int eb = 0; eb <= ne; eb += 8) {
        int idx = eb + (l & 7);
        int sv = (idx < ne) ? csr[e0 + idx] : d;
        int nn = min(8, ne + 1 - eb);
        #pragma unroll
        for (int i = 0; i < 8; i++) {
            if (i < nn) {
                int s = __shfl(sv, (l & 56) | i);
                float v = asrc[s * 8 + hme] + adh;
                v = v > 0.f ? v : 0.2f * v;
                float amine = __expf(v - m) * rz;
                float a[8];
                #pragma unroll
                for (int hh = 0; hh < 8; hh++)
                    a[hh] = __shfl(amine, (l & 56) | hh);
                int4 pv = *(const int4*)(hl0b + ((size_t)s << 9) + 8 * l);
                float f0 = bflo(pv.x), f1 = bfhi(pv.x);
                float f2 = bflo(pv.y), f3 = bfhi(pv.y);
                float f4 = bflo(pv.z), f5 = bfhi(pv.z);
                float f6 = bflo(pv.w), f7 = bfhi(pv.w);
                #pragma unroll
                for (int hh = 0; hh < 8; hh++) {
                    acc[hh][0] = fmaf(a[hh], f0, acc[hh][0]);
                    acc[hh][1] = fmaf(a[hh], f1, acc[hh][1]);
                    acc[hh][2] = fmaf(a[hh], f2, acc[hh][2]);
                    acc[hh][3] = fmaf(a[hh], f3, acc[hh][3]);
                    acc[hh][4] = fmaf(a[hh], f4, acc[hh][4]);
                    acc[hh][5] = fmaf(a[hh], f5, acc[hh][5]);
                    acc[hh][6] = fmaf(a[hh], f6, acc[hh][6]);
                    acc[hh][7] = fmaf(a[hh], f7, acc[hh][7]);
                }
            }
        }
    }

    #pragma unroll
    for (int hh = 0; hh < 8; hh++) {
        ushort4 qa = make_ushort4(f2bf(acc[hh][0]), f2bf(acc[hh][1]),
                                  f2bf(acc[hh][2]), f2bf(acc[hh][3]));
        ushort4 qb = make_ushort4(f2bf(acc[hh][4]), f2bf(acc[hh][5]),
                                  f2bf(acc[hh][6]), f2bf(acc[hh][7]));
        size_t ob = (size_t)dl * 4096 + hh * 512 + 8 * l;
        *(ushort4*)(aggh + ob) = qa;
        *(ushort4*)(aggh + ob + 4) = qb;
    }
}

// ------------------------------- launcher ----------------------------------
extern "C" void kernel_launch(void* const* d_in, const int* in_sizes, int n_in,
                              void* d_out, int out_size, void* d_ws, size_t ws_size,
                              hipStream_t stream) {
    const float* x = (const float*)d_in[0];
    const int* ei = (const int*)d_in[1];
    const float* W0 = (const float*)d_in[2];
    const float* at_s0 = (const float*)d_in[3];
    const float* at_d0 = (const float*)d_in[4];
    const float* b0 = (const float*)d_in[5];
    const float* W1 = (const float*)d_in[6];
    const float* at_s1 = (const float*)d_in[7];
    const float* at_d1 = (const float*)d_in[8];
    const float* b1 = (const float*)d_in[9];
    float* out = (float*)d_out;

    const int N = NNODES;
    const int E = in_sizes[1] / 2;
    const int* esrc = ei;
    const int* edst = ei + E;

    char* p = (char*)d_ws;
    auto carve = [&](size_t bytes) -> void* {
        void* r = (void*)p;
        p += ((bytes + 255) & ~(size_t)255);
        return r;
    };
    u16* h0b = (u16*)carve((size_t)N * 512 * 2);
    u16* hl0b = (u16*)carve((size_t)N * 512 * 2);
    float* as0 = (float*)carve((size_t)N * 8 * 4);
    float* ad0 = (float*)carve((size_t)N * 8 * 4);
    float* as1 = (float*)carve((size_t)N * 8 * 4);
    float* ad1 = (float*)carve((size_t)N * 8 * 4);
    int* deg = (int*)carve((size_t)N * 4);
    int* indptr = (int*)carve((size_t)(N + 1) * 4);
    int* cursor = (int*)carve((size_t)N * 4);
    int* csr = (int*)carve((size_t)E * 4);
    float* ws1 = (float*)carve(512 * 8 * 4);
    float* wd1 = (float*)carve(512 * 8 * 4);
    u16* xh = (u16*)carve((size_t)N * 512 * 2);
    u16* xl = (u16*)carve((size_t)N * 512 * 2);
    u16* W0h = (u16*)carve((size_t)512 * 512 * 2);
    u16* W0l = (u16*)carve((size_t)512 * 512 * 2);
    u16* B1h = (u16*)carve((size_t)512 * 4096 * 2);
    size_t used = (size_t)(p - (char*)d_ws);

    int CH = 1024;
    const int cands[5] = {16384, 8192, 4096, 2048, 1024};
    for (int ci = 0; ci < 5; ci++) {
        if (ws_size >= used + (size_t)cands[ci] * 8192 + 512) {
            CH = cands[ci];
            break;
        }
    }
    u16* aggh = (u16*)carve((size_t)CH * 4096 * 2);

    // CSR build
    zero_k<<<(N + 255) / 256, 256, 0, stream>>>(deg, N);
    count_k<<<(E + 255) / 256, 256, 0, stream>>>(edst, E, deg);
    scan_k<<<1, 1024, 0, stream>>>(deg, indptr, cursor, N);
    scatter_k<<<(E + 255) / 256, 256, 0, stream>>>(esrc, edst, E, cursor, csr);

    // operand prep + folded layer-1 attention weights
    prepx_k<<<(N * 512 / 4 + 255) / 256, 256, 0, stream>>>(x, xh, xl);
    prepW0t_k<<<64, 256, 0, stream>>>(W0, W0h, W0l);
    prepW1t_k<<<512, 256, 0, stream>>>(W1, B1h);
    prep1_k<<<512, 256, 0, stream>>>(W1, at_s1, at_d1, ws1, wd1);

    // Layer 0: 3-term GEMM (bf16 out) with fused alpha0 epilogue
    mgemm_k<2, 3><<<dim3(4, N / 128), 256, 0, stream>>>(
        xh, xl, W0h, W0l, h0b, 512, nullptr, at_s0, at_d0, as0, ad0);
    node0w_k<<<N / 4, 256, 0, stream>>>(h0b, as0, ad0, indptr, csr, b0, ws1,
                                        wd1, hl0b, as1, ad1);

    // Layer 1: bf16 aggregate per chunk, pure-bf16 GEMM (+b1, ELU)
    for (int base = 0; base < N; base += CH) {
        node1w_k<<<CH / 4, 256, 0, stream>>>(hl0b, as1, ad1, indptr, csr, aggh,
                                             base, CH);
        mgemm_k<1, 1><<<dim3(4, CH / 128), 256, 0, stream>>>(
            aggh, nullptr, B1h, nullptr, out + (size_t)base * 512, 4096, b1,
            nullptr, nullptr, nullptr, nullptr);
    }
}

// Round 16
// 402.508 us; speedup vs baseline: 1.3469x; 1.0969x over previous
//
#include <hip/hip_runtime.h>
#include <hip/hip_bf16.h>

// ---------------------------------------------------------------------------
// GAT 2-layer, N=16384 nodes, D=512, H=8, E=524288 edges (+self loops)
// GEMM0: split-bf16 3-term MFMA (BK=32), fused alpha0, bf16 h0 out.
// GEMM1: pure bf16 MFMA, BK=64 (2 K-halves per barrier pair).
// Both GEMMs: bijective XCD tile remap (A panel fetched once per row-tile).
// Node features bf16; one wave per node; alpha1 fused into node0.
// ---------------------------------------------------------------------------

#define NNODES 16384

typedef unsigned short u16;
typedef unsigned int u32;
typedef __attribute__((ext_vector_type(8))) __bf16 bf16x8;
typedef __attribute__((ext_vector_type(4))) float f32x4;

__device__ __forceinline__ u16 f2bf(float v) {
    u32 u = __builtin_bit_cast(u32, v);
    u32 r = (u + 0x7fffu + ((u >> 16) & 1u)) >> 16;
    return (u16)r;
}
__device__ __forceinline__ float bf2f(u16 s) {
    u32 u = ((u32)s) << 16;
    return __builtin_bit_cast(float, u);
}
__device__ __forceinline__ float bflo(u32 u) {
    return __builtin_bit_cast(float, u << 16);
}
__device__ __forceinline__ float bfhi(u32 u) {
    return __builtin_bit_cast(float, u & 0xffff0000u);
}
__device__ __forceinline__ void split2(float v, u16& h, u16& l) {
    h = f2bf(v);
    l = f2bf(v - bf2f(h));
}
__device__ __forceinline__ u32 pack2(float a, float b) {
    return (u32)f2bf(a) | ((u32)f2bf(b) << 16);
}

// async global->LDS, 16B per lane
__device__ __forceinline__ void gload_lds16(const u16* g, u16* l) {
    __builtin_amdgcn_global_load_lds(
        (__attribute__((address_space(1))) void*)(void*)(g),
        (__attribute__((address_space(3))) void*)(void*)(l), 16, 0, 0);
}

// ------------------------------ CSR build ---------------------------------
__global__ void zero_k(int* p, int n) {
    int i = blockIdx.x * 256 + threadIdx.x;
    if (i < n) p[i] = 0;
}

__global__ void count_k(const int* __restrict__ dst, int E, int* __restrict__ deg) {
    int i = blockIdx.x * 256 + threadIdx.x;
    if (i < E) atomicAdd(&deg[dst[i]], 1);
}

__global__ __launch_bounds__(1024) void scan_k(const int* __restrict__ deg,
                                               int* __restrict__ indptr,
                                               int* __restrict__ cursor, int n) {
    __shared__ int sums[1024];
    int t = threadIdx.x;
    int base = t * 16;
    int local[16];
    int s = 0;
    #pragma unroll
    for (int i = 0; i < 16; i++) { local[i] = s; s += deg[base + i]; }
    sums[t] = s;
    __syncthreads();
    for (int off = 1; off < 1024; off <<= 1) {
        int v = (t >= off) ? sums[t - off] : 0;
        __syncthreads();
        sums[t] += v;
        __syncthreads();
    }
    int base_sum = (t == 0) ? 0 : sums[t - 1];
    #pragma unroll
    for (int i = 0; i < 16; i++) {
        int v = base_sum + local[i];
        indptr[base + i] = v;
        cursor[base + i] = v;
    }
    if (t == 1023) indptr[n] = base_sum + s;
}

__global__ void scatter_k(const int* __restrict__ src, const int* __restrict__ dst,
                          int E, int* __restrict__ cursor, int* __restrict__ csr) {
    int i = blockIdx.x * 256 + threadIdx.x;
    if (i < E) {
        int pos = atomicAdd(&cursor[dst[i]], 1);
        csr[pos] = src[i];
    }
}

// ------------------------- split-bf16 prep kernels -------------------------
__global__ void prepx_k(const float* __restrict__ x, u16* __restrict__ xh,
                        u16* __restrict__ xl) {
    int idx = blockIdx.x * 256 + threadIdx.x;
    int e = idx << 2;
    int n = e >> 9, k = e & 511;
    int g = n >> 10, s = n & 1023;
    float4 v = *(const float4*)(x + ((size_t)(s * 16 + g) << 9) + k);
    u16 h[4], l[4];
    split2(v.x, h[0], l[0]);
    split2(v.y, h[1], l[1]);
    split2(v.z, h[2], l[2]);
    split2(v.w, h[3], l[3]);
    size_t o = ((size_t)n << 9) + k;
    *(ushort4*)(xh + o) = make_ushort4(h[0], h[1], h[2], h[3]);
    *(ushort4*)(xl + o) = make_ushort4(l[0], l[1], l[2], l[3]);
}

// W0t[n][k] = W0[k][n], tiled 64x64 transpose through LDS
__global__ __launch_bounds__(256) void prepW0t_k(const float* __restrict__ W0,
                                                 u16* __restrict__ Wh,
                                                 u16* __restrict__ Wl) {
    __shared__ u32 tile[64][65];
    int b = blockIdx.x;
    int kt = (b >> 3) * 64, nt = (b & 7) * 64;
    int t = threadIdx.x;
    #pragma unroll
    for (int i = 0; i < 16; i++) {
        int idx = i * 256 + t;
        int r = idx >> 6, c = idx & 63;
        float v = W0[(size_t)(kt + r) * 512 + nt + c];
        u16 h, l;
        split2(v, h, l);
        tile[r][c] = ((u32)h << 16) | l;
    }
    __syncthreads();
    #pragma unroll
    for (int i = 0; i < 8; i++) {
        int idx = i * 256 + t;
        int r = idx >> 5, c2 = (idx & 31) * 2;
        u32 p0 = tile[c2][r], p1 = tile[c2 + 1][r];
        size_t o = (size_t)(nt + r) * 512 + kt + c2;
        *(ushort2*)(Wh + o) = make_ushort2((u16)(p0 >> 16), (u16)(p1 >> 16));
        *(ushort2*)(Wl + o) = make_ushort2((u16)(p0 & 0xffff), (u16)(p1 & 0xffff));
    }
}

// B1t[c][h*512+k] = bf16(W1[k][h*512+c]/8), per-head tiled 64x64 transpose
__global__ __launch_bounds__(256) void prepW1t_k(const float* __restrict__ W1,
                                                 u16* __restrict__ Bh) {
    __shared__ u16 tile[64][66];
    int b = blockIdx.x;
    int hh = b >> 6;
    int rem = b & 63;
    int kt = (rem >> 3) * 64, ct = (rem & 7) * 64;
    int t = threadIdx.x;
    #pragma unroll
    for (int i = 0; i < 16; i++) {
        int idx = i * 256 + t;
        int r = idx >> 6, c = idx & 63;
        float v = W1[(size_t)(kt + r) * 4096 + hh * 512 + ct + c] * 0.125f;
        tile[r][c] = f2bf(v);
    }
    __syncthreads();
    #pragma unroll
    for (int i = 0; i < 8; i++) {
        int idx = i * 256 + t;
        int r = idx >> 5, c2 = (idx & 31) * 2;
        size_t o = (size_t)(ct + r) * 4096 + hh * 512 + kt + c2;
        *(ushort2*)(Bh + o) = make_ushort2(tile[c2][r], tile[c2 + 1][r]);
    }
}

// ---------------------------------------------------------------------------
// MFMA GEMM: C[M,512] = A[M,K] @ Bt[512,K]^T, XCD-remapped tiles.
// TERMS=3: split-bf16 3-term, BK=32. TERMS=1: pure bf16, BK=64 (2 halves).
// MODE 1: f32 out, +bias, ELU. MODE 2: bf16 out + fused alpha0.
// ---------------------------------------------------------------------------
template <int MODE, int TERMS>
__global__ __launch_bounds__(256) void mgemm_k(
    const u16* __restrict__ Ah, const u16* __restrict__ Al,
    const u16* __restrict__ Bh, const u16* __restrict__ Bl,
    void* __restrict__ Cv, int K, const float* __restrict__ bias,
    const float* __restrict__ att_s, const float* __restrict__ att_d,
    float* __restrict__ as_, float* __restrict__ ad_) {
    __shared__ u16 smem[16384];  // 32 KB both variants

    int t = threadIdx.x;
    int lane = t & 63, w = t >> 6;
    int wr = w >> 1, wc = w & 1;

    // bijective XCD remap: all 4 col-tiles of a row-tile land on one XCD
    int orig = blockIdx.x + (blockIdx.y << 2);
    int xcd = orig & 7, slot = orig >> 3;
    int by = xcd * ((int)gridDim.y >> 3) + (slot >> 2);
    int bx = slot & 3;
    int row0 = by * 128, col0 = bx * 128;

    f32x4 acc[4][4];
    #pragma unroll
    for (int i = 0; i < 4; i++)
        #pragma unroll
        for (int j = 0; j < 4; j++) acc[i][j] = (f32x4){0.f, 0.f, 0.f, 0.f};

    int srow = lane >> 2;
    int sl4 = lane & 3;
    const u16* gp[8];
    u16* lp[8];
    #pragma unroll
    for (int ii = 0; ii < 8; ii++) {
        const u16* gb;
        int g0, koff;
        if (TERMS == 3) {
            // planes: Ah | Al | Bh | Bl, BK=32, 8 segs each
            gb = (w == 0) ? Ah : (w == 1) ? Al : (w == 2) ? Bh : Bl;
            g0 = (w < 2) ? row0 : col0;
            koff = 0;
        } else {
            // regions: A-khalf0 | A-khalf1 | B-khalf0 | B-khalf1, BK=64
            gb = (w < 2) ? Ah : Bh;
            g0 = (w < 2) ? row0 : col0;
            koff = (w & 1) * 32;
        }
        int row = ii * 16 + srow;
        int sslot = sl4 ^ ((row >> 1) & 3);
        gp[ii] = gb + (size_t)(g0 + row) * K + koff + sslot * 8;
        lp[ii] = smem + w * 4096 + ii * 512;
    }

    int rl = lane & 15, kb = lane >> 4;

    if (TERMS == 3) {
        for (int k0 = 0; k0 < K; k0 += 32) {
            #pragma unroll
            for (int ii = 0; ii < 8; ii++) gload_lds16(gp[ii] + k0, lp[ii]);
            __syncthreads();

            bf16x8 afh[4], afl_[4], bfh[4], bfl[4];
            #pragma unroll
            for (int f = 0; f < 4; f++) {
                int r = wr * 64 + f * 16 + rl;
                int off = r * 32 + ((kb ^ ((r >> 1) & 3)) << 3);
                afh[f] = *(const bf16x8*)(smem + off);
                afl_[f] = *(const bf16x8*)(smem + 4096 + off);
            }
            #pragma unroll
            for (int j = 0; j < 4; j++) {
                int r = wc * 64 + j * 16 + rl;
                int off = r * 32 + ((kb ^ ((r >> 1) & 3)) << 3);
                bfh[j] = *(const bf16x8*)(smem + 8192 + off);
                bfl[j] = *(const bf16x8*)(smem + 12288 + off);
            }
            #pragma unroll
            for (int i = 0; i < 4; i++)
                #pragma unroll
                for (int j = 0; j < 4; j++) {
                    acc[i][j] = __builtin_amdgcn_mfma_f32_16x16x32_bf16(
                        afl_[i], bfh[j], acc[i][j], 0, 0, 0);
                    acc[i][j] = __builtin_amdgcn_mfma_f32_16x16x32_bf16(
                        afh[i], bfl[j], acc[i][j], 0, 0, 0);
                    acc[i][j] = __builtin_amdgcn_mfma_f32_16x16x32_bf16(
                        afh[i], bfh[j], acc[i][j], 0, 0, 0);
                }
            __syncthreads();
        }
    } else {
        for (int k0 = 0; k0 < K; k0 += 64) {
            #pragma unroll
            for (int ii = 0; ii < 8; ii++) gload_lds16(gp[ii] + k0, lp[ii]);
            __syncthreads();

            #pragma unroll
            for (int ks = 0; ks < 2; ks++) {
                bf16x8 af[4], bf[4];
                #pragma unroll
                for (int f = 0; f < 4; f++) {
                    int r = wr * 64 + f * 16 + rl;
                    int off = r * 32 + ((kb ^ ((r >> 1) & 3)) << 3);
                    af[f] = *(const bf16x8*)(smem + ks * 4096 + off);
                }
                #pragma unroll
                for (int j = 0; j < 4; j++) {
                    int r = wc * 64 + j * 16 + rl;
                    int off = r * 32 + ((kb ^ ((r >> 1) & 3)) << 3);
                    bf[j] = *(const bf16x8*)(smem + 8192 + ks * 4096 + off);
                }
                #pragma unroll
                for (int i = 0; i < 4; i++)
                    #pragma unroll
                    for (int j = 0; j < 4; j++)
                        acc[i][j] = __builtin_amdgcn_mfma_f32_16x16x32_bf16(
                            af[i], bf[j], acc[i][j], 0, 0, 0);
            }
            __syncthreads();
        }
    }

    // C/D layout 16x16: col = lane&15, row = (lane>>4)*4 + q
    int cr = kb * 4;
    #pragma unroll
    for (int i = 0; i < 4; i++) {
        #pragma unroll
        for (int j = 0; j < 4; j++) {
            int col = col0 + wc * 64 + j * 16 + rl;
            float bv = (MODE == 1) ? bias[col] : 0.f;
            f32x4 v = acc[i][j];
            #pragma unroll
            for (int q = 0; q < 4; q++) {
                float o = v[q] + bv;
                size_t grow = (size_t)(row0 + wr * 64 + i * 16 + cr + q);
                if (MODE == 1) {
                    o = o > 0.f ? o : __expf(o) - 1.f;
                    ((float*)Cv)[grow * 512 + col] = o;
                } else {
                    ((u16*)Cv)[grow * 512 + col] = f2bf(o);
                }
            }
        }
    }

    if (MODE == 2) {
        // this wave's 64 cols = head h (f32-accurate alpha0 from registers)
        int h = (col0 >> 6) + wc;
        float as_v[4], ad_v[4];
        #pragma unroll
        for (int j = 0; j < 4; j++) {
            as_v[j] = att_s[h * 64 + j * 16 + rl];
            ad_v[j] = att_d[h * 64 + j * 16 + rl];
        }
        #pragma unroll
        for (int i = 0; i < 4; i++) {
            float ps[4] = {}, pd[4] = {};
            #pragma unroll
            for (int j = 0; j < 4; j++) {
                f32x4 v = acc[i][j];
                #pragma unroll
                for (int q = 0; q < 4; q++) {
                    ps[q] = fmaf(v[q], as_v[j], ps[q]);
                    pd[q] = fmaf(v[q], ad_v[j], pd[q]);
                }
            }
            #pragma unroll
            for (int off = 1; off < 16; off <<= 1) {
                #pragma unroll
                for (int q = 0; q < 4; q++) {
                    ps[q] += __shfl_xor(ps[q], off);
                    pd[q] += __shfl_xor(pd[q], off);
                }
            }
            if (rl == 0) {
                #pragma unroll
                for (int q = 0; q < 4; q++) {
                    size_t row = (size_t)(row0 + wr * 64 + i * 16 + cr + q);
                    as_[row * 8 + h] = ps[q];
                    ad_[row * 8 + h] = pd[q];
                }
            }
        }
    }
}

// ------------------------------ attention ---------------------------------
__global__ __launch_bounds__(256) void prep1_k(const float* __restrict__ W1,
                                               const float* __restrict__ as1,
                                               const float* __restrict__ ad1,
                                               float* __restrict__ ws1,
                                               float* __restrict__ wd1) {
    int k = blockIdx.x;
    int t = threadIdx.x;
    int h = t >> 5, lane = t & 31;
    float ps = 0.f, pd = 0.f;
    for (int c = lane; c < 512; c += 32) {
        float w = W1[(size_t)k * 4096 + h * 512 + c];
        ps += w * as1[h * 512 + c];
        pd += w * ad1[h * 512 + c];
    }
    #pragma unroll
    for (int off = 1; off < 32; off <<= 1) {
        ps += __shfl_xor(ps, off);
        pd += __shfl_xor(pd, off);
    }
    if (lane == 0) {
        ws1[k * 8 + h] = ps;
        wd1[k * 8 + h] = pd;
    }
}

// ---------------------------------------------------------------------------
// node0w: ONE WAVE PER NODE (4 nodes/block, zero barriers). h0 is bf16.
// ---------------------------------------------------------------------------
__global__ __launch_bounds__(256) void node0w_k(
    const u16* __restrict__ h0b, const float* __restrict__ asrc,
    const float* __restrict__ adst, const int* __restrict__ indptr,
    const int* __restrict__ csr, const float* __restrict__ b0,
    const float* __restrict__ ws1, const float* __restrict__ wd1,
    u16* __restrict__ hl0b, float* __restrict__ as1, float* __restrict__ ad1) {
    int b = blockIdx.x;
    int wid = threadIdx.x >> 6;
    int l = threadIdx.x & 63;
    int d = (b & 7) * (NNODES / 8) + ((b >> 3) << 2) + wid;  // XCD-pinned
    int h = l >> 3;
    int e0 = indptr[d];
    int ne = indptr[d + 1] - e0;   // real edges; e==ne is the self loop
    float adh = adst[d * 8 + h];

    float m = -3.0e38f, z = 0.f;
    for (int e = (l & 7); e <= ne; e += 8) {
        int s = (e < ne) ? csr[e0 + e] : d;
        float v = asrc[s * 8 + h] + adh;
        v = v > 0.f ? v : 0.2f * v;
        float mn = fmaxf(m, v);
        z = z * __expf(m - mn) + __expf(v - mn);
        m = mn;
    }
    #pragma unroll
    for (int off = 1; off < 8; off <<= 1) {
        float mo = __shfl_xor(m, off);
        float zo = __shfl_xor(z, off);
        float mn = fmaxf(m, mo);
        z = z * __expf(m - mn) + zo * __expf(mo - mn);
        m = mn;
    }
    float rz = 1.0f / (z + 1e-16f);

    float acc[8] = {};
    for (int eb = 0; eb <= ne; eb += 8) {
        int idx = eb + (l & 7);
        int sv = (idx < ne) ? csr[e0 + idx] : d;
        int nn = min(8, ne + 1 - eb);
        #pragma unroll
        for (int i = 0; i < 8; i++) {
            if (i < nn) {
                int s = __shfl(sv, (l & 56) | i);
                float v = asrc[s * 8 + h] + adh;
                v = v > 0.f ? v : 0.2f * v;
                float a = __expf(v - m) * rz;
                int4 pv = *(const int4*)(h0b + ((size_t)s << 9) + 8 * l);
                acc[0] = fmaf(a, bflo(pv.x), acc[0]);
                acc[1] = fmaf(a, bfhi(pv.x), acc[1]);
                acc[2] = fmaf(a, bflo(pv.y), acc[2]);
                acc[3] = fmaf(a, bfhi(pv.y), acc[3]);
                acc[4] = fmaf(a, bflo(pv.z), acc[4]);
                acc[5] = fmaf(a, bfhi(pv.z), acc[5]);
                acc[6] = fmaf(a, bflo(pv.w), acc[6]);
                acc[7] = fmaf(a, bfhi(pv.w), acc[7]);
            }
        }
    }

    const float4* b4 = (const float4*)(b0 + 8 * l);
    float4 bva = b4[0], bvb = b4[1];
    float o[8];
    o[0] = acc[0] + bva.x; o[1] = acc[1] + bva.y;
    o[2] = acc[2] + bva.z; o[3] = acc[3] + bva.w;
    o[4] = acc[4] + bvb.x; o[5] = acc[5] + bvb.y;
    o[6] = acc[6] + bvb.z; o[7] = acc[7] + bvb.w;
    #pragma unroll
    for (int k = 0; k < 8; k++) o[k] = o[k] > 0.f ? o[k] : __expf(o[k]) - 1.f;
    int4 hv;
    hv.x = (int)pack2(o[0], o[1]);
    hv.y = (int)pack2(o[2], o[3]);
    hv.z = (int)pack2(o[4], o[5]);
    hv.w = (int)pack2(o[6], o[7]);
    *(int4*)(hl0b + ((size_t)d << 9) + 8 * l) = hv;

    float ps[8] = {}, pd[8] = {};
    #pragma unroll
    for (int k = 0; k < 8; k++) {
        const float4* w4 = (const float4*)(ws1 + (size_t)(8 * l + k) * 8);
        const float4* v4 = (const float4*)(wd1 + (size_t)(8 * l + k) * 8);
        float4 wa = w4[0], wb = w4[1];
        float4 va = v4[0], vb = v4[1];
        float ok = o[k];
        ps[0] = fmaf(ok, wa.x, ps[0]); ps[1] = fmaf(ok, wa.y, ps[1]);
        ps[2] = fmaf(ok, wa.z, ps[2]); ps[3] = fmaf(ok, wa.w, ps[3]);
        ps[4] = fmaf(ok, wb.x, ps[4]); ps[5] = fmaf(ok, wb.y, ps[5]);
        ps[6] = fmaf(ok, wb.z, ps[6]); ps[7] = fmaf(ok, wb.w, ps[7]);
        pd[0] = fmaf(ok, va.x, pd[0]); pd[1] = fmaf(ok, va.y, pd[1]);
        pd[2] = fmaf(ok, va.z, pd[2]); pd[3] = fmaf(ok, va.w, pd[3]);
        pd[4] = fmaf(ok, vb.x, pd[4]); pd[5] = fmaf(ok, vb.y, pd[5]);
        pd[6] = fmaf(ok, vb.z, pd[6]); pd[7] = fmaf(ok, vb.w, pd[7]);
    }
    #pragma unroll
    for (int off = 1; off < 64; off <<= 1) {
        #pragma unroll
        for (int j = 0; j < 8; j++) {
            ps[j] += __shfl_xor(ps[j], off);
            pd[j] += __shfl_xor(pd[j], off);
        }
    }
    #pragma unroll
    for (int j = 0; j < 8; j++) {
        if (l == j) as1[(size_t)d * 8 + j] = ps[j];
        if (l == 8 + j) ad1[(size_t)d * 8 + j] = pd[j];
    }
}

// ---------------------------------------------------------------------------
// node1w: ONE WAVE PER NODE. hl0 is bf16.
// ---------------------------------------------------------------------------
__global__ __launch_bounds__(256) void node1w_k(
    const u16* __restrict__ hl0b, const float* __restrict__ asrc,
    const float* __restrict__ adst, const int* __restrict__ indptr,
    const int* __restrict__ csr, u16* __restrict__ aggh, int base, int ch) {
    int b = blockIdx.x;
    int wid = threadIdx.x >> 6;
    int l = threadIdx.x & 63;
    int dl = (b & 7) * (ch >> 3) + ((b >> 3) << 2) + wid;
    int d = base + dl;
    int hme = l & 7;
    int e0 = indptr[d];
    int ne = indptr[d + 1] - e0;
    float adh = adst[d * 8 + hme];

    float m = -3.0e38f, z = 0.f;
    for (int e = (l >> 3); e <= ne; e += 8) {
        int s = (e < ne) ? csr[e0 + e] : d;
        float v = asrc[s * 8 + hme] + adh;
        v = v > 0.f ? v : 0.2f * v;
        float mn = fmaxf(m, v);
        z = z * __expf(m - mn) + __expf(v - mn);
        m = mn;
    }
    #pragma unroll
    for (int off = 8; off < 64; off <<= 1) {
        float mo = __shfl_xor(m, off);
        float zo = __shfl_xor(z, off);
        float mn = fmaxf(m, mo);
        z = z * __expf(m - mn) + zo * __expf(mo - mn);
        m = mn;
    }
    float rz = 1.0f / (z + 1e-16f);

    float acc[8][8] = {};
    for (int eb = 0; eb <= ne; eb += 8) {
        int idx = eb + (l & 7);
        int sv = (idx < ne) ? csr[e0 + idx] : d;
        int nn = min(8, ne + 1 - eb);
        #pragma unroll
        for (int i = 0; i < 8; i++) {
            if (i < nn) {
                int s = __shfl(sv, (l & 56) | i);
                float v = asrc[s * 8 + hme] + adh;
                v = v > 0.f ? v : 0.2f * v;
                float amine = __expf(v - m) * rz;
                float a[8];
                #pragma unroll
                for (int hh = 0; hh < 8; hh++)
                    a[hh] = __shfl(amine, (l & 56) | hh);
                int4 pv = *(const int4*)(hl0b + ((size_t)s << 9) + 8 * l);
                float f0 = bflo(pv.x), f1 = bfhi(pv.x);
                float f2 = bflo(pv.y), f3 = bfhi(pv.y);
                float f4 = bflo(pv.z), f5 = bfhi(pv.z);
                float f6 = bflo(pv.w), f7 = bfhi(pv.w);
                #pragma unroll
                for (int hh = 0; hh < 8; hh++) {
                    acc[hh][0] = fmaf(a[hh], f0, acc[hh][0]);
                    acc[hh][1] = fmaf(a[hh], f1, acc[hh][1]);
                    acc[hh][2] = fmaf(a[hh], f2, acc[hh][2]);
                    acc[hh][3] = fmaf(a[hh], f3, acc[hh][3]);
                    acc[hh][4] = fmaf(a[hh], f4, acc[hh][4]);
                    acc[hh][5] = fmaf(a[hh], f5, acc[hh][5]);
                    acc[hh][6] = fmaf(a[hh], f6, acc[hh][6]);
                    acc[hh][7] = fmaf(a[hh], f7, acc[hh][7]);
                }
            }
        }
    }

    #pragma unroll
    for (int hh = 0; hh < 8; hh++) {
        ushort4 qa = make_ushort4(f2bf(acc[hh][0]), f2bf(acc[hh][1]),
                                  f2bf(acc[hh][2]), f2bf(acc[hh][3]));
        ushort4 qb = make_ushort4(f2bf(acc[hh][4]), f2bf(acc[hh][5]),
                                  f2bf(acc[hh][6]), f2bf(acc[hh][7]));
        size_t ob = (size_t)dl * 4096 + hh * 512 + 8 * l;
        *(ushort4*)(aggh + ob) = qa;
        *(ushort4*)(aggh + ob + 4) = qb;
    }
}

// ------------------------------- launcher ----------------------------------
extern "C" void kernel_launch(void* const* d_in, const int* in_sizes, int n_in,
                              void* d_out, int out_size, void* d_ws, size_t ws_size,
                              hipStream_t stream) {
    const float* x = (const float*)d_in[0];
    const int* ei = (const int*)d_in[1];
    const float* W0 = (const float*)d_in[2];
    const float* at_s0 = (const float*)d_in[3];
    const float* at_d0 = (const float*)d_in[4];
    const float* b0 = (const float*)d_in[5];
    const float* W1 = (const float*)d_in[6];
    const float* at_s1 = (const float*)d_in[7];
    const float* at_d1 = (const float*)d_in[8];
    const float* b1 = (const float*)d_in[9];
    float* out = (float*)d_out;

    const int N = NNODES;
    const int E = in_sizes[1] / 2;
    const int* esrc = ei;
    const int* edst = ei + E;

    char* p = (char*)d_ws;
    auto carve = [&](size_t bytes) -> void* {
        void* r = (void*)p;
        p += ((bytes + 255) & ~(size_t)255);
        return r;
    };
    u16* h0b = (u16*)carve((size_t)N * 512 * 2);
    u16* hl0b = (u16*)carve((size_t)N * 512 * 2);
    float* as0 = (float*)carve((size_t)N * 8 * 4);
    float* ad0 = (float*)carve((size_t)N * 8 * 4);
    float* as1 = (float*)carve((size_t)N * 8 * 4);
    float* ad1 = (float*)carve((size_t)N * 8 * 4);
    int* deg = (int*)carve((size_t)N * 4);
    int* indptr = (int*)carve((size_t)(N + 1) * 4);
    int* cursor = (int*)carve((size_t)N * 4);
    int* csr = (int*)carve((size_t)E * 4);
    float* ws1 = (float*)carve(512 * 8 * 4);
    float* wd1 = (float*)carve(512 * 8 * 4);
    u16* xh = (u16*)carve((size_t)N * 512 * 2);
    u16* xl = (u16*)carve((size_t)N * 512 * 2);
    u16* W0h = (u16*)carve((size_t)512 * 512 * 2);
    u16* W0l = (u16*)carve((size_t)512 * 512 * 2);
    u16* B1h = (u16*)carve((size_t)512 * 4096 * 2);
    size_t used = (size_t)(p - (char*)d_ws);

    int CH = 1024;
    const int cands[5] = {16384, 8192, 4096, 2048, 1024};
    for (int ci = 0; ci < 5; ci++) {
        if (ws_size >= used + (size_t)cands[ci] * 8192 + 512) {
            CH = cands[ci];
            break;
        }
    }
    u16* aggh = (u16*)carve((size_t)CH * 4096 * 2);

    // CSR build
    zero_k<<<(N + 255) / 256, 256, 0, stream>>>(deg, N);
    count_k<<<(E + 255) / 256, 256, 0, stream>>>(edst, E, deg);
    scan_k<<<1, 1024, 0, stream>>>(deg, indptr, cursor, N);
    scatter_k<<<(E + 255) / 256, 256, 0, stream>>>(esrc, edst, E, cursor, csr);

    // operand prep + folded layer-1 attention weights
    prepx_k<<<(N * 512 / 4 + 255) / 256, 256, 0, stream>>>(x, xh, xl);
    prepW0t_k<<<64, 256, 0, stream>>>(W0, W0h, W0l);
    prepW1t_k<<<512, 256, 0, stream>>>(W1, B1h);
    prep1_k<<<512, 256, 0, stream>>>(W1, at_s1, at_d1, ws1, wd1);

    // Layer 0: 3-term GEMM (bf16 out) with fused alpha0 epilogue
    mgemm_k<2, 3><<<dim3(4, N / 128), 256, 0, stream>>>(
        xh, xl, W0h, W0l, h0b, 512, nullptr, at_s0, at_d0, as0, ad0);
    node0w_k<<<N / 4, 256, 0, stream>>>(h0b, as0, ad0, indptr, csr, b0, ws1,
                                        wd1, hl0b, as1, ad1);

    // Layer 1: bf16 aggregate per chunk, pure-bf16 BK=64 GEMM (+b1, ELU)
    for (int base = 0; base < N; base += CH) {
        node1w_k<<<CH / 4, 256, 0, stream>>>(hl0b, as1, ad1, indptr, csr, aggh,
                                             base, CH);
        mgemm_k<1, 1><<<dim3(4, CH / 128), 256, 0, stream>>>(
            aggh, nullptr, B1h, nullptr, out + (size_t)base * 512, 4096, b1,
            nullptr, nullptr, nullptr, nullptr);
    }
}

// Round 17
// 389.542 us; speedup vs baseline: 1.3917x; 1.0333x over previous
//
#include <hip/hip_runtime.h>
#include <hip/hip_bf16.h>

// ---------------------------------------------------------------------------
// GAT 2-layer, N=16384 nodes, D=512, H=8, E=524288 edges (+self loops)
// GEMM0: split-bf16 3-term MFMA (BK=32), fused alpha0, bf16 h0 out.
// GEMM1: pure bf16 MFMA, BK=64. Both: bijective XCD tile remap.
// Node kernels: one wave/node, LDS alpha staging (1 exp per (edge,head),
// broadcast ds_read instead of 8 bpermutes/edge). alpha1 fused into node0.
// ---------------------------------------------------------------------------

#define NNODES 16384

typedef unsigned short u16;
typedef unsigned int u32;
typedef __attribute__((ext_vector_type(8))) __bf16 bf16x8;
typedef __attribute__((ext_vector_type(4))) float f32x4;

__device__ __forceinline__ u16 f2bf(float v) {
    u32 u = __builtin_bit_cast(u32, v);
    u32 r = (u + 0x7fffu + ((u >> 16) & 1u)) >> 16;
    return (u16)r;
}
__device__ __forceinline__ float bf2f(u16 s) {
    u32 u = ((u32)s) << 16;
    return __builtin_bit_cast(float, u);
}
__device__ __forceinline__ float bflo(u32 u) {
    return __builtin_bit_cast(float, u << 16);
}
__device__ __forceinline__ float bfhi(u32 u) {
    return __builtin_bit_cast(float, u & 0xffff0000u);
}
__device__ __forceinline__ void split2(float v, u16& h, u16& l) {
    h = f2bf(v);
    l = f2bf(v - bf2f(h));
}
__device__ __forceinline__ u32 pack2(float a, float b) {
    return (u32)f2bf(a) | ((u32)f2bf(b) << 16);
}

// async global->LDS, 16B per lane
__device__ __forceinline__ void gload_lds16(const u16* g, u16* l) {
    __builtin_amdgcn_global_load_lds(
        (__attribute__((address_space(1))) void*)(void*)(g),
        (__attribute__((address_space(3))) void*)(void*)(l), 16, 0, 0);
}

// ------------------------------ CSR build ---------------------------------
__global__ void zero_k(int* p, int n) {
    int i = blockIdx.x * 256 + threadIdx.x;
    if (i < n) p[i] = 0;
}

__global__ void count_k(const int* __restrict__ dst, int E, int* __restrict__ deg) {
    int i = blockIdx.x * 256 + threadIdx.x;
    if (i < E) atomicAdd(&deg[dst[i]], 1);
}

__global__ __launch_bounds__(1024) void scan_k(const int* __restrict__ deg,
                                               int* __restrict__ indptr,
                                               int* __restrict__ cursor, int n) {
    __shared__ int sums[1024];
    int t = threadIdx.x;
    int base = t * 16;
    int local[16];
    int s = 0;
    #pragma unroll
    for (int i = 0; i < 16; i++) { local[i] = s; s += deg[base + i]; }
    sums[t] = s;
    __syncthreads();
    for (int off = 1; off < 1024; off <<= 1) {
        int v = (t >= off) ? sums[t - off] : 0;
        __syncthreads();
        sums[t] += v;
        __syncthreads();
    }
    int base_sum = (t == 0) ? 0 : sums[t - 1];
    #pragma unroll
    for (int i = 0; i < 16; i++) {
        int v = base_sum + local[i];
        indptr[base + i] = v;
        cursor[base + i] = v;
    }
    if (t == 1023) indptr[n] = base_sum + s;
}

__global__ void scatter_k(const int* __restrict__ src, const int* __restrict__ dst,
                          int E, int* __restrict__ cursor, int* __restrict__ csr) {
    int i = blockIdx.x * 256 + threadIdx.x;
    if (i < E) {
        int pos = atomicAdd(&cursor[dst[i]], 1);
        csr[pos] = src[i];
    }
}

// ------------------------- split-bf16 prep kernels -------------------------
__global__ void prepx_k(const float* __restrict__ x, u16* __restrict__ xh,
                        u16* __restrict__ xl) {
    int idx = blockIdx.x * 256 + threadIdx.x;
    int e = idx << 2;
    int n = e >> 9, k = e & 511;
    int g = n >> 10, s = n & 1023;
    float4 v = *(const float4*)(x + ((size_t)(s * 16 + g) << 9) + k);
    u16 h[4], l[4];
    split2(v.x, h[0], l[0]);
    split2(v.y, h[1], l[1]);
    split2(v.z, h[2], l[2]);
    split2(v.w, h[3], l[3]);
    size_t o = ((size_t)n << 9) + k;
    *(ushort4*)(xh + o) = make_ushort4(h[0], h[1], h[2], h[3]);
    *(ushort4*)(xl + o) = make_ushort4(l[0], l[1], l[2], l[3]);
}

// W0t[n][k] = W0[k][n], tiled 64x64 transpose through LDS
__global__ __launch_bounds__(256) void prepW0t_k(const float* __restrict__ W0,
                                                 u16* __restrict__ Wh,
                                                 u16* __restrict__ Wl) {
    __shared__ u32 tile[64][65];
    int b = blockIdx.x;
    int kt = (b >> 3) * 64, nt = (b & 7) * 64;
    int t = threadIdx.x;
    #pragma unroll
    for (int i = 0; i < 16; i++) {
        int idx = i * 256 + t;
        int r = idx >> 6, c = idx & 63;
        float v = W0[(size_t)(kt + r) * 512 + nt + c];
        u16 h, l;
        split2(v, h, l);
        tile[r][c] = ((u32)h << 16) | l;
    }
    __syncthreads();
    #pragma unroll
    for (int i = 0; i < 8; i++) {
        int idx = i * 256 + t;
        int r = idx >> 5, c2 = (idx & 31) * 2;
        u32 p0 = tile[c2][r], p1 = tile[c2 + 1][r];
        size_t o = (size_t)(nt + r) * 512 + kt + c2;
        *(ushort2*)(Wh + o) = make_ushort2((u16)(p0 >> 16), (u16)(p1 >> 16));
        *(ushort2*)(Wl + o) = make_ushort2((u16)(p0 & 0xffff), (u16)(p1 & 0xffff));
    }
}

// B1t[c][h*512+k] = bf16(W1[k][h*512+c]/8), per-head tiled 64x64 transpose
__global__ __launch_bounds__(256) void prepW1t_k(const float* __restrict__ W1,
                                                 u16* __restrict__ Bh) {
    __shared__ u16 tile[64][66];
    int b = blockIdx.x;
    int hh = b >> 6;
    int rem = b & 63;
    int kt = (rem >> 3) * 64, ct = (rem & 7) * 64;
    int t = threadIdx.x;
    #pragma unroll
    for (int i = 0; i < 16; i++) {
        int idx = i * 256 + t;
        int r = idx >> 6, c = idx & 63;
        float v = W1[(size_t)(kt + r) * 4096 + hh * 512 + ct + c] * 0.125f;
        tile[r][c] = f2bf(v);
    }
    __syncthreads();
    #pragma unroll
    for (int i = 0; i < 8; i++) {
        int idx = i * 256 + t;
        int r = idx >> 5, c2 = (idx & 31) * 2;
        size_t o = (size_t)(ct + r) * 4096 + hh * 512 + kt + c2;
        *(ushort2*)(Bh + o) = make_ushort2(tile[c2][r], tile[c2 + 1][r]);
    }
}

// ---------------------------------------------------------------------------
// MFMA GEMM: C[M,512] = A[M,K] @ Bt[512,K]^T, XCD-remapped tiles.
// TERMS=3: split-bf16 3-term, BK=32. TERMS=1: pure bf16, BK=64 (2 halves).
// MODE 1: f32 out, +bias, ELU. MODE 2: bf16 out + fused alpha0.
// ---------------------------------------------------------------------------
template <int MODE, int TERMS>
__global__ __launch_bounds__(256) void mgemm_k(
    const u16* __restrict__ Ah, const u16* __restrict__ Al,
    const u16* __restrict__ Bh, const u16* __restrict__ Bl,
    void* __restrict__ Cv, int K, const float* __restrict__ bias,
    const float* __restrict__ att_s, const float* __restrict__ att_d,
    float* __restrict__ as_, float* __restrict__ ad_) {
    __shared__ u16 smem[16384];  // 32 KB both variants

    int t = threadIdx.x;
    int lane = t & 63, w = t >> 6;
    int wr = w >> 1, wc = w & 1;

    // bijective XCD remap: all 4 col-tiles of a row-tile land on one XCD
    int orig = blockIdx.x + (blockIdx.y << 2);
    int xcd = orig & 7, slot = orig >> 3;
    int by = xcd * ((int)gridDim.y >> 3) + (slot >> 2);
    int bx = slot & 3;
    int row0 = by * 128, col0 = bx * 128;

    f32x4 acc[4][4];
    #pragma unroll
    for (int i = 0; i < 4; i++)
        #pragma unroll
        for (int j = 0; j < 4; j++) acc[i][j] = (f32x4){0.f, 0.f, 0.f, 0.f};

    int srow = lane >> 2;
    int sl4 = lane & 3;
    const u16* gp[8];
    u16* lp[8];
    #pragma unroll
    for (int ii = 0; ii < 8; ii++) {
        const u16* gb;
        int g0, koff;
        if (TERMS == 3) {
            gb = (w == 0) ? Ah : (w == 1) ? Al : (w == 2) ? Bh : Bl;
            g0 = (w < 2) ? row0 : col0;
            koff = 0;
        } else {
            gb = (w < 2) ? Ah : Bh;
            g0 = (w < 2) ? row0 : col0;
            koff = (w & 1) * 32;
        }
        int row = ii * 16 + srow;
        int sslot = sl4 ^ ((row >> 1) & 3);
        gp[ii] = gb + (size_t)(g0 + row) * K + koff + sslot * 8;
        lp[ii] = smem + w * 4096 + ii * 512;
    }

    int rl = lane & 15, kb = lane >> 4;

    if (TERMS == 3) {
        for (int k0 = 0; k0 < K; k0 += 32) {
            #pragma unroll
            for (int ii = 0; ii < 8; ii++) gload_lds16(gp[ii] + k0, lp[ii]);
            __syncthreads();

            bf16x8 afh[4], afl_[4], bfh[4], bfl[4];
            #pragma unroll
            for (int f = 0; f < 4; f++) {
                int r = wr * 64 + f * 16 + rl;
                int off = r * 32 + ((kb ^ ((r >> 1) & 3)) << 3);
                afh[f] = *(const bf16x8*)(smem + off);
                afl_[f] = *(const bf16x8*)(smem + 4096 + off);
            }
            #pragma unroll
            for (int j = 0; j < 4; j++) {
                int r = wc * 64 + j * 16 + rl;
                int off = r * 32 + ((kb ^ ((r >> 1) & 3)) << 3);
                bfh[j] = *(const bf16x8*)(smem + 8192 + off);
                bfl[j] = *(const bf16x8*)(smem + 12288 + off);
            }
            #pragma unroll
            for (int i = 0; i < 4; i++)
                #pragma unroll
                for (int j = 0; j < 4; j++) {
                    acc[i][j] = __builtin_amdgcn_mfma_f32_16x16x32_bf16(
                        afl_[i], bfh[j], acc[i][j], 0, 0, 0);
                    acc[i][j] = __builtin_amdgcn_mfma_f32_16x16x32_bf16(
                        afh[i], bfl[j], acc[i][j], 0, 0, 0);
                    acc[i][j] = __builtin_amdgcn_mfma_f32_16x16x32_bf16(
                        afh[i], bfh[j], acc[i][j], 0, 0, 0);
                }
            __syncthreads();
        }
    } else {
        for (int k0 = 0; k0 < K; k0 += 64) {
            #pragma unroll
            for (int ii = 0; ii < 8; ii++) gload_lds16(gp[ii] + k0, lp[ii]);
            __syncthreads();

            #pragma unroll
            for (int ks = 0; ks < 2; ks++) {
                bf16x8 af[4], bf[4];
                #pragma unroll
                for (int f = 0; f < 4; f++) {
                    int r = wr * 64 + f * 16 + rl;
                    int off = r * 32 + ((kb ^ ((r >> 1) & 3)) << 3);
                    af[f] = *(const bf16x8*)(smem + ks * 4096 + off);
                }
                #pragma unroll
                for (int j = 0; j < 4; j++) {
                    int r = wc * 64 + j * 16 + rl;
                    int off = r * 32 + ((kb ^ ((r >> 1) & 3)) << 3);
                    bf[j] = *(const bf16x8*)(smem + 8192 + ks * 4096 + off);
                }
                #pragma unroll
                for (int i = 0; i < 4; i++)
                    #pragma unroll
                    for (int j = 0; j < 4; j++)
                        acc[i][j] = __builtin_amdgcn_mfma_f32_16x16x32_bf16(
                            af[i], bf[j], acc[i][j], 0, 0, 0);
            }
            __syncthreads();
        }
    }

    // C/D layout 16x16: col = lane&15, row = (lane>>4)*4 + q
    int cr = kb * 4;
    #pragma unroll
    for (int i = 0; i < 4; i++) {
        #pragma unroll
        for (int j = 0; j < 4; j++) {
            int col = col0 + wc * 64 + j * 16 + rl;
            float bv = (MODE == 1) ? bias[col] : 0.f;
            f32x4 v = acc[i][j];
            #pragma unroll
            for (int q = 0; q < 4; q++) {
                float o = v[q] + bv;
                size_t grow = (size_t)(row0 + wr * 64 + i * 16 + cr + q);
                if (MODE == 1) {
                    o = o > 0.f ? o : __expf(o) - 1.f;
                    ((float*)Cv)[grow * 512 + col] = o;
                } else {
                    ((u16*)Cv)[grow * 512 + col] = f2bf(o);
                }
            }
        }
    }

    if (MODE == 2) {
        int h = (col0 >> 6) + wc;
        float as_v[4], ad_v[4];
        #pragma unroll
        for (int j = 0; j < 4; j++) {
            as_v[j] = att_s[h * 64 + j * 16 + rl];
            ad_v[j] = att_d[h * 64 + j * 16 + rl];
        }
        #pragma unroll
        for (int i = 0; i < 4; i++) {
            float ps[4] = {}, pd[4] = {};
            #pragma unroll
            for (int j = 0; j < 4; j++) {
                f32x4 v = acc[i][j];
                #pragma unroll
                for (int q = 0; q < 4; q++) {
                    ps[q] = fmaf(v[q], as_v[j], ps[q]);
                    pd[q] = fmaf(v[q], ad_v[j], pd[q]);
                }
            }
            #pragma unroll
            for (int off = 1; off < 16; off <<= 1) {
                #pragma unroll
                for (int q = 0; q < 4; q++) {
                    ps[q] += __shfl_xor(ps[q], off);
                    pd[q] += __shfl_xor(pd[q], off);
                }
            }
            if (rl == 0) {
                #pragma unroll
                for (int q = 0; q < 4; q++) {
                    size_t row = (size_t)(row0 + wr * 64 + i * 16 + cr + q);
                    as_[row * 8 + h] = ps[q];
                    ad_[row * 8 + h] = pd[q];
                }
            }
        }
    }
}

// ------------------------------ attention ---------------------------------
__global__ __launch_bounds__(256) void prep1_k(const float* __restrict__ W1,
                                               const float* __restrict__ as1,
                                               const float* __restrict__ ad1,
                                               float* __restrict__ ws1,
                                               float* __restrict__ wd1) {
    int k = blockIdx.x;
    int t = threadIdx.x;
    int h = t >> 5, lane = t & 31;
    float ps = 0.f, pd = 0.f;
    for (int c = lane; c < 512; c += 32) {
        float w = W1[(size_t)k * 4096 + h * 512 + c];
        ps += w * as1[h * 512 + c];
        pd += w * ad1[h * 512 + c];
    }
    #pragma unroll
    for (int off = 1; off < 32; off <<= 1) {
        ps += __shfl_xor(ps, off);
        pd += __shfl_xor(pd, off);
    }
    if (lane == 0) {
        ws1[k * 8 + h] = ps;
        wd1[k * 8 + h] = pd;
    }
}

// ---------------------------------------------------------------------------
// node0w: ONE WAVE PER NODE (4 nodes/block). h0 bf16. Lane l: softmax head
// h=l>>3 (stripe l&7); aggregates channels 8l..8l+7 (same head).
// Alpha staging: lane computes alpha(edge=l&7, head=l>>3) once per chunk
// into per-wave LDS; per-edge broadcast ds_read replaces score recompute.
// ---------------------------------------------------------------------------
__global__ __launch_bounds__(256) void node0w_k(
    const u16* __restrict__ h0b, const float* __restrict__ asrc,
    const float* __restrict__ adst, const int* __restrict__ indptr,
    const int* __restrict__ csr, const float* __restrict__ b0,
    const float* __restrict__ ws1, const float* __restrict__ wd1,
    u16* __restrict__ hl0b, float* __restrict__ as1, float* __restrict__ ad1) {
    __shared__ float al_s[4][64];
    int b = blockIdx.x;
    int wid = threadIdx.x >> 6;
    int l = threadIdx.x & 63;
    int d = (b & 7) * (NNODES / 8) + ((b >> 3) << 2) + wid;  // XCD-pinned
    int h = l >> 3;
    int e0 = indptr[d];
    int ne = indptr[d + 1] - e0;   // real edges; e==ne is the self loop
    float adh = adst[d * 8 + h];

    float m = -3.0e38f, z = 0.f;
    for (int e = (l & 7); e <= ne; e += 8) {
        int s = (e < ne) ? csr[e0 + e] : d;
        float v = asrc[s * 8 + h] + adh;
        v = v > 0.f ? v : 0.2f * v;
        float mn = fmaxf(m, v);
        z = z * __expf(m - mn) + __expf(v - mn);
        m = mn;
    }
    #pragma unroll
    for (int off = 1; off < 8; off <<= 1) {
        float mo = __shfl_xor(m, off);
        float zo = __shfl_xor(z, off);
        float mn = fmaxf(m, mo);
        z = z * __expf(m - mn) + zo * __expf(mo - mn);
        m = mn;
    }
    float rz = 1.0f / (z + 1e-16f);

    float acc[8] = {};
    for (int eb = 0; eb <= ne; eb += 8) {
        int idx = eb + (l & 7);
        int sv = (idx < ne) ? csr[e0 + idx] : d;
        // alpha for (edge l&7, head l>>3) -- this lane's softmax stats
        {
            float v = asrc[sv * 8 + h] + adh;
            v = v > 0.f ? v : 0.2f * v;
            al_s[wid][(l & 7) * 8 + h] = __expf(v - m) * rz;
        }
        int nn = min(8, ne + 1 - eb);
        #pragma unroll
        for (int i = 0; i < 8; i++) {
            if (i < nn) {
                int s = __shfl(sv, (l & 56) | i);
                float a = al_s[wid][i * 8 + h];
                int4 pv = *(const int4*)(h0b + ((size_t)s << 9) + 8 * l);
                acc[0] = fmaf(a, bflo(pv.x), acc[0]);
                acc[1] = fmaf(a, bfhi(pv.x), acc[1]);
                acc[2] = fmaf(a, bflo(pv.y), acc[2]);
                acc[3] = fmaf(a, bfhi(pv.y), acc[3]);
                acc[4] = fmaf(a, bflo(pv.z), acc[4]);
                acc[5] = fmaf(a, bfhi(pv.z), acc[5]);
                acc[6] = fmaf(a, bflo(pv.w), acc[6]);
                acc[7] = fmaf(a, bfhi(pv.w), acc[7]);
            }
        }
    }

    const float4* b4 = (const float4*)(b0 + 8 * l);
    float4 bva = b4[0], bvb = b4[1];
    float o[8];
    o[0] = acc[0] + bva.x; o[1] = acc[1] + bva.y;
    o[2] = acc[2] + bva.z; o[3] = acc[3] + bva.w;
    o[4] = acc[4] + bvb.x; o[5] = acc[5] + bvb.y;
    o[6] = acc[6] + bvb.z; o[7] = acc[7] + bvb.w;
    #pragma unroll
    for (int k = 0; k < 8; k++) o[k] = o[k] > 0.f ? o[k] : __expf(o[k]) - 1.f;
    int4 hv;
    hv.x = (int)pack2(o[0], o[1]);
    hv.y = (int)pack2(o[2], o[3]);
    hv.z = (int)pack2(o[4], o[5]);
    hv.w = (int)pack2(o[6], o[7]);
    *(int4*)(hl0b + ((size_t)d << 9) + 8 * l) = hv;

    float ps[8] = {}, pd[8] = {};
    #pragma unroll
    for (int k = 0; k < 8; k++) {
        const float4* w4 = (const float4*)(ws1 + (size_t)(8 * l + k) * 8);
        const float4* v4 = (const float4*)(wd1 + (size_t)(8 * l + k) * 8);
        float4 wa = w4[0], wb = w4[1];
        float4 va = v4[0], vb = v4[1];
        float ok = o[k];
        ps[0] = fmaf(ok, wa.x, ps[0]); ps[1] = fmaf(ok, wa.y, ps[1]);
        ps[2] = fmaf(ok, wa.z, ps[2]); ps[3] = fmaf(ok, wa.w, ps[3]);
        ps[4] = fmaf(ok, wb.x, ps[4]); ps[5] = fmaf(ok, wb.y, ps[5]);
        ps[6] = fmaf(ok, wb.z, ps[6]); ps[7] = fmaf(ok, wb.w, ps[7]);
        pd[0] = fmaf(ok, va.x, pd[0]); pd[1] = fmaf(ok, va.y, pd[1]);
        pd[2] = fmaf(ok, va.z, pd[2]); pd[3] = fmaf(ok, va.w, pd[3]);
        pd[4] = fmaf(ok, vb.x, pd[4]); pd[5] = fmaf(ok, vb.y, pd[5]);
        pd[6] = fmaf(ok, vb.z, pd[6]); pd[7] = fmaf(ok, vb.w, pd[7]);
    }
    #pragma unroll
    for (int off = 1; off < 64; off <<= 1) {
        #pragma unroll
        for (int j = 0; j < 8; j++) {
            ps[j] += __shfl_xor(ps[j], off);
            pd[j] += __shfl_xor(pd[j], off);
        }
    }
    #pragma unroll
    for (int j = 0; j < 8; j++) {
        if (l == j) as1[(size_t)d * 8 + j] = ps[j];
        if (l == 8 + j) ad1[(size_t)d * 8 + j] = pd[j];
    }
}

// ---------------------------------------------------------------------------
// node1w: ONE WAVE PER NODE. hl0 bf16. Lane l: softmax head hme=l&7
// (stripe l>>3). Alpha staging: lane computes alpha(edge=l>>3, head=l&7)
// once per chunk into per-wave LDS; per-edge 2x b128 broadcast read.
// ---------------------------------------------------------------------------
__global__ __launch_bounds__(256) void node1w_k(
    const u16* __restrict__ hl0b, const float* __restrict__ asrc,
    const float* __restrict__ adst, const int* __restrict__ indptr,
    const int* __restrict__ csr, u16* __restrict__ aggh, int base, int ch) {
    __shared__ float al_s[4][64];
    int b = blockIdx.x;
    int wid = threadIdx.x >> 6;
    int l = threadIdx.x & 63;
    int dl = (b & 7) * (ch >> 3) + ((b >> 3) << 2) + wid;
    int d = base + dl;
    int hme = l & 7;
    int e0 = indptr[d];
    int ne = indptr[d + 1] - e0;
    float adh = adst[d * 8 + hme];

    float m = -3.0e38f, z = 0.f;
    for (int e = (l >> 3); e <= ne; e += 8) {
        int s = (e < ne) ? csr[e0 + e] : d;
        float v = asrc[s * 8 + hme] + adh;
        v = v > 0.f ? v : 0.2f * v;
        float mn = fmaxf(m, v);
        z = z * __expf(m - mn) + __expf(v - mn);
        m = mn;
    }
    #pragma unroll
    for (int off = 8; off < 64; off <<= 1) {
        float mo = __shfl_xor(m, off);
        float zo = __shfl_xor(z, off);
        float mn = fmaxf(m, mo);
        z = z * __expf(m - mn) + zo * __expf(mo - mn);
        m = mn;
    }
    float rz = 1.0f / (z + 1e-16f);

    float acc[8][8] = {};
    for (int eb = 0; eb <= ne; eb += 8) {
        int idx = eb + (l >> 3);
        int sv = (idx < ne) ? csr[e0 + idx] : d;
        // alpha for (edge l>>3, head l&7) -- this lane's softmax stats
        {
            float v = asrc[sv * 8 + hme] + adh;
            v = v > 0.f ? v : 0.2f * v;
            al_s[wid][(l >> 3) * 8 + hme] = __expf(v - m) * rz;
        }
        int nn = min(8, ne + 1 - eb);
        #pragma unroll
        for (int i = 0; i < 8; i++) {
            if (i < nn) {
                int s = __shfl(sv, i << 3);  // broadcast: lane i*8 holds edge i
                const float4* ap = (const float4*)&al_s[wid][i * 8];
                float4 a0 = ap[0], a1 = ap[1];
                int4 pv = *(const int4*)(hl0b + ((size_t)s << 9) + 8 * l);
                float f0 = bflo(pv.x), f1 = bfhi(pv.x);
                float f2 = bflo(pv.y), f3 = bfhi(pv.y);
                float f4 = bflo(pv.z), f5 = bfhi(pv.z);
                float f6 = bflo(pv.w), f7 = bfhi(pv.w);
                float av[8] = {a0.x, a0.y, a0.z, a0.w, a1.x, a1.y, a1.z, a1.w};
                #pragma unroll
                for (int hh = 0; hh < 8; hh++) {
                    acc[hh][0] = fmaf(av[hh], f0, acc[hh][0]);
                    acc[hh][1] = fmaf(av[hh], f1, acc[hh][1]);
                    acc[hh][2] = fmaf(av[hh], f2, acc[hh][2]);
                    acc[hh][3] = fmaf(av[hh], f3, acc[hh][3]);
                    acc[hh][4] = fmaf(av[hh], f4, acc[hh][4]);
                    acc[hh][5] = fmaf(av[hh], f5, acc[hh][5]);
                    acc[hh][6] = fmaf(av[hh], f6, acc[hh][6]);
                    acc[hh][7] = fmaf(av[hh], f7, acc[hh][7]);
                }
            }
        }
    }

    #pragma unroll
    for (int hh = 0; hh < 8; hh++) {
        int4 q;
        q.x = (int)(((u32)f2bf(acc[hh][0])) | ((u32)f2bf(acc[hh][1]) << 16));
        q.y = (int)(((u32)f2bf(acc[hh][2])) | ((u32)f2bf(acc[hh][3]) << 16));
        q.z = (int)(((u32)f2bf(acc[hh][4])) | ((u32)f2bf(acc[hh][5]) << 16));
        q.w = (int)(((u32)f2bf(acc[hh][6])) | ((u32)f2bf(acc[hh][7]) << 16));
        size_t ob = (size_t)dl * 4096 + hh * 512 + 8 * l;
        *(int4*)(aggh + ob) = q;
    }
}

// ------------------------------- launcher ----------------------------------
extern "C" void kernel_launch(void* const* d_in, const int* in_sizes, int n_in,
                              void* d_out, int out_size, void* d_ws, size_t ws_size,
                              hipStream_t stream) {
    const float* x = (const float*)d_in[0];
    const int* ei = (const int*)d_in[1];
    const float* W0 = (const float*)d_in[2];
    const float* at_s0 = (const float*)d_in[3];
    const float* at_d0 = (const float*)d_in[4];
    const float* b0 = (const float*)d_in[5];
    const float* W1 = (const float*)d_in[6];
    const float* at_s1 = (const float*)d_in[7];
    const float* at_d1 = (const float*)d_in[8];
    const float* b1 = (const float*)d_in[9];
    float* out = (float*)d_out;

    const int N = NNODES;
    const int E = in_sizes[1] / 2;
    const int* esrc = ei;
    const int* edst = ei + E;

    char* p = (char*)d_ws;
    auto carve = [&](size_t bytes) -> void* {
        void* r = (void*)p;
        p += ((bytes + 255) & ~(size_t)255);
        return r;
    };
    u16* h0b = (u16*)carve((size_t)N * 512 * 2);
    u16* hl0b = (u16*)carve((size_t)N * 512 * 2);
    float* as0 = (float*)carve((size_t)N * 8 * 4);
    float* ad0 = (float*)carve((size_t)N * 8 * 4);
    float* as1 = (float*)carve((size_t)N * 8 * 4);
    float* ad1 = (float*)carve((size_t)N * 8 * 4);
    int* deg = (int*)carve((size_t)N * 4);
    int* indptr = (int*)carve((size_t)(N + 1) * 4);
    int* cursor = (int*)carve((size_t)N * 4);
    int* csr = (int*)carve((size_t)E * 4);
    float* ws1 = (float*)carve(512 * 8 * 4);
    float* wd1 = (float*)carve(512 * 8 * 4);
    u16* xh = (u16*)carve((size_t)N * 512 * 2);
    u16* xl = (u16*)carve((size_t)N * 512 * 2);
    u16* W0h = (u16*)carve((size_t)512 * 512 * 2);
    u16* W0l = (u16*)carve((size_t)512 * 512 * 2);
    u16* B1h = (u16*)carve((size_t)512 * 4096 * 2);
    size_t used = (size_t)(p - (char*)d_ws);

    int CH = 1024;
    const int cands[5] = {16384, 8192, 4096, 2048, 1024};
    for (int ci = 0; ci < 5; ci++) {
        if (ws_size >= used + (size_t)cands[ci] * 8192 + 512) {
            CH = cands[ci];
            break;
        }
    }
    u16* aggh = (u16*)carve((size_t)CH * 4096 * 2);

    // CSR build
    zero_k<<<(N + 255) / 256, 256, 0, stream>>>(deg, N);
    count_k<<<(E + 255) / 256, 256, 0, stream>>>(edst, E, deg);
    scan_k<<<1, 1024, 0, stream>>>(deg, indptr, cursor, N);
    scatter_k<<<(E + 255) / 256, 256, 0, stream>>>(esrc, edst, E, cursor, csr);

    // operand prep + folded layer-1 attention weights
    prepx_k<<<(N * 512 / 4 + 255) / 256, 256, 0, stream>>>(x, xh, xl);
    prepW0t_k<<<64, 256, 0, stream>>>(W0, W0h, W0l);
    prepW1t_k<<<512, 256, 0, stream>>>(W1, B1h);
    prep1_k<<<512, 256, 0, stream>>>(W1, at_s1, at_d1, ws1, wd1);

    // Layer 0: 3-term GEMM (bf16 out) with fused alpha0 epilogue
    mgemm_k<2, 3><<<dim3(4, N / 128), 256, 0, stream>>>(
        xh, xl, W0h, W0l, h0b, 512, nullptr, at_s0, at_d0, as0, ad0);
    node0w_k<<<N / 4, 256, 0, stream>>>(h0b, as0, ad0, indptr, csr, b0, ws1,
                                        wd1, hl0b, as1, ad1);

    // Layer 1: bf16 aggregate per chunk, pure-bf16 BK=64 GEMM (+b1, ELU)
    for (int base = 0; base < N; base += CH) {
        node1w_k<<<CH / 4, 256, 0, stream>>>(hl0b, as1, ad1, indptr, csr, aggh,
                                             base, CH);
        mgemm_k<1, 1><<<dim3(4, CH / 128), 256, 0, stream>>>(
            aggh, nullptr, B1h, nullptr, out + (size_t)base * 512, 4096, b1,
            nullptr, nullptr, nullptr, nullptr);
    }
}

// Round 18
// 388.142 us; speedup vs baseline: 1.3967x; 1.0036x over previous
//
#include <hip/hip_runtime.h>
#include <hip/hip_bf16.h>

// ---------------------------------------------------------------------------
// GAT 2-layer, N=16384 nodes, D=512, H=8, E=524288 edges (+self loops)
// GEMM0: split-bf16 3-term MFMA (BK=32), fused alpha0, bf16 h0 out.
// GEMM1: pure bf16 MFMA, BK=64. Both: bijective XCD tile remap.
// Node kernels: one wave/node, LDS alpha staging. alpha1 fused into node0
// with LDS-transpose reduction (replaces 96-shfl butterfly).
// ---------------------------------------------------------------------------

#define NNODES 16384

typedef unsigned short u16;
typedef unsigned int u32;
typedef __attribute__((ext_vector_type(8))) __bf16 bf16x8;
typedef __attribute__((ext_vector_type(4))) float f32x4;

__device__ __forceinline__ u16 f2bf(float v) {
    u32 u = __builtin_bit_cast(u32, v);
    u32 r = (u + 0x7fffu + ((u >> 16) & 1u)) >> 16;
    return (u16)r;
}
__device__ __forceinline__ float bf2f(u16 s) {
    u32 u = ((u32)s) << 16;
    return __builtin_bit_cast(float, u);
}
__device__ __forceinline__ float bflo(u32 u) {
    return __builtin_bit_cast(float, u << 16);
}
__device__ __forceinline__ float bfhi(u32 u) {
    return __builtin_bit_cast(float, u & 0xffff0000u);
}
__device__ __forceinline__ void split2(float v, u16& h, u16& l) {
    h = f2bf(v);
    l = f2bf(v - bf2f(h));
}
__device__ __forceinline__ u32 pack2(float a, float b) {
    return (u32)f2bf(a) | ((u32)f2bf(b) << 16);
}

// async global->LDS, 16B per lane
__device__ __forceinline__ void gload_lds16(const u16* g, u16* l) {
    __builtin_amdgcn_global_load_lds(
        (__attribute__((address_space(1))) void*)(void*)(g),
        (__attribute__((address_space(3))) void*)(void*)(l), 16, 0, 0);
}

// ------------------------------ CSR build ---------------------------------
__global__ void zero_k(int* p, int n) {
    int i = blockIdx.x * 256 + threadIdx.x;
    if (i < n) p[i] = 0;
}

__global__ void count_k(const int* __restrict__ dst, int E, int* __restrict__ deg) {
    int i = blockIdx.x * 256 + threadIdx.x;
    if (i < E) atomicAdd(&deg[dst[i]], 1);
}

__global__ __launch_bounds__(1024) void scan_k(const int* __restrict__ deg,
                                               int* __restrict__ indptr,
                                               int* __restrict__ cursor, int n) {
    __shared__ int sums[1024];
    int t = threadIdx.x;
    int base = t * 16;
    int local[16];
    int s = 0;
    #pragma unroll
    for (int i = 0; i < 16; i++) { local[i] = s; s += deg[base + i]; }
    sums[t] = s;
    __syncthreads();
    for (int off = 1; off < 1024; off <<= 1) {
        int v = (t >= off) ? sums[t - off] : 0;
        __syncthreads();
        sums[t] += v;
        __syncthreads();
    }
    int base_sum = (t == 0) ? 0 : sums[t - 1];
    #pragma unroll
    for (int i = 0; i < 16; i++) {
        int v = base_sum + local[i];
        indptr[base + i] = v;
        cursor[base + i] = v;
    }
    if (t == 1023) indptr[n] = base_sum + s;
}

__global__ void scatter_k(const int* __restrict__ src, const int* __restrict__ dst,
                          int E, int* __restrict__ cursor, int* __restrict__ csr) {
    int i = blockIdx.x * 256 + threadIdx.x;
    if (i < E) {
        int pos = atomicAdd(&cursor[dst[i]], 1);
        csr[pos] = src[i];
    }
}

// ------------------------- split-bf16 prep kernels -------------------------
__global__ void prepx_k(const float* __restrict__ x, u16* __restrict__ xh,
                        u16* __restrict__ xl) {
    int idx = blockIdx.x * 256 + threadIdx.x;
    int e = idx << 2;
    int n = e >> 9, k = e & 511;
    int g = n >> 10, s = n & 1023;
    float4 v = *(const float4*)(x + ((size_t)(s * 16 + g) << 9) + k);
    u16 h[4], l[4];
    split2(v.x, h[0], l[0]);
    split2(v.y, h[1], l[1]);
    split2(v.z, h[2], l[2]);
    split2(v.w, h[3], l[3]);
    size_t o = ((size_t)n << 9) + k;
    *(ushort4*)(xh + o) = make_ushort4(h[0], h[1], h[2], h[3]);
    *(ushort4*)(xl + o) = make_ushort4(l[0], l[1], l[2], l[3]);
}

// W0t[n][k] = W0[k][n], tiled 64x64 transpose through LDS
__global__ __launch_bounds__(256) void prepW0t_k(const float* __restrict__ W0,
                                                 u16* __restrict__ Wh,
                                                 u16* __restrict__ Wl) {
    __shared__ u32 tile[64][65];
    int b = blockIdx.x;
    int kt = (b >> 3) * 64, nt = (b & 7) * 64;
    int t = threadIdx.x;
    #pragma unroll
    for (int i = 0; i < 16; i++) {
        int idx = i * 256 + t;
        int r = idx >> 6, c = idx & 63;
        float v = W0[(size_t)(kt + r) * 512 + nt + c];
        u16 h, l;
        split2(v, h, l);
        tile[r][c] = ((u32)h << 16) | l;
    }
    __syncthreads();
    #pragma unroll
    for (int i = 0; i < 8; i++) {
        int idx = i * 256 + t;
        int r = idx >> 5, c2 = (idx & 31) * 2;
        u32 p0 = tile[c2][r], p1 = tile[c2 + 1][r];
        size_t o = (size_t)(nt + r) * 512 + kt + c2;
        *(ushort2*)(Wh + o) = make_ushort2((u16)(p0 >> 16), (u16)(p1 >> 16));
        *(ushort2*)(Wl + o) = make_ushort2((u16)(p0 & 0xffff), (u16)(p1 & 0xffff));
    }
}

// B1t[c][h*512+k] = bf16(W1[k][h*512+c]/8), per-head tiled 64x64 transpose
__global__ __launch_bounds__(256) void prepW1t_k(const float* __restrict__ W1,
                                                 u16* __restrict__ Bh) {
    __shared__ u16 tile[64][66];
    int b = blockIdx.x;
    int hh = b >> 6;
    int rem = b & 63;
    int kt = (rem >> 3) * 64, ct = (rem & 7) * 64;
    int t = threadIdx.x;
    #pragma unroll
    for (int i = 0; i < 16; i++) {
        int idx = i * 256 + t;
        int r = idx >> 6, c = idx & 63;
        float v = W1[(size_t)(kt + r) * 4096 + hh * 512 + ct + c] * 0.125f;
        tile[r][c] = f2bf(v);
    }
    __syncthreads();
    #pragma unroll
    for (int i = 0; i < 8; i++) {
        int idx = i * 256 + t;
        int r = idx >> 5, c2 = (idx & 31) * 2;
        size_t o = (size_t)(ct + r) * 4096 + hh * 512 + kt + c2;
        *(ushort2*)(Bh + o) = make_ushort2(tile[c2][r], tile[c2 + 1][r]);
    }
}

// ---------------------------------------------------------------------------
// MFMA GEMM: C[M,512] = A[M,K] @ Bt[512,K]^T, XCD-remapped tiles.
// TERMS=3: split-bf16 3-term, BK=32. TERMS=1: pure bf16, BK=64 (2 halves).
// MODE 1: f32 out, +bias, ELU. MODE 2: bf16 out + fused alpha0.
// ---------------------------------------------------------------------------
template <int MODE, int TERMS>
__global__ __launch_bounds__(256) void mgemm_k(
    const u16* __restrict__ Ah, const u16* __restrict__ Al,
    const u16* __restrict__ Bh, const u16* __restrict__ Bl,
    void* __restrict__ Cv, int K, const float* __restrict__ bias,
    const float* __restrict__ att_s, const float* __restrict__ att_d,
    float* __restrict__ as_, float* __restrict__ ad_) {
    __shared__ u16 smem[16384];  // 32 KB both variants

    int t = threadIdx.x;
    int lane = t & 63, w = t >> 6;
    int wr = w >> 1, wc = w & 1;

    // bijective XCD remap: all 4 col-tiles of a row-tile land on one XCD
    int orig = blockIdx.x + (blockIdx.y << 2);
    int xcd = orig & 7, slot = orig >> 3;
    int by = xcd * ((int)gridDim.y >> 3) + (slot >> 2);
    int bx = slot & 3;
    int row0 = by * 128, col0 = bx * 128;

    f32x4 acc[4][4];
    #pragma unroll
    for (int i = 0; i < 4; i++)
        #pragma unroll
        for (int j = 0; j < 4; j++) acc[i][j] = (f32x4){0.f, 0.f, 0.f, 0.f};

    int srow = lane >> 2;
    int sl4 = lane & 3;
    const u16* gp[8];
    u16* lp[8];
    #pragma unroll
    for (int ii = 0; ii < 8; ii++) {
        const u16* gb;
        int g0, koff;
        if (TERMS == 3) {
            gb = (w == 0) ? Ah : (w == 1) ? Al : (w == 2) ? Bh : Bl;
            g0 = (w < 2) ? row0 : col0;
            koff = 0;
        } else {
            gb = (w < 2) ? Ah : Bh;
            g0 = (w < 2) ? row0 : col0;
            koff = (w & 1) * 32;
        }
        int row = ii * 16 + srow;
        int sslot = sl4 ^ ((row >> 1) & 3);
        gp[ii] = gb + (size_t)(g0 + row) * K + koff + sslot * 8;
        lp[ii] = smem + w * 4096 + ii * 512;
    }

    int rl = lane & 15, kb = lane >> 4;

    if (TERMS == 3) {
        for (int k0 = 0; k0 < K; k0 += 32) {
            #pragma unroll
            for (int ii = 0; ii < 8; ii++) gload_lds16(gp[ii] + k0, lp[ii]);
            __syncthreads();

            bf16x8 afh[4], afl_[4], bfh[4], bfl[4];
            #pragma unroll
            for (int f = 0; f < 4; f++) {
                int r = wr * 64 + f * 16 + rl;
                int off = r * 32 + ((kb ^ ((r >> 1) & 3)) << 3);
                afh[f] = *(const bf16x8*)(smem + off);
                afl_[f] = *(const bf16x8*)(smem + 4096 + off);
            }
            #pragma unroll
            for (int j = 0; j < 4; j++) {
                int r = wc * 64 + j * 16 + rl;
                int off = r * 32 + ((kb ^ ((r >> 1) & 3)) << 3);
                bfh[j] = *(const bf16x8*)(smem + 8192 + off);
                bfl[j] = *(const bf16x8*)(smem + 12288 + off);
            }
            #pragma unroll
            for (int i = 0; i < 4; i++)
                #pragma unroll
                for (int j = 0; j < 4; j++) {
                    acc[i][j] = __builtin_amdgcn_mfma_f32_16x16x32_bf16(
                        afl_[i], bfh[j], acc[i][j], 0, 0, 0);
                    acc[i][j] = __builtin_amdgcn_mfma_f32_16x16x32_bf16(
                        afh[i], bfl[j], acc[i][j], 0, 0, 0);
                    acc[i][j] = __builtin_amdgcn_mfma_f32_16x16x32_bf16(
                        afh[i], bfh[j], acc[i][j], 0, 0, 0);
                }
            __syncthreads();
        }
    } else {
        for (int k0 = 0; k0 < K; k0 += 64) {
            #pragma unroll
            for (int ii = 0; ii < 8; ii++) gload_lds16(gp[ii] + k0, lp[ii]);
            __syncthreads();

            #pragma unroll
            for (int ks = 0; ks < 2; ks++) {
                bf16x8 af[4], bf[4];
                #pragma unroll
                for (int f = 0; f < 4; f++) {
                    int r = wr * 64 + f * 16 + rl;
                    int off = r * 32 + ((kb ^ ((r >> 1) & 3)) << 3);
                    af[f] = *(const bf16x8*)(smem + ks * 4096 + off);
                }
                #pragma unroll
                for (int j = 0; j < 4; j++) {
                    int r = wc * 64 + j * 16 + rl;
                    int off = r * 32 + ((kb ^ ((r >> 1) & 3)) << 3);
                    bf[j] = *(const bf16x8*)(smem + 8192 + ks * 4096 + off);
                }
                #pragma unroll
                for (int i = 0; i < 4; i++)
                    #pragma unroll
                    for (int j = 0; j < 4; j++)
                        acc[i][j] = __builtin_amdgcn_mfma_f32_16x16x32_bf16(
                            af[i], bf[j], acc[i][j], 0, 0, 0);
            }
            __syncthreads();
        }
    }

    // C/D layout 16x16: col = lane&15, row = (lane>>4)*4 + q
    int cr = kb * 4;
    #pragma unroll
    for (int i = 0; i < 4; i++) {
        #pragma unroll
        for (int j = 0; j < 4; j++) {
            int col = col0 + wc * 64 + j * 16 + rl;
            float bv = (MODE == 1) ? bias[col] : 0.f;
            f32x4 v = acc[i][j];
            #pragma unroll
            for (int q = 0; q < 4; q++) {
                float o = v[q] + bv;
                size_t grow = (size_t)(row0 + wr * 64 + i * 16 + cr + q);
                if (MODE == 1) {
                    o = o > 0.f ? o : __expf(o) - 1.f;
                    ((float*)Cv)[grow * 512 + col] = o;
                } else {
                    ((u16*)Cv)[grow * 512 + col] = f2bf(o);
                }
            }
        }
    }

    if (MODE == 2) {
        int h = (col0 >> 6) + wc;
        float as_v[4], ad_v[4];
        #pragma unroll
        for (int j = 0; j < 4; j++) {
            as_v[j] = att_s[h * 64 + j * 16 + rl];
            ad_v[j] = att_d[h * 64 + j * 16 + rl];
        }
        #pragma unroll
        for (int i = 0; i < 4; i++) {
            float ps[4] = {}, pd[4] = {};
            #pragma unroll
            for (int j = 0; j < 4; j++) {
                f32x4 v = acc[i][j];
                #pragma unroll
                for (int q = 0; q < 4; q++) {
                    ps[q] = fmaf(v[q], as_v[j], ps[q]);
                    pd[q] = fmaf(v[q], ad_v[j], pd[q]);
                }
            }
            #pragma unroll
            for (int off = 1; off < 16; off <<= 1) {
                #pragma unroll
                for (int q = 0; q < 4; q++) {
                    ps[q] += __shfl_xor(ps[q], off);
                    pd[q] += __shfl_xor(pd[q], off);
                }
            }
            if (rl == 0) {
                #pragma unroll
                for (int q = 0; q < 4; q++) {
                    size_t row = (size_t)(row0 + wr * 64 + i * 16 + cr + q);
                    as_[row * 8 + h] = ps[q];
                    ad_[row * 8 + h] = pd[q];
                }
            }
        }
    }
}

// ------------------------------ attention ---------------------------------
__global__ __launch_bounds__(256) void prep1_k(const float* __restrict__ W1,
                                               const float* __restrict__ as1,
                                               const float* __restrict__ ad1,
                                               float* __restrict__ ws1,
                                               float* __restrict__ wd1) {
    int k = blockIdx.x;
    int t = threadIdx.x;
    int h = t >> 5, lane = t & 31;
    float ps = 0.f, pd = 0.f;
    for (int c = lane; c < 512; c += 32) {
        float w = W1[(size_t)k * 4096 + h * 512 + c];
        ps += w * as1[h * 512 + c];
        pd += w * ad1[h * 512 + c];
    }
    #pragma unroll
    for (int off = 1; off < 32; off <<= 1) {
        ps += __shfl_xor(ps, off);
        pd += __shfl_xor(pd, off);
    }
    if (lane == 0) {
        ws1[k * 8 + h] = ps;
        wd1[k * 8 + h] = pd;
    }
}

// ---------------------------------------------------------------------------
// node0w: ONE WAVE PER NODE (4 nodes/block). h0 bf16. Lane l: softmax head
// h=l>>3 (stripe l&7); aggregates channels 8l..8l+7. Alpha staging in LDS.
// Fused alpha1 epilogue via LDS-transpose reduce (no 96-shfl butterfly).
// ---------------------------------------------------------------------------
__global__ __launch_bounds__(256) void node0w_k(
    const u16* __restrict__ h0b, const float* __restrict__ asrc,
    const float* __restrict__ adst, const int* __restrict__ indptr,
    const int* __restrict__ csr, const float* __restrict__ b0,
    const float* __restrict__ ws1, const float* __restrict__ wd1,
    u16* __restrict__ hl0b, float* __restrict__ as1, float* __restrict__ ad1) {
    __shared__ float al_s[4][64];
    __shared__ float red_s[4][16][68];   // padded: b128-aligned rows, spread banks
    int b = blockIdx.x;
    int wid = threadIdx.x >> 6;
    int l = threadIdx.x & 63;
    int d = (b & 7) * (NNODES / 8) + ((b >> 3) << 2) + wid;  // XCD-pinned
    int h = l >> 3;
    int e0 = indptr[d];
    int ne = indptr[d + 1] - e0;   // real edges; e==ne is the self loop
    float adh = adst[d * 8 + h];

    float m = -3.0e38f, z = 0.f;
    for (int e = (l & 7); e <= ne; e += 8) {
        int s = (e < ne) ? csr[e0 + e] : d;
        float v = asrc[s * 8 + h] + adh;
        v = v > 0.f ? v : 0.2f * v;
        float mn = fmaxf(m, v);
        z = z * __expf(m - mn) + __expf(v - mn);
        m = mn;
    }
    #pragma unroll
    for (int off = 1; off < 8; off <<= 1) {
        float mo = __shfl_xor(m, off);
        float zo = __shfl_xor(z, off);
        float mn = fmaxf(m, mo);
        z = z * __expf(m - mn) + zo * __expf(mo - mn);
        m = mn;
    }
    float rz = 1.0f / (z + 1e-16f);

    float acc[8] = {};
    for (int eb = 0; eb <= ne; eb += 8) {
        int idx = eb + (l & 7);
        int sv = (idx < ne) ? csr[e0 + idx] : d;
        {
            float v = asrc[sv * 8 + h] + adh;
            v = v > 0.f ? v : 0.2f * v;
            al_s[wid][(l & 7) * 8 + h] = __expf(v - m) * rz;
        }
        int nn = min(8, ne + 1 - eb);
        #pragma unroll
        for (int i = 0; i < 8; i++) {
            if (i < nn) {
                int s = __shfl(sv, (l & 56) | i);
                float a = al_s[wid][i * 8 + h];
                int4 pv = *(const int4*)(h0b + ((size_t)s << 9) + 8 * l);
                acc[0] = fmaf(a, bflo(pv.x), acc[0]);
                acc[1] = fmaf(a, bfhi(pv.x), acc[1]);
                acc[2] = fmaf(a, bflo(pv.y), acc[2]);
                acc[3] = fmaf(a, bfhi(pv.y), acc[3]);
                acc[4] = fmaf(a, bflo(pv.z), acc[4]);
                acc[5] = fmaf(a, bfhi(pv.z), acc[5]);
                acc[6] = fmaf(a, bflo(pv.w), acc[6]);
                acc[7] = fmaf(a, bfhi(pv.w), acc[7]);
            }
        }
    }

    const float4* b4 = (const float4*)(b0 + 8 * l);
    float4 bva = b4[0], bvb = b4[1];
    float o[8];
    o[0] = acc[0] + bva.x; o[1] = acc[1] + bva.y;
    o[2] = acc[2] + bva.z; o[3] = acc[3] + bva.w;
    o[4] = acc[4] + bvb.x; o[5] = acc[5] + bvb.y;
    o[6] = acc[6] + bvb.z; o[7] = acc[7] + bvb.w;
    #pragma unroll
    for (int k = 0; k < 8; k++) o[k] = o[k] > 0.f ? o[k] : __expf(o[k]) - 1.f;
    int4 hv;
    hv.x = (int)pack2(o[0], o[1]);
    hv.y = (int)pack2(o[2], o[3]);
    hv.z = (int)pack2(o[4], o[5]);
    hv.w = (int)pack2(o[6], o[7]);
    *(int4*)(hl0b + ((size_t)d << 9) + 8 * l) = hv;

    // fused alpha1: per-lane partials, LDS transpose, 16 lanes row-sum
    float ps[8] = {}, pd[8] = {};
    #pragma unroll
    for (int k = 0; k < 8; k++) {
        const float4* w4 = (const float4*)(ws1 + (size_t)(8 * l + k) * 8);
        const float4* v4 = (const float4*)(wd1 + (size_t)(8 * l + k) * 8);
        float4 wa = w4[0], wb = w4[1];
        float4 va = v4[0], vb = v4[1];
        float ok = o[k];
        ps[0] = fmaf(ok, wa.x, ps[0]); ps[1] = fmaf(ok, wa.y, ps[1]);
        ps[2] = fmaf(ok, wa.z, ps[2]); ps[3] = fmaf(ok, wa.w, ps[3]);
        ps[4] = fmaf(ok, wb.x, ps[4]); ps[5] = fmaf(ok, wb.y, ps[5]);
        ps[6] = fmaf(ok, wb.z, ps[6]); ps[7] = fmaf(ok, wb.w, ps[7]);
        pd[0] = fmaf(ok, va.x, pd[0]); pd[1] = fmaf(ok, va.y, pd[1]);
        pd[2] = fmaf(ok, va.z, pd[2]); pd[3] = fmaf(ok, va.w, pd[3]);
        pd[4] = fmaf(ok, vb.x, pd[4]); pd[5] = fmaf(ok, vb.y, pd[5]);
        pd[6] = fmaf(ok, vb.z, pd[6]); pd[7] = fmaf(ok, vb.w, pd[7]);
    }
    #pragma unroll
    for (int j = 0; j < 8; j++) {
        red_s[wid][j][l] = ps[j];
        red_s[wid][8 + j][l] = pd[j];
    }
    // same-wave LDS RAW: compiler inserts lgkmcnt wait; no barrier needed
    if (l < 16) {
        const float4* row = (const float4*)&red_s[wid][l][0];
        float s = 0.f;
        #pragma unroll
        for (int q = 0; q < 16; q++) {
            float4 v = row[q];
            s += (v.x + v.y) + (v.z + v.w);
        }
        if (l < 8) as1[(size_t)d * 8 + l] = s;
        else ad1[(size_t)d * 8 + (l - 8)] = s;
    }
}

// ---------------------------------------------------------------------------
// node1w: ONE WAVE PER NODE. hl0 bf16. Lane l: softmax head hme=l&7
// (stripe l>>3). Alpha staging in LDS; per-edge 2x b128 broadcast read.
// ---------------------------------------------------------------------------
__global__ __launch_bounds__(256) void node1w_k(
    const u16* __restrict__ hl0b, const float* __restrict__ asrc,
    const float* __restrict__ adst, const int* __restrict__ indptr,
    const int* __restrict__ csr, u16* __restrict__ aggh, int base, int ch) {
    __shared__ float al_s[4][64];
    int b = blockIdx.x;
    int wid = threadIdx.x >> 6;
    int l = threadIdx.x & 63;
    int dl = (b & 7) * (ch >> 3) + ((b >> 3) << 2) + wid;
    int d = base + dl;
    int hme = l & 7;
    int e0 = indptr[d];
    int ne = indptr[d + 1] - e0;
    float adh = adst[d * 8 + hme];

    float m = -3.0e38f, z = 0.f;
    for (int e = (l >> 3); e <= ne; e += 8) {
        int s = (e < ne) ? csr[e0 + e] : d;
        float v = asrc[s * 8 + hme] + adh;
        v = v > 0.f ? v : 0.2f * v;
        float mn = fmaxf(m, v);
        z = z * __expf(m - mn) + __expf(v - mn);
        m = mn;
    }
    #pragma unroll
    for (int off = 8; off < 64; off <<= 1) {
        float mo = __shfl_xor(m, off);
        float zo = __shfl_xor(z, off);
        float mn = fmaxf(m, mo);
        z = z * __expf(m - mn) + zo * __expf(mo - mn);
        m = mn;
    }
    float rz = 1.0f / (z + 1e-16f);

    float acc[8][8] = {};
    for (int eb = 0; eb <= ne; eb += 8) {
        int idx = eb + (l >> 3);
        int sv = (idx < ne) ? csr[e0 + idx] : d;
        {
            float v = asrc[sv * 8 + hme] + adh;
            v = v > 0.f ? v : 0.2f * v;
            al_s[wid][(l >> 3) * 8 + hme] = __expf(v - m) * rz;
        }
        int nn = min(8, ne + 1 - eb);
        #pragma unroll
        for (int i = 0; i < 8; i++) {
            if (i < nn) {
                int s = __shfl(sv, i << 3);  // broadcast: lane i*8 holds edge i
                const float4* ap = (const float4*)&al_s[wid][i * 8];
                float4 a0 = ap[0], a1 = ap[1];
                int4 pv = *(const int4*)(hl0b + ((size_t)s << 9) + 8 * l);
                float f0 = bflo(pv.x), f1 = bfhi(pv.x);
                float f2 = bflo(pv.y), f3 = bfhi(pv.y);
                float f4 = bflo(pv.z), f5 = bfhi(pv.z);
                float f6 = bflo(pv.w), f7 = bfhi(pv.w);
                float av[8] = {a0.x, a0.y, a0.z, a0.w, a1.x, a1.y, a1.z, a1.w};
                #pragma unroll
                for (int hh = 0; hh < 8; hh++) {
                    acc[hh][0] = fmaf(av[hh], f0, acc[hh][0]);
                    acc[hh][1] = fmaf(av[hh], f1, acc[hh][1]);
                    acc[hh][2] = fmaf(av[hh], f2, acc[hh][2]);
                    acc[hh][3] = fmaf(av[hh], f3, acc[hh][3]);
                    acc[hh][4] = fmaf(av[hh], f4, acc[hh][4]);
                    acc[hh][5] = fmaf(av[hh], f5, acc[hh][5]);
                    acc[hh][6] = fmaf(av[hh], f6, acc[hh][6]);
                    acc[hh][7] = fmaf(av[hh], f7, acc[hh][7]);
                }
            }
        }
    }

    #pragma unroll
    for (int hh = 0; hh < 8; hh++) {
        int4 q;
        q.x = (int)(((u32)f2bf(acc[hh][0])) | ((u32)f2bf(acc[hh][1]) << 16));
        q.y = (int)(((u32)f2bf(acc[hh][2])) | ((u32)f2bf(acc[hh][3]) << 16));
        q.z = (int)(((u32)f2bf(acc[hh][4])) | ((u32)f2bf(acc[hh][5]) << 16));
        q.w = (int)(((u32)f2bf(acc[hh][6])) | ((u32)f2bf(acc[hh][7]) << 16));
        size_t ob = (size_t)dl * 4096 + hh * 512 + 8 * l;
        *(int4*)(aggh + ob) = q;
    }
}

// ------------------------------- launcher ----------------------------------
extern "C" void kernel_launch(void* const* d_in, const int* in_sizes, int n_in,
                              void* d_out, int out_size, void* d_ws, size_t ws_size,
                              hipStream_t stream) {
    const float* x = (const float*)d_in[0];
    const int* ei = (const int*)d_in[1];
    const float* W0 = (const float*)d_in[2];
    const float* at_s0 = (const float*)d_in[3];
    const float* at_d0 = (const float*)d_in[4];
    const float* b0 = (const float*)d_in[5];
    const float* W1 = (const float*)d_in[6];
    const float* at_s1 = (const float*)d_in[7];
    const float* at_d1 = (const float*)d_in[8];
    const float* b1 = (const float*)d_in[9];
    float* out = (float*)d_out;

    const int N = NNODES;
    const int E = in_sizes[1] / 2;
    const int* esrc = ei;
    const int* edst = ei + E;

    char* p = (char*)d_ws;
    auto carve = [&](size_t bytes) -> void* {
        void* r = (void*)p;
        p += ((bytes + 255) & ~(size_t)255);
        return r;
    };
    u16* h0b = (u16*)carve((size_t)N * 512 * 2);
    u16* hl0b = (u16*)carve((size_t)N * 512 * 2);
    float* as0 = (float*)carve((size_t)N * 8 * 4);
    float* ad0 = (float*)carve((size_t)N * 8 * 4);
    float* as1 = (float*)carve((size_t)N * 8 * 4);
    float* ad1 = (float*)carve((size_t)N * 8 * 4);
    int* deg = (int*)carve((size_t)N * 4);
    int* indptr = (int*)carve((size_t)(N + 1) * 4);
    int* cursor = (int*)carve((size_t)N * 4);
    int* csr = (int*)carve((size_t)E * 4);
    float* ws1 = (float*)carve(512 * 8 * 4);
    float* wd1 = (float*)carve(512 * 8 * 4);
    u16* xh = (u16*)carve((size_t)N * 512 * 2);
    u16* xl = (u16*)carve((size_t)N * 512 * 2);
    u16* W0h = (u16*)carve((size_t)512 * 512 * 2);
    u16* W0l = (u16*)carve((size_t)512 * 512 * 2);
    u16* B1h = (u16*)carve((size_t)512 * 4096 * 2);
    size_t used = (size_t)(p - (char*)d_ws);

    int CH = 1024;
    const int cands[5] = {16384, 8192, 4096, 2048, 1024};
    for (int ci = 0; ci < 5; ci++) {
        if (ws_size >= used + (size_t)cands[ci] * 8192 + 512) {
            CH = cands[ci];
            break;
        }
    }
    u16* aggh = (u16*)carve((size_t)CH * 4096 * 2);

    // CSR build
    zero_k<<<(N + 255) / 256, 256, 0, stream>>>(deg, N);
    count_k<<<(E + 255) / 256, 256, 0, stream>>>(edst, E, deg);
    scan_k<<<1, 1024, 0, stream>>>(deg, indptr, cursor, N);
    scatter_k<<<(E + 255) / 256, 256, 0, stream>>>(esrc, edst, E, cursor, csr);

    // operand prep + folded layer-1 attention weights
    prepx_k<<<(N * 512 / 4 + 255) / 256, 256, 0, stream>>>(x, xh, xl);
    prepW0t_k<<<64, 256, 0, stream>>>(W0, W0h, W0l);
    prepW1t_k<<<512, 256, 0, stream>>>(W1, B1h);
    prep1_k<<<512, 256, 0, stream>>>(W1, at_s1, at_d1, ws1, wd1);

    // Layer 0: 3-term GEMM (bf16 out) with fused alpha0 epilogue
    mgemm_k<2, 3><<<dim3(4, N / 128), 256, 0, stream>>>(
        xh, xl, W0h, W0l, h0b, 512, nullptr, at_s0, at_d0, as0, ad0);
    node0w_k<<<N / 4, 256, 0, stream>>>(h0b, as0, ad0, indptr, csr, b0, ws1,
                                        wd1, hl0b, as1, ad1);

    // Layer 1: bf16 aggregate per chunk, pure-bf16 BK=64 GEMM (+b1, ELU)
    for (int base = 0; base < N; base += CH) {
        node1w_k<<<CH / 4, 256, 0, stream>>>(hl0b, as1, ad1, indptr, csr, aggh,
                                             base, CH);
        mgemm_k<1, 1><<<dim3(4, CH / 128), 256, 0, stream>>>(
            aggh, nullptr, B1h, nullptr, out + (size_t)base * 512, 4096, b1,
            nullptr, nullptr, nullptr, nullptr);
    }
}

// Round 19
// 384.818 us; speedup vs baseline: 1.4088x; 1.0086x over previous
//
#include <hip/hip_runtime.h>
#include <hip/hip_bf16.h>

// ---------------------------------------------------------------------------
// GAT 2-layer, N=16384 nodes, D=512, H=8, E=524288 edges (+self loops)
// GEMM0: split-bf16 3-term MFMA (BK=32), fused alpha0, bf16 h0 out.
// GEMM1: pure bf16 MFMA, BK=64. Both: bijective XCD tile remap.
// Node kernels: one wave/node, BATCHED two-pass softmax (csr+scores cached
// in registers; no serial load chains), LDS alpha staging.
// ---------------------------------------------------------------------------

#define NNODES 16384
#define MXIT 12   // supports node degree up to 95; guarded tail beyond

typedef unsigned short u16;
typedef unsigned int u32;
typedef __attribute__((ext_vector_type(8))) __bf16 bf16x8;
typedef __attribute__((ext_vector_type(4))) float f32x4;

__device__ __forceinline__ u16 f2bf(float v) {
    u32 u = __builtin_bit_cast(u32, v);
    u32 r = (u + 0x7fffu + ((u >> 16) & 1u)) >> 16;
    return (u16)r;
}
__device__ __forceinline__ float bf2f(u16 s) {
    u32 u = ((u32)s) << 16;
    return __builtin_bit_cast(float, u);
}
__device__ __forceinline__ float bflo(u32 u) {
    return __builtin_bit_cast(float, u << 16);
}
__device__ __forceinline__ float bfhi(u32 u) {
    return __builtin_bit_cast(float, u & 0xffff0000u);
}
__device__ __forceinline__ void split2(float v, u16& h, u16& l) {
    h = f2bf(v);
    l = f2bf(v - bf2f(h));
}
__device__ __forceinline__ u32 pack2(float a, float b) {
    return (u32)f2bf(a) | ((u32)f2bf(b) << 16);
}

// async global->LDS, 16B per lane
__device__ __forceinline__ void gload_lds16(const u16* g, u16* l) {
    __builtin_amdgcn_global_load_lds(
        (__attribute__((address_space(1))) void*)(void*)(g),
        (__attribute__((address_space(3))) void*)(void*)(l), 16, 0, 0);
}

// ------------------------------ CSR build ---------------------------------
__global__ void zero_k(int* p, int n) {
    int i = blockIdx.x * 256 + threadIdx.x;
    if (i < n) p[i] = 0;
}

__global__ void count_k(const int* __restrict__ dst, int E, int* __restrict__ deg) {
    int i = blockIdx.x * 256 + threadIdx.x;
    if (i < E) atomicAdd(&deg[dst[i]], 1);
}

__global__ __launch_bounds__(1024) void scan_k(const int* __restrict__ deg,
                                               int* __restrict__ indptr,
                                               int* __restrict__ cursor, int n) {
    __shared__ int sums[1024];
    int t = threadIdx.x;
    int base = t * 16;
    int local[16];
    int s = 0;
    #pragma unroll
    for (int i = 0; i < 16; i++) { local[i] = s; s += deg[base + i]; }
    sums[t] = s;
    __syncthreads();
    for (int off = 1; off < 1024; off <<= 1) {
        int v = (t >= off) ? sums[t - off] : 0;
        __syncthreads();
        sums[t] += v;
        __syncthreads();
    }
    int base_sum = (t == 0) ? 0 : sums[t - 1];
    #pragma unroll
    for (int i = 0; i < 16; i++) {
        int v = base_sum + local[i];
        indptr[base + i] = v;
        cursor[base + i] = v;
    }
    if (t == 1023) indptr[n] = base_sum + s;
}

__global__ void scatter_k(const int* __restrict__ src, const int* __restrict__ dst,
                          int E, int* __restrict__ cursor, int* __restrict__ csr) {
    int i = blockIdx.x * 256 + threadIdx.x;
    if (i < E) {
        int pos = atomicAdd(&cursor[dst[i]], 1);
        csr[pos] = src[i];
    }
}

// ------------------------- split-bf16 prep kernels -------------------------
__global__ void prepx_k(const float* __restrict__ x, u16* __restrict__ xh,
                        u16* __restrict__ xl) {
    int idx = blockIdx.x * 256 + threadIdx.x;
    int e = idx << 2;
    int n = e >> 9, k = e & 511;
    int g = n >> 10, s = n & 1023;
    float4 v = *(const float4*)(x + ((size_t)(s * 16 + g) << 9) + k);
    u16 h[4], l[4];
    split2(v.x, h[0], l[0]);
    split2(v.y, h[1], l[1]);
    split2(v.z, h[2], l[2]);
    split2(v.w, h[3], l[3]);
    size_t o = ((size_t)n << 9) + k;
    *(ushort4*)(xh + o) = make_ushort4(h[0], h[1], h[2], h[3]);
    *(ushort4*)(xl + o) = make_ushort4(l[0], l[1], l[2], l[3]);
}

// W0t[n][k] = W0[k][n], tiled 64x64 transpose through LDS
__global__ __launch_bounds__(256) void prepW0t_k(const float* __restrict__ W0,
                                                 u16* __restrict__ Wh,
                                                 u16* __restrict__ Wl) {
    __shared__ u32 tile[64][65];
    int b = blockIdx.x;
    int kt = (b >> 3) * 64, nt = (b & 7) * 64;
    int t = threadIdx.x;
    #pragma unroll
    for (int i = 0; i < 16; i++) {
        int idx = i * 256 + t;
        int r = idx >> 6, c = idx & 63;
        float v = W0[(size_t)(kt + r) * 512 + nt + c];
        u16 h, l;
        split2(v, h, l);
        tile[r][c] = ((u32)h << 16) | l;
    }
    __syncthreads();
    #pragma unroll
    for (int i = 0; i < 8; i++) {
        int idx = i * 256 + t;
        int r = idx >> 5, c2 = (idx & 31) * 2;
        u32 p0 = tile[c2][r], p1 = tile[c2 + 1][r];
        size_t o = (size_t)(nt + r) * 512 + kt + c2;
        *(ushort2*)(Wh + o) = make_ushort2((u16)(p0 >> 16), (u16)(p1 >> 16));
        *(ushort2*)(Wl + o) = make_ushort2((u16)(p0 & 0xffff), (u16)(p1 & 0xffff));
    }
}

// B1t[c][h*512+k] = bf16(W1[k][h*512+c]/8), per-head tiled 64x64 transpose
__global__ __launch_bounds__(256) void prepW1t_k(const float* __restrict__ W1,
                                                 u16* __restrict__ Bh) {
    __shared__ u16 tile[64][66];
    int b = blockIdx.x;
    int hh = b >> 6;
    int rem = b & 63;
    int kt = (rem >> 3) * 64, ct = (rem & 7) * 64;
    int t = threadIdx.x;
    #pragma unroll
    for (int i = 0; i < 16; i++) {
        int idx = i * 256 + t;
        int r = idx >> 6, c = idx & 63;
        float v = W1[(size_t)(kt + r) * 4096 + hh * 512 + ct + c] * 0.125f;
        tile[r][c] = f2bf(v);
    }
    __syncthreads();
    #pragma unroll
    for (int i = 0; i < 8; i++) {
        int idx = i * 256 + t;
        int r = idx >> 5, c2 = (idx & 31) * 2;
        size_t o = (size_t)(ct + r) * 4096 + hh * 512 + kt + c2;
        *(ushort2*)(Bh + o) = make_ushort2(tile[c2][r], tile[c2 + 1][r]);
    }
}

// ---------------------------------------------------------------------------
// MFMA GEMM: C[M,512] = A[M,K] @ Bt[512,K]^T, XCD-remapped tiles.
// TERMS=3: split-bf16 3-term, BK=32. TERMS=1: pure bf16, BK=64 (2 halves).
// MODE 1: f32 out, +bias, ELU. MODE 2: bf16 out + fused alpha0.
// ---------------------------------------------------------------------------
template <int MODE, int TERMS>
__global__ __launch_bounds__(256) void mgemm_k(
    const u16* __restrict__ Ah, const u16* __restrict__ Al,
    const u16* __restrict__ Bh, const u16* __restrict__ Bl,
    void* __restrict__ Cv, int K, const float* __restrict__ bias,
    const float* __restrict__ att_s, const float* __restrict__ att_d,
    float* __restrict__ as_, float* __restrict__ ad_) {
    __shared__ u16 smem[16384];  // 32 KB both variants

    int t = threadIdx.x;
    int lane = t & 63, w = t >> 6;
    int wr = w >> 1, wc = w & 1;

    // bijective XCD remap: all 4 col-tiles of a row-tile land on one XCD
    int orig = blockIdx.x + (blockIdx.y << 2);
    int xcd = orig & 7, slot = orig >> 3;
    int by = xcd * ((int)gridDim.y >> 3) + (slot >> 2);
    int bx = slot & 3;
    int row0 = by * 128, col0 = bx * 128;

    f32x4 acc[4][4];
    #pragma unroll
    for (int i = 0; i < 4; i++)
        #pragma unroll
        for (int j = 0; j < 4; j++) acc[i][j] = (f32x4){0.f, 0.f, 0.f, 0.f};

    int srow = lane >> 2;
    int sl4 = lane & 3;
    const u16* gp[8];
    u16* lp[8];
    #pragma unroll
    for (int ii = 0; ii < 8; ii++) {
        const u16* gb;
        int g0, koff;
        if (TERMS == 3) {
            gb = (w == 0) ? Ah : (w == 1) ? Al : (w == 2) ? Bh : Bl;
            g0 = (w < 2) ? row0 : col0;
            koff = 0;
        } else {
            gb = (w < 2) ? Ah : Bh;
            g0 = (w < 2) ? row0 : col0;
            koff = (w & 1) * 32;
        }
        int row = ii * 16 + srow;
        int sslot = sl4 ^ ((row >> 1) & 3);
        gp[ii] = gb + (size_t)(g0 + row) * K + koff + sslot * 8;
        lp[ii] = smem + w * 4096 + ii * 512;
    }

    int rl = lane & 15, kb = lane >> 4;

    if (TERMS == 3) {
        for (int k0 = 0; k0 < K; k0 += 32) {
            #pragma unroll
            for (int ii = 0; ii < 8; ii++) gload_lds16(gp[ii] + k0, lp[ii]);
            __syncthreads();

            bf16x8 afh[4], afl_[4], bfh[4], bfl[4];
            #pragma unroll
            for (int f = 0; f < 4; f++) {
                int r = wr * 64 + f * 16 + rl;
                int off = r * 32 + ((kb ^ ((r >> 1) & 3)) << 3);
                afh[f] = *(const bf16x8*)(smem + off);
                afl_[f] = *(const bf16x8*)(smem + 4096 + off);
            }
            #pragma unroll
            for (int j = 0; j < 4; j++) {
                int r = wc * 64 + j * 16 + rl;
                int off = r * 32 + ((kb ^ ((r >> 1) & 3)) << 3);
                bfh[j] = *(const bf16x8*)(smem + 8192 + off);
                bfl[j] = *(const bf16x8*)(smem + 12288 + off);
            }
            #pragma unroll
            for (int i = 0; i < 4; i++)
                #pragma unroll
                for (int j = 0; j < 4; j++) {
                    acc[i][j] = __builtin_amdgcn_mfma_f32_16x16x32_bf16(
                        afl_[i], bfh[j], acc[i][j], 0, 0, 0);
                    acc[i][j] = __builtin_amdgcn_mfma_f32_16x16x32_bf16(
                        afh[i], bfl[j], acc[i][j], 0, 0, 0);
                    acc[i][j] = __builtin_amdgcn_mfma_f32_16x16x32_bf16(
                        afh[i], bfh[j], acc[i][j], 0, 0, 0);
                }
            __syncthreads();
        }
    } else {
        for (int k0 = 0; k0 < K; k0 += 64) {
            #pragma unroll
            for (int ii = 0; ii < 8; ii++) gload_lds16(gp[ii] + k0, lp[ii]);
            __syncthreads();

            #pragma unroll
            for (int ks = 0; ks < 2; ks++) {
                bf16x8 af[4], bf[4];
                #pragma unroll
                for (int f = 0; f < 4; f++) {
                    int r = wr * 64 + f * 16 + rl;
                    int off = r * 32 + ((kb ^ ((r >> 1) & 3)) << 3);
                    af[f] = *(const bf16x8*)(smem + ks * 4096 + off);
                }
                #pragma unroll
                for (int j = 0; j < 4; j++) {
                    int r = wc * 64 + j * 16 + rl;
                    int off = r * 32 + ((kb ^ ((r >> 1) & 3)) << 3);
                    bf[j] = *(const bf16x8*)(smem + 8192 + ks * 4096 + off);
                }
                #pragma unroll
                for (int i = 0; i < 4; i++)
                    #pragma unroll
                    for (int j = 0; j < 4; j++)
                        acc[i][j] = __builtin_amdgcn_mfma_f32_16x16x32_bf16(
                            af[i], bf[j], acc[i][j], 0, 0, 0);
            }
            __syncthreads();
        }
    }

    // C/D layout 16x16: col = lane&15, row = (lane>>4)*4 + q
    int cr = kb * 4;
    #pragma unroll
    for (int i = 0; i < 4; i++) {
        #pragma unroll
        for (int j = 0; j < 4; j++) {
            int col = col0 + wc * 64 + j * 16 + rl;
            float bv = (MODE == 1) ? bias[col] : 0.f;
            f32x4 v = acc[i][j];
            #pragma unroll
            for (int q = 0; q < 4; q++) {
                float o = v[q] + bv;
                size_t grow = (size_t)(row0 + wr * 64 + i * 16 + cr + q);
                if (MODE == 1) {
                    o = o > 0.f ? o : __expf(o) - 1.f;
                    ((float*)Cv)[grow * 512 + col] = o;
                } else {
                    ((u16*)Cv)[grow * 512 + col] = f2bf(o);
                }
            }
        }
    }

    if (MODE == 2) {
        int h = (col0 >> 6) + wc;
        float as_v[4], ad_v[4];
        #pragma unroll
        for (int j = 0; j < 4; j++) {
            as_v[j] = att_s[h * 64 + j * 16 + rl];
            ad_v[j] = att_d[h * 64 + j * 16 + rl];
        }
        #pragma unroll
        for (int i = 0; i < 4; i++) {
            float ps[4] = {}, pd[4] = {};
            #pragma unroll
            for (int j = 0; j < 4; j++) {
                f32x4 v = acc[i][j];
                #pragma unroll
                for (int q = 0; q < 4; q++) {
                    ps[q] = fmaf(v[q], as_v[j], ps[q]);
                    pd[q] = fmaf(v[q], ad_v[j], pd[q]);
                }
            }
            #pragma unroll
            for (int off = 1; off < 16; off <<= 1) {
                #pragma unroll
                for (int q = 0; q < 4; q++) {
                    ps[q] += __shfl_xor(ps[q], off);
                    pd[q] += __shfl_xor(pd[q], off);
                }
            }
            if (rl == 0) {
                #pragma unroll
                for (int q = 0; q < 4; q++) {
                    size_t row = (size_t)(row0 + wr * 64 + i * 16 + cr + q);
                    as_[row * 8 + h] = ps[q];
                    ad_[row * 8 + h] = pd[q];
                }
            }
        }
    }
}

// ------------------------------ attention ---------------------------------
__global__ __launch_bounds__(256) void prep1_k(const float* __restrict__ W1,
                                               const float* __restrict__ as1,
                                               const float* __restrict__ ad1,
                                               float* __restrict__ ws1,
                                               float* __restrict__ wd1) {
    int k = blockIdx.x;
    int t = threadIdx.x;
    int h = t >> 5, lane = t & 31;
    float ps = 0.f, pd = 0.f;
    for (int c = lane; c < 512; c += 32) {
        float w = W1[(size_t)k * 4096 + h * 512 + c];
        ps += w * as1[h * 512 + c];
        pd += w * ad1[h * 512 + c];
    }
    #pragma unroll
    for (int off = 1; off < 32; off <<= 1) {
        ps += __shfl_xor(ps, off);
        pd += __shfl_xor(pd, off);
    }
    if (lane == 0) {
        ws1[k * 8 + h] = ps;
        wd1[k * 8 + h] = pd;
    }
}

// ---------------------------------------------------------------------------
// node0w: ONE WAVE PER NODE. h0 bf16. Lane l: softmax head h=l>>3 (edge
// stripe l&7); aggregates channels 8l..8l+7. BATCHED two-pass softmax:
// csr + scores cached in statically-indexed registers (no serial chains).
// ---------------------------------------------------------------------------
__global__ __launch_bounds__(256) void node0w_k(
    const u16* __restrict__ h0b, const float* __restrict__ asrc,
    const float* __restrict__ adst, const int* __restrict__ indptr,
    const int* __restrict__ csr, const float* __restrict__ b0,
    const float* __restrict__ ws1, const float* __restrict__ wd1,
    u16* __restrict__ hl0b, float* __restrict__ as1, float* __restrict__ ad1) {
    __shared__ float al_s[4][64];
    __shared__ float red_s[4][16][68];
    int b = blockIdx.x;
    int wid = threadIdx.x >> 6;
    int l = threadIdx.x & 63;
    int d = (b & 7) * (NNODES / 8) + ((b >> 3) << 2) + wid;  // XCD-pinned
    int h = l >> 3;
    int str = l & 7;               // edge stripe
    int e0 = indptr[d];
    int ne = indptr[d + 1] - e0;   // real edges; e==ne is the self loop
    float adh = adst[d * 8 + h];

    // batched loads: csr (independent), then scores (independent)
    int svs[MXIT];
    float vs[MXIT];
    #pragma unroll
    for (int ii = 0; ii < MXIT; ii++) {
        int e = str + ii * 8;
        if (e <= ne) svs[ii] = (e < ne) ? csr[e0 + e] : d;
    }
    #pragma unroll
    for (int ii = 0; ii < MXIT; ii++) {
        int e = str + ii * 8;
        if (e <= ne) {
            float v = asrc[svs[ii] * 8 + h] + adh;
            vs[ii] = v > 0.f ? v : 0.2f * v;
        }
    }
    float m = -3.0e38f;
    #pragma unroll
    for (int ii = 0; ii < MXIT; ii++)
        if (str + ii * 8 <= ne) m = fmaxf(m, vs[ii]);
    // rare tail (deg > 95): extend max dynamically
    for (int e = str + MXIT * 8; e <= ne; e += 8) {
        int s = (e < ne) ? csr[e0 + e] : d;
        float v = asrc[s * 8 + h] + adh;
        v = v > 0.f ? v : 0.2f * v;
        m = fmaxf(m, v);
    }
    #pragma unroll
    for (int off = 1; off < 8; off <<= 1) m = fmaxf(m, __shfl_xor(m, off));
    float z = 0.f;
    #pragma unroll
    for (int ii = 0; ii < MXIT; ii++) {
        if (str + ii * 8 <= ne) {
            vs[ii] = __expf(vs[ii] - m);   // cache numerator
            z += vs[ii];
        }
    }
    for (int e = str + MXIT * 8; e <= ne; e += 8) {
        int s = (e < ne) ? csr[e0 + e] : d;
        float v = asrc[s * 8 + h] + adh;
        v = v > 0.f ? v : 0.2f * v;
        z += __expf(v - m);
    }
    #pragma unroll
    for (int off = 1; off < 8; off <<= 1) z += __shfl_xor(z, off);
    float rz = 1.0f / (z + 1e-16f);

    // aggregate: cached svs/vs -> alpha staging with zero gathers
    float acc[8] = {};
    #pragma unroll
    for (int ii = 0; ii < MXIT; ii++) {
        int eb = ii * 8;
        if (eb <= ne) {
            al_s[wid][str * 8 + h] = vs[ii] * rz;
            int nn = min(8, ne + 1 - eb);
            int sv = svs[ii];
            #pragma unroll
            for (int i = 0; i < 8; i++) {
                if (i < nn) {
                    int s = __shfl(sv, (l & 56) | i);
                    float a = al_s[wid][i * 8 + h];
                    int4 pv = *(const int4*)(h0b + ((size_t)s << 9) + 8 * l);
                    acc[0] = fmaf(a, bflo(pv.x), acc[0]);
                    acc[1] = fmaf(a, bfhi(pv.x), acc[1]);
                    acc[2] = fmaf(a, bflo(pv.y), acc[2]);
                    acc[3] = fmaf(a, bfhi(pv.y), acc[3]);
                    acc[4] = fmaf(a, bflo(pv.z), acc[4]);
                    acc[5] = fmaf(a, bfhi(pv.z), acc[5]);
                    acc[6] = fmaf(a, bflo(pv.w), acc[6]);
                    acc[7] = fmaf(a, bfhi(pv.w), acc[7]);
                }
            }
        }
    }
    // rare tail (deg > 95): old gather path
    for (int eb = MXIT * 8; eb <= ne; eb += 8) {
        int idx = eb + str;
        int sv = (idx < ne) ? csr[e0 + idx] : d;
        {
            float v = asrc[sv * 8 + h] + adh;
            v = v > 0.f ? v : 0.2f * v;
            al_s[wid][str * 8 + h] = __expf(v - m) * rz;
        }
        int nn = min(8, ne + 1 - eb);
        #pragma unroll
        for (int i = 0; i < 8; i++) {
            if (i < nn) {
                int s = __shfl(sv, (l & 56) | i);
                float a = al_s[wid][i * 8 + h];
                int4 pv = *(const int4*)(h0b + ((size_t)s << 9) + 8 * l);
                acc[0] = fmaf(a, bflo(pv.x), acc[0]);
                acc[1] = fmaf(a, bfhi(pv.x), acc[1]);
                acc[2] = fmaf(a, bflo(pv.y), acc[2]);
                acc[3] = fmaf(a, bfhi(pv.y), acc[3]);
                acc[4] = fmaf(a, bflo(pv.z), acc[4]);
                acc[5] = fmaf(a, bfhi(pv.z), acc[5]);
                acc[6] = fmaf(a, bflo(pv.w), acc[6]);
                acc[7] = fmaf(a, bfhi(pv.w), acc[7]);
            }
        }
    }

    const float4* b4 = (const float4*)(b0 + 8 * l);
    float4 bva = b4[0], bvb = b4[1];
    float o[8];
    o[0] = acc[0] + bva.x; o[1] = acc[1] + bva.y;
    o[2] = acc[2] + bva.z; o[3] = acc[3] + bva.w;
    o[4] = acc[4] + bvb.x; o[5] = acc[5] + bvb.y;
    o[6] = acc[6] + bvb.z; o[7] = acc[7] + bvb.w;
    #pragma unroll
    for (int k = 0; k < 8; k++) o[k] = o[k] > 0.f ? o[k] : __expf(o[k]) - 1.f;
    int4 hv;
    hv.x = (int)pack2(o[0], o[1]);
    hv.y = (int)pack2(o[2], o[3]);
    hv.z = (int)pack2(o[4], o[5]);
    hv.w = (int)pack2(o[6], o[7]);
    *(int4*)(hl0b + ((size_t)d << 9) + 8 * l) = hv;

    // fused alpha1: per-lane partials, LDS transpose, 16 lanes row-sum
    float ps[8] = {}, pd[8] = {};
    #pragma unroll
    for (int k = 0; k < 8; k++) {
        const float4* w4 = (const float4*)(ws1 + (size_t)(8 * l + k) * 8);
        const float4* v4 = (const float4*)(wd1 + (size_t)(8 * l + k) * 8);
        float4 wa = w4[0], wb = w4[1];
        float4 va = v4[0], vb = v4[1];
        float ok = o[k];
        ps[0] = fmaf(ok, wa.x, ps[0]); ps[1] = fmaf(ok, wa.y, ps[1]);
        ps[2] = fmaf(ok, wa.z, ps[2]); ps[3] = fmaf(ok, wa.w, ps[3]);
        ps[4] = fmaf(ok, wb.x, ps[4]); ps[5] = fmaf(ok, wb.y, ps[5]);
        ps[6] = fmaf(ok, wb.z, ps[6]); ps[7] = fmaf(ok, wb.w, ps[7]);
        pd[0] = fmaf(ok, va.x, pd[0]); pd[1] = fmaf(ok, va.y, pd[1]);
        pd[2] = fmaf(ok, va.z, pd[2]); pd[3] = fmaf(ok, va.w, pd[3]);
        pd[4] = fmaf(ok, vb.x, pd[4]); pd[5] = fmaf(ok, vb.y, pd[5]);
        pd[6] = fmaf(ok, vb.z, pd[6]); pd[7] = fmaf(ok, vb.w, pd[7]);
    }
    #pragma unroll
    for (int j = 0; j < 8; j++) {
        red_s[wid][j][l] = ps[j];
        red_s[wid][8 + j][l] = pd[j];
    }
    if (l < 16) {
        const float4* row = (const float4*)&red_s[wid][l][0];
        float s = 0.f;
        #pragma unroll
        for (int q = 0; q < 16; q++) {
            float4 v = row[q];
            s += (v.x + v.y) + (v.z + v.w);
        }
        if (l < 8) as1[(size_t)d * 8 + l] = s;
        else ad1[(size_t)d * 8 + (l - 8)] = s;
    }
}

// ---------------------------------------------------------------------------
// node1w: ONE WAVE PER NODE. hl0 bf16. Lane l: softmax head hme=l&7 (edge
// stripe l>>3). Batched two-pass softmax; cached svs/vs in aggregate.
// ---------------------------------------------------------------------------
__global__ __launch_bounds__(256) void node1w_k(
    const u16* __restrict__ hl0b, const float* __restrict__ asrc,
    const float* __restrict__ adst, const int* __restrict__ indptr,
    const int* __restrict__ csr, u16* __restrict__ aggh, int base, int ch) {
    __shared__ float al_s[4][64];
    int b = blockIdx.x;
    int wid = threadIdx.x >> 6;
    int l = threadIdx.x & 63;
    int dl = (b & 7) * (ch >> 3) + ((b >> 3) << 2) + wid;
    int d = base + dl;
    int hme = l & 7;
    int str = l >> 3;              // edge stripe
    int e0 = indptr[d];
    int ne = indptr[d + 1] - e0;
    float adh = adst[d * 8 + hme];

    int svs[MXIT];
    float vs[MXIT];
    #pragma unroll
    for (int ii = 0; ii < MXIT; ii++) {
        int e = str + ii * 8;
        if (e <= ne) svs[ii] = (e < ne) ? csr[e0 + e] : d;
    }
    #pragma unroll
    for (int ii = 0; ii < MXIT; ii++) {
        int e = str + ii * 8;
        if (e <= ne) {
            float v = asrc[svs[ii] * 8 + hme] + adh;
            vs[ii] = v > 0.f ? v : 0.2f * v;
        }
    }
    float m = -3.0e38f;
    #pragma unroll
    for (int ii = 0; ii < MXIT; ii++)
        if (str + ii * 8 <= ne) m = fmaxf(m, vs[ii]);
    for (int e = str + MXIT * 8; e <= ne; e += 8) {
        int s = (e < ne) ? csr[e0 + e] : d;
        float v = asrc[s * 8 + hme] + adh;
        v = v > 0.f ? v : 0.2f * v;
        m = fmaxf(m, v);
    }
    #pragma unroll
    for (int off = 8; off < 64; off <<= 1) m = fmaxf(m, __shfl_xor(m, off));
    float z = 0.f;
    #pragma unroll
    for (int ii = 0; ii < MXIT; ii++) {
        if (str + ii * 8 <= ne) {
            vs[ii] = __expf(vs[ii] - m);
            z += vs[ii];
        }
    }
    for (int e = str + MXIT * 8; e <= ne; e += 8) {
        int s = (e < ne) ? csr[e0 + e] : d;
        float v = asrc[s * 8 + hme] + adh;
        v = v > 0.f ? v : 0.2f * v;
        z += __expf(v - m);
    }
    #pragma unroll
    for (int off = 8; off < 64; off <<= 1) z += __shfl_xor(z, off);
    float rz = 1.0f / (z + 1e-16f);

    float acc[8][8] = {};
    #pragma unroll
    for (int ii = 0; ii < MXIT; ii++) {
        int eb = ii * 8;
        if (eb <= ne) {
            al_s[wid][str * 8 + hme] = vs[ii] * rz;
            int nn = min(8, ne + 1 - eb);
            int sv = svs[ii];
            #pragma unroll
            for (int i = 0; i < 8; i++) {
                if (i < nn) {
                    int s = __shfl(sv, i << 3);
                    const float4* ap = (const float4*)&al_s[wid][i * 8];
                    float4 a0 = ap[0], a1 = ap[1];
                    int4 pv = *(const int4*)(hl0b + ((size_t)s << 9) + 8 * l);
                    float f0 = bflo(pv.x), f1 = bfhi(pv.x);
                    float f2 = bflo(pv.y), f3 = bfhi(pv.y);
                    float f4 = bflo(pv.z), f5 = bfhi(pv.z);
                    float f6 = bflo(pv.w), f7 = bfhi(pv.w);
                    float av[8] = {a0.x, a0.y, a0.z, a0.w,
                                   a1.x, a1.y, a1.z, a1.w};
                    #pragma unroll
                    for (int hh = 0; hh < 8; hh++) {
                        acc[hh][0] = fmaf(av[hh], f0, acc[hh][0]);
                        acc[hh][1] = fmaf(av[hh], f1, acc[hh][1]);
                        acc[hh][2] = fmaf(av[hh], f2, acc[hh][2]);
                        acc[hh][3] = fmaf(av[hh], f3, acc[hh][3]);
                        acc[hh][4] = fmaf(av[hh], f4, acc[hh][4]);
                        acc[hh][5] = fmaf(av[hh], f5, acc[hh][5]);
                        acc[hh][6] = fmaf(av[hh], f6, acc[hh][6]);
                        acc[hh][7] = fmaf(av[hh], f7, acc[hh][7]);
                    }
                }
            }
        }
    }
    // rare tail (deg > 95): old gather path
    for (int eb = MXIT * 8; eb <= ne; eb += 8) {
        int idx = eb + str;
        int sv = (idx < ne) ? csr[e0 + idx] : d;
        {
            float v = asrc[sv * 8 + hme] + adh;
            v = v > 0.f ? v : 0.2f * v;
            al_s[wid][str * 8 + hme] = __expf(v - m) * rz;
        }
        int nn = min(8, ne + 1 - eb);
        #pragma unroll
        for (int i = 0; i < 8; i++) {
            if (i < nn) {
                int s = __shfl(sv, i << 3);
                const float4* ap = (const float4*)&al_s[wid][i * 8];
                float4 a0 = ap[0], a1 = ap[1];
                int4 pv = *(const int4*)(hl0b + ((size_t)s << 9) + 8 * l);
                float f0 = bflo(pv.x), f1 = bfhi(pv.x);
                float f2 = bflo(pv.y), f3 = bfhi(pv.y);
                float f4 = bflo(pv.z), f5 = bfhi(pv.z);
                float f6 = bflo(pv.w), f7 = bfhi(pv.w);
                float av[8] = {a0.x, a0.y, a0.z, a0.w, a1.x, a1.y, a1.z, a1.w};
                #pragma unroll
                for (int hh = 0; hh < 8; hh++) {
                    acc[hh][0] = fmaf(av[hh], f0, acc[hh][0]);
                    acc[hh][1] = fmaf(av[hh], f1, acc[hh][1]);
                    acc[hh][2] = fmaf(av[hh], f2, acc[hh][2]);
                    acc[hh][3] = fmaf(av[hh], f3, acc[hh][3]);
                    acc[hh][4] = fmaf(av[hh], f4, acc[hh][4]);
                    acc[hh][5] = fmaf(av[hh], f5, acc[hh][5]);
                    acc[hh][6] = fmaf(av[hh], f6, acc[hh][6]);
                    acc[hh][7] = fmaf(av[hh], f7, acc[hh][7]);
                }
            }
        }
    }

    #pragma unroll
    for (int hh = 0; hh < 8; hh++) {
        int4 q;
        q.x = (int)(((u32)f2bf(acc[hh][0])) | ((u32)f2bf(acc[hh][1]) << 16));
        q.y = (int)(((u32)f2bf(acc[hh][2])) | ((u32)f2bf(acc[hh][3]) << 16));
        q.z = (int)(((u32)f2bf(acc[hh][4])) | ((u32)f2bf(acc[hh][5]) << 16));
        q.w = (int)(((u32)f2bf(acc[hh][6])) | ((u32)f2bf(acc[hh][7]) << 16));
        size_t ob = (size_t)dl * 4096 + hh * 512 + 8 * l;
        *(int4*)(aggh + ob) = q;
    }
}

// ------------------------------- launcher ----------------------------------
extern "C" void kernel_launch(void* const* d_in, const int* in_sizes, int n_in,
                              void* d_out, int out_size, void* d_ws, size_t ws_size,
                              hipStream_t stream) {
    const float* x = (const float*)d_in[0];
    const int* ei = (const int*)d_in[1];
    const float* W0 = (const float*)d_in[2];
    const float* at_s0 = (const float*)d_in[3];
    const float* at_d0 = (const float*)d_in[4];
    const float* b0 = (const float*)d_in[5];
    const float* W1 = (const float*)d_in[6];
    const float* at_s1 = (const float*)d_in[7];
    const float* at_d1 = (const float*)d_in[8];
    const float* b1 = (const float*)d_in[9];
    float* out = (float*)d_out;

    const int N = NNODES;
    const int E = in_sizes[1] / 2;
    const int* esrc = ei;
    const int* edst = ei + E;

    char* p = (char*)d_ws;
    auto carve = [&](size_t bytes) -> void* {
        void* r = (void*)p;
        p += ((bytes + 255) & ~(size_t)255);
        return r;
    };
    u16* h0b = (u16*)carve((size_t)N * 512 * 2);
    u16* hl0b = (u16*)carve((size_t)N * 512 * 2);
    float* as0 = (float*)carve((size_t)N * 8 * 4);
    float* ad0 = (float*)carve((size_t)N * 8 * 4);
    float* as1 = (float*)carve((size_t)N * 8 * 4);
    float* ad1 = (float*)carve((size_t)N * 8 * 4);
    int* deg = (int*)carve((size_t)N * 4);
    int* indptr = (int*)carve((size_t)(N + 1) * 4);
    int* cursor = (int*)carve((size_t)N * 4);
    int* csr = (int*)carve((size_t)E * 4);
    float* ws1 = (float*)carve(512 * 8 * 4);
    float* wd1 = (float*)carve(512 * 8 * 4);
    u16* xh = (u16*)carve((size_t)N * 512 * 2);
    u16* xl = (u16*)carve((size_t)N * 512 * 2);
    u16* W0h = (u16*)carve((size_t)512 * 512 * 2);
    u16* W0l = (u16*)carve((size_t)512 * 512 * 2);
    u16* B1h = (u16*)carve((size_t)512 * 4096 * 2);
    size_t used = (size_t)(p - (char*)d_ws);

    int CH = 1024;
    const int cands[5] = {16384, 8192, 4096, 2048, 1024};
    for (int ci = 0; ci < 5; ci++) {
        if (ws_size >= used + (size_t)cands[ci] * 8192 + 512) {
            CH = cands[ci];
            break;
        }
    }
    u16* aggh = (u16*)carve((size_t)CH * 4096 * 2);

    // CSR build
    zero_k<<<(N + 255) / 256, 256, 0, stream>>>(deg, N);
    count_k<<<(E + 255) / 256, 256, 0, stream>>>(edst, E, deg);
    scan_k<<<1, 1024, 0, stream>>>(deg, indptr, cursor, N);
    scatter_k<<<(E + 255) / 256, 256, 0, stream>>>(esrc, edst, E, cursor, csr);

    // operand prep + folded layer-1 attention weights
    prepx_k<<<(N * 512 / 4 + 255) / 256, 256, 0, stream>>>(x, xh, xl);
    prepW0t_k<<<64, 256, 0, stream>>>(W0, W0h, W0l);
    prepW1t_k<<<512, 256, 0, stream>>>(W1, B1h);
    prep1_k<<<512, 256, 0, stream>>>(W1, at_s1, at_d1, ws1, wd1);

    // Layer 0: 3-term GEMM (bf16 out) with fused alpha0 epilogue
    mgemm_k<2, 3><<<dim3(4, N / 128), 256, 0, stream>>>(
        xh, xl, W0h, W0l, h0b, 512, nullptr, at_s0, at_d0, as0, ad0);
    node0w_k<<<N / 4, 256, 0, stream>>>(h0b, as0, ad0, indptr, csr, b0, ws1,
                                        wd1, hl0b, as1, ad1);

    // Layer 1: bf16 aggregate per chunk, pure-bf16 BK=64 GEMM (+b1, ELU)
    for (int base = 0; base < N; base += CH) {
        node1w_k<<<CH / 4, 256, 0, stream>>>(hl0b, as1, ad1, indptr, csr, aggh,
                                             base, CH);
        mgemm_k<1, 1><<<dim3(4, CH / 128), 256, 0, stream>>>(
            aggh, nullptr, B1h, nullptr, out + (size_t)base * 512, 4096, b1,
            nullptr, nullptr, nullptr, nullptr);
    }
}